// Round 3
// baseline (5508.604 us; speedup 1.0000x reference)
//
#include <hip/hip_runtime.h>
#include <hip/hip_bf16.h>

typedef __hip_bfloat16 bf16;

#define HW 32400
#define NCLS 10
#define PQ 200
#define HIDDEN 128
#define NSPLIT 20
#define SPLITLEN 1620   // 20*1620 = 32400 exactly
#define CAP 6144
#define NBIN 4096

__device__ __forceinline__ float b2f(bf16 v) { return __bfloat162float(v); }
__device__ __forceinline__ void stf(float* p, float v) { *p = v; }
__device__ __forceinline__ void stf(bf16* p, float v) { *p = __float2bfloat16(v); }
// runtime-dtype load: isbf!=0 -> bf16 array, else fp32 array
__device__ __forceinline__ float ldsel(const void* p, long i, unsigned isbf) {
  return isbf ? __bfloat162float(((const bf16*)p)[i]) : ((const float*)p)[i];
}
__device__ __forceinline__ float ldf(const float* p, long i) { return p[i]; }
__device__ __forceinline__ float ldf(const bf16* p, long i) { return __bfloat162float(p[i]); }

// ---------------------------------------------------------------------------
// dtype detection: if inputs are bf16, low 16 bits of each 32-bit word are a
// genuine ~N(0,1) bf16 (exp field in [110,140] essentially always); if fp32,
// low 16 bits are uniform mantissa bits (exp-field hit rate ~12%).
// FLAGS[0] = 1 if bf16 inputs, 0 if fp32. FLAGS[1] = 0 (constant fp32 flag).
// ---------------------------------------------------------------------------
__global__ void detect_k(const unsigned* __restrict__ L, unsigned* __restrict__ FLAGS)
{
  __shared__ unsigned cnt[2];
  int tid = threadIdx.x;
  if (tid < 2) cnt[tid] = 0;
  __syncthreads();
  unsigned nz = 0, pl = 0;
  for (int w = tid; w < 4096; w += 256) {
    unsigned u = L[w];
    if (u) {
      nz++;
      unsigned e = (u >> 7) & 0xFF;
      if (e >= 110 && e <= 140) pl++;
    }
  }
  atomicAdd(&cnt[0], nz);
  atomicAdd(&cnt[1], pl);
  __syncthreads();
  if (tid == 0) {
    FLAGS[0] = (2u * cnt[1] > cnt[0]) ? 1u : 0u;
    FLAGS[1] = 0u;
  }
}

// batched weight conversion into fp32 arena (exact in both modes)
struct CvtArgs { const void* src[40]; int n[40]; int off[40]; };
__global__ __launch_bounds__(256) void cvt_k(CvtArgs a, float* __restrict__ dst,
                                             const unsigned* __restrict__ FLAGS)
{
  int j = blockIdx.y;
  unsigned isbf = FLAGS[0];
  int n = a.n[j];
  const void* s = a.src[j];
  float* d = dst + a.off[j];
  for (int t = blockIdx.x * 256 + threadIdx.x; t < n; t += gridDim.x * 256)
    d[t] = ldsel(s, t, isbf);
}

// ---------------------------------------------------------------------------
// conv2d 3x3 SAME as 9 shifted GEMMs. 60-pixel row tiles x 64 out-channels,
// thread = 4x4. A dtype chosen at runtime via FLAGS[fidx].
// ---------------------------------------------------------------------------
template <typename CT>
__global__ __launch_bounds__(256) void convgemm2d(
    const void* __restrict__ A, const unsigned* __restrict__ FLAGS, int fidx,
    long abatch,
    const float* __restrict__ W, const float* __restrict__ bias,
    const float* __restrict__ g, const float* __restrict__ beta, int act,
    CT* __restrict__ C, long cbatch, int N, int K)
{
  __shared__ __align__(16) float As[3][16][68];
  __shared__ __align__(16) float Ws[9][16][68];
  unsigned isbf = FLAGS[fidx];
  int b = blockIdx.z;
  int y = blockIdx.x / 3;
  int x0 = (blockIdx.x % 3) * 60;
  int n0 = blockIdx.y * 64;
  int tid = threadIdx.x;
  int nt = tid & 15, mt = tid >> 4;
  float acc[4][4] = {};
  for (int k0 = 0; k0 < K; k0 += 16) {
    for (int e = tid; e < 3 * 16 * 62; e += 256) {
      int seg = e / (16 * 62); int r = e - seg * (16 * 62);
      int k = r / 62; int j = r - k * 62;
      int gx = x0 + j - 1, gy = y + seg - 1;
      float v = 0.f;
      if (gx >= 0 && gx < 180 && gy >= 0 && gy < 180)
        v = ldsel(A, (long)b * abatch + (long)(k0 + k) * HW + gy * 180 + gx, isbf);
      As[seg][k][j] = v;
    }
    for (int e = tid; e < 64 * 16 * 9; e += 256) {
      int n = e / 144; int r = e - n * 144; int k = r / 9; int tap = r - k * 9;
      float v = 0.f;
      if (n0 + n < N) v = W[((long)(n0 + n) * K + (k0 + k)) * 9 + tap];
      Ws[tap][k][n] = v;
    }
    __syncthreads();
    for (int kk = 0; kk < 16; kk++) {
      float a6[3][6];
#pragma unroll
      for (int dy = 0; dy < 3; dy++) {
        float4 t4 = *(const float4*)&As[dy][kk][mt * 4];
        a6[dy][0] = t4.x; a6[dy][1] = t4.y; a6[dy][2] = t4.z; a6[dy][3] = t4.w;
        float2 t2 = *(const float2*)&As[dy][kk][mt * 4 + 4];
        a6[dy][4] = t2.x; a6[dy][5] = t2.y;
      }
#pragma unroll
      for (int dy = 0; dy < 3; dy++)
#pragma unroll
        for (int dx = 0; dx < 3; dx++) {
          float4 wv = *(const float4*)&Ws[dy * 3 + dx][kk][nt * 4];
#pragma unroll
          for (int mi = 0; mi < 4; mi++) {
            float av = a6[dy][mi + dx];
            acc[mi][0] = fmaf(av, wv.x, acc[mi][0]);
            acc[mi][1] = fmaf(av, wv.y, acc[mi][1]);
            acc[mi][2] = fmaf(av, wv.z, acc[mi][2]);
            acc[mi][3] = fmaf(av, wv.w, acc[mi][3]);
          }
        }
    }
    __syncthreads();
  }
  if (mt < 15) {
#pragma unroll
    for (int mi = 0; mi < 4; mi++) {
      int i = mt * 4 + mi;
      int n_out = y * 180 + x0 + i;
#pragma unroll
      for (int jj = 0; jj < 4; jj++) {
        int co = n0 + nt * 4 + jj;
        if (co < N) {
          float v = acc[mi][jj] + bias[co];
          if (g) v = v * g[co] + beta[co];
          if (act == 1) v = fmaxf(v, 0.f);
          else if (act == 2) v = 1.f / (1.f + expf(-v));
          stf(&C[(long)b * cbatch + (long)co * HW + n_out], v);
        }
      }
    }
  }
}

// ---------------------------------------------------------------------------
// Generic tiled GEMM: C = act(A @ W^T + bias) (+ res)
// amode 0: A[m*lda+k].  amode 1: A[k*lda+m] (+A2 same layout, un-batched).
// amode 2: A[m][k] = relu((p0*pe1w[2k]+p1*pe1w[2k+1]+pe1b[k])*pe1g[k]+pe1bt[k])
//          with (p0,p1) the BEV cell center of row m (fused pos-embed).
// cmode 0: C[m*ldc+n] ; cmode 1: C[n*ldc+m].  K multiple of 16.
// ---------------------------------------------------------------------------
template <typename AT, typename CT>
__global__ __launch_bounds__(256) void gemm_k(
    const AT* __restrict__ A, const AT* __restrict__ A2, int lda, int amode,
    long abatch,
    const float* __restrict__ W, const float* __restrict__ bias, int act,
    const float* __restrict__ res,
    const float* __restrict__ pe1w, const float* __restrict__ pe1b,
    const float* __restrict__ pe1g, const float* __restrict__ pe1bt,
    CT* __restrict__ C, int ldc, int cmode, long cbatch,
    int M, int N, int K)
{
  __shared__ __align__(16) float As[16][68];
  __shared__ __align__(16) float Ws[16][68];
  int b = blockIdx.z;
  int m0 = blockIdx.x * 64, n0 = blockIdx.y * 64;
  int tid = threadIdx.x;
  int nt = tid & 15, mt = tid >> 4;
  float acc[4][4] = {};
  const AT* Ab = A + (long)b * abatch;
  for (int k0 = 0; k0 < K; k0 += 16) {
    if (amode == 0) {
      for (int e = tid; e < 1024; e += 256) {
        int m = e >> 4, k = e & 15;
        float v = 0.f;
        if (m0 + m < M) v = ldf(Ab, (long)(m0 + m) * lda + k0 + k);
        As[k][m] = v;
      }
    } else if (amode == 1) {
      for (int e = tid; e < 1024; e += 256) {
        int m = e & 63, k = e >> 6;
        float v = 0.f;
        if (m0 + m < M) {
          long idx = (long)(k0 + k) * lda + m0 + m;
          v = ldf(Ab, idx);
          if (A2) v += ldf(A2, idx);
        }
        As[k][m] = v;
      }
    } else {
      for (int e = tid; e < 1024; e += 256) {
        int m = e & 63, k = e >> 6;
        float v = 0.f;
        int gm = m0 + m;
        if (gm < M) {
          float p0 = (float)(gm / 180) + 0.5f;
          float p1 = (float)(gm % 180) + 0.5f;
          int kk = k0 + k;
          float t = p0 * pe1w[kk * 2] + p1 * pe1w[kk * 2 + 1] + pe1b[kk];
          t = t * pe1g[kk] + pe1bt[kk];
          v = fmaxf(t, 0.f);
        }
        As[k][m] = v;
      }
    }
    for (int e = tid; e < 1024; e += 256) {
      int n = e >> 4, k = e & 15;
      float v = 0.f;
      if (n0 + n < N) v = W[(long)(n0 + n) * K + k0 + k];
      Ws[k][n] = v;
    }
    __syncthreads();
#pragma unroll
    for (int kk = 0; kk < 16; kk++) {
      float4 av = *(const float4*)&As[kk][mt * 4];
      float4 wv = *(const float4*)&Ws[kk][nt * 4];
      float am[4] = {av.x, av.y, av.z, av.w};
      float wn[4] = {wv.x, wv.y, wv.z, wv.w};
#pragma unroll
      for (int mi = 0; mi < 4; mi++)
#pragma unroll
        for (int ni = 0; ni < 4; ni++)
          acc[mi][ni] = fmaf(am[mi], wn[ni], acc[mi][ni]);
    }
    __syncthreads();
  }
#pragma unroll
  for (int mi = 0; mi < 4; mi++) {
    int m = m0 + mt * 4 + mi;
    if (m >= M) continue;
#pragma unroll
    for (int ni = 0; ni < 4; ni++) {
      int n = n0 + nt * 4 + ni;
      if (n >= N) continue;
      float v = acc[mi][ni];
      if (bias) v += bias[n];
      if (act == 1) v = fmaxf(v, 0.f);
      if (res) v += res[(long)m * ldc + n];
      long ci = (cmode == 0) ? ((long)b * cbatch + (long)m * ldc + n)
                             : ((long)b * cbatch + (long)n * ldc + m);
      stf(&C[ci], v);
    }
  }
}

// ---------------------------------------------------------------------------
__global__ void nms_k(const float* __restrict__ HEAT, float* __restrict__ SCORE)
{
  int t = blockIdx.x * 256 + threadIdx.x;
  if (t >= 2 * NCLS * HW) return;
  int b = t / (NCLS * HW); int r = t % (NCLS * HW);
  int cls = r / HW; int n = r % HW;
  const float* hb = HEAT + ((long)(b * NCLS + cls)) * HW;
  float v = hb[n];
  bool keep = true;
  if (cls < 8) {
    int y = n / 180, x = n % 180;
    if (y == 0 || y == 179 || x == 0 || x == 179) keep = false;
    else {
      float mx = -1e30f;
#pragma unroll
      for (int dy = -1; dy <= 1; dy++)
#pragma unroll
        for (int dx = -1; dx <= 1; dx++)
          mx = fmaxf(mx, hb[(y + dy) * 180 + x + dx]);
      keep = (v == mx);
    }
  }
  SCORE[(long)b * (NCLS * HW) + r] = keep ? v : 0.f;
}

__global__ void zero_u32(unsigned* p, int n)
{
  int t = blockIdx.x * 256 + threadIdx.x;
  if (t < n) p[t] = 0;
}

__global__ __launch_bounds__(256) void hist_k(const float* __restrict__ SCORE,
                                              unsigned* __restrict__ HIST)
{
  __shared__ unsigned lh[NBIN];
  int b = blockIdx.y;
  for (int e = threadIdx.x; e < NBIN; e += 256) lh[e] = 0;
  __syncthreads();
  int start = blockIdx.x * 1350;
  const float* sb = SCORE + (long)b * (NCLS * HW);
  for (int e = start + threadIdx.x; e < start + 1350; e += 256) {
    unsigned bits = __float_as_uint(sb[e]);
    atomicAdd(&lh[bits >> 18], 1u);
  }
  __syncthreads();
  for (int e = threadIdx.x; e < NBIN; e += 256) {
    unsigned c = lh[e];
    if (c) atomicAdd(&HIST[b * NBIN + e], c);
  }
}

__global__ void thresh_k(const unsigned* __restrict__ HIST, unsigned* __restrict__ THR)
{
  __shared__ unsigned ps[256];
  int b = blockIdx.x;
  const unsigned* hb = HIST + b * NBIN;
  unsigned s = 0;
  for (int j = 0; j < 16; j++) s += hb[threadIdx.x * 16 + j];
  ps[threadIdx.x] = s;
  __syncthreads();
  if (threadIdx.x == 0) {
    unsigned cum = 0; int t = 255;
    for (; t > 0; t--) { if (cum + ps[t] >= PQ) break; cum += ps[t]; }
    int bin = t * 16 + 15;
    for (; bin > t * 16; bin--) { unsigned c = hb[bin]; if (cum + c >= PQ) break; cum += c; }
    if (bin < 1) bin = 1;
    THR[b] = (unsigned)bin;
  }
}

__global__ void collect_k(const float* __restrict__ SCORE, const unsigned* __restrict__ THR,
                          unsigned* __restrict__ ACNT, unsigned long long* __restrict__ CAND)
{
  int t = blockIdx.x * 256 + threadIdx.x;
  if (t >= 2 * NCLS * HW) return;
  int b = t / (NCLS * HW); int r = t % (NCLS * HW);
  float v = SCORE[(long)b * (NCLS * HW) + r];
  unsigned bits = __float_as_uint(v);
  if ((bits >> 18) >= THR[b]) {
    unsigned slot = atomicAdd(&ACNT[b], 1u);
    if (slot < CAP) CAND[(long)b * CAP + slot] =
        ((unsigned long long)bits << 32) | (unsigned)(~r);
  }
}

__global__ __launch_bounds__(64) void select_k(
    const unsigned long long* __restrict__ CAND, const unsigned* __restrict__ ACNT,
    unsigned* __restrict__ TOPC, unsigned* __restrict__ TOPI, float* __restrict__ QPA)
{
  __shared__ unsigned long long cnd[CAP];
  int b = blockIdx.x;
  int lane = threadIdx.x;
  unsigned cnt = ACNT[b]; if (cnt > CAP) cnt = CAP;
  for (int e = lane; e < (int)cnt; e += 64) cnd[e] = CAND[(long)b * CAP + e];
  __syncthreads();
  for (int p = 0; p < PQ; p++) {
    unsigned long long best = 0;
    for (int e = lane; e < (int)cnt; e += 64) { unsigned long long c = cnd[e]; if (c > best) best = c; }
#pragma unroll
    for (int o = 32; o; o >>= 1) {
      unsigned long long other = __shfl_xor(best, o, 64);
      if (other > best) best = other;
    }
    for (int e = lane; e < (int)cnt; e += 64) if (best != 0 && cnd[e] == best) cnd[e] = 0;
    if (lane == 0) {
      unsigned idx = (best == 0) ? 0u : ~(unsigned)(best & 0xFFFFFFFFull);
      if (idx >= NCLS * HW) idx = 0;
      unsigned cls = idx / HW, n = idx % HW;
      TOPC[b * PQ + p] = cls; TOPI[b * PQ + p] = n;
      QPA[((long)(b * PQ + p)) * 2 + 0] = (float)(n / 180) + 0.5f;
      QPA[((long)(b * PQ + p)) * 2 + 1] = (float)(n % 180) + 0.5f;
    }
    __syncthreads();
  }
}

__global__ void gather_k(const float* __restrict__ LIDF, const unsigned* __restrict__ TOPC,
                         const unsigned* __restrict__ TOPI, const float* __restrict__ cew,
                         const float* __restrict__ ceb, float* __restrict__ X)
{
  int t = blockIdx.x * 256 + threadIdx.x;
  if (t >= 2 * PQ * HIDDEN) return;
  int c = t & 127; int r = t >> 7; int p = r % PQ; int b = r / PQ;
  unsigned n = TOPI[b * PQ + p]; unsigned cls = TOPC[b * PQ + p];
  if (n >= HW) n = 0;
  if (cls >= NCLS) cls = 0;
  X[t] = LIDF[((long)(b * HIDDEN + c)) * HW + n] + cew[c * NCLS + cls] + ceb[c];
}

// posembed stage 1 for queries only
__global__ void pe_stage1(const float* __restrict__ qpos,
                          const float* __restrict__ w1, const float* __restrict__ b1,
                          const float* __restrict__ g, const float* __restrict__ bt,
                          float* __restrict__ T1, int M)
{
  int t = blockIdx.x * 256 + threadIdx.x;
  if (t >= M * HIDDEN) return;
  int c = t & 127; int m = t >> 7;
  float p0 = qpos[m * 2], p1 = qpos[m * 2 + 1];
  float v = p0 * w1[c * 2] + p1 * w1[c * 2 + 1] + b1[c];
  v = v * g[c] + bt[c];
  T1[t] = fmaxf(v, 0.f);
}

__global__ void add2_k(const float* __restrict__ a, const float* __restrict__ b,
                       float* __restrict__ o, int n)
{
  int t = blockIdx.x * 256 + threadIdx.x;
  if (t < n) o[t] = a[t] + b[t];
}

__global__ __launch_bounds__(64) void self_attn_k(const float* __restrict__ SQKV,
                                                  float* __restrict__ SAO)
{
  int q = blockIdx.x, h = blockIdx.y, b = blockIdx.z;
  int lane = threadIdx.x;
  const float* qp = SQKV + ((long)(b * PQ + q)) * 384 + h * 16;
  float qv[16];
#pragma unroll
  for (int d = 0; d < 16; d++) qv[d] = qp[d] * 0.25f;
  float sv[4]; int kks[4]; int nk = 0;
  float lmax = -1e30f;
  for (int kk = lane; kk < PQ; kk += 64) {
    const float* kp = SQKV + ((long)(b * PQ + kk)) * 384 + 128 + h * 16;
    float s = 0.f;
#pragma unroll
    for (int d = 0; d < 16; d++) s = fmaf(qv[d], kp[d], s);
    sv[nk] = s; kks[nk] = kk; nk++;
    lmax = fmaxf(lmax, s);
  }
#pragma unroll
  for (int o = 32; o; o >>= 1) lmax = fmaxf(lmax, __shfl_xor(lmax, o, 64));
  float lsum = 0.f; float acc[16] = {};
  for (int t = 0; t < nk; t++) {
    float p = expf(sv[t] - lmax);
    lsum += p;
    const float* vp = SQKV + ((long)(b * PQ + kks[t])) * 384 + 256 + h * 16;
#pragma unroll
    for (int d = 0; d < 16; d++) acc[d] = fmaf(p, vp[d], acc[d]);
  }
#pragma unroll
  for (int o = 32; o; o >>= 1) lsum += __shfl_xor(lsum, o, 64);
#pragma unroll
  for (int d = 0; d < 16; d++) {
    float v = acc[d];
#pragma unroll
    for (int o = 32; o; o >>= 1) v += __shfl_xor(v, o, 64);
    if (lane == 0) SAO[((long)(b * PQ + q)) * HIDDEN + h * 16 + d] = v / lsum;
  }
}

// flash cross-attention, key-split. QH [400][128] fp32, KVT [B][256][HW] bf16.
// PART [B][8][NSPLIT][200][18] = o[16], m, l
__global__ __launch_bounds__(256) void flash_k(const float* __restrict__ QH,
                                               const bf16* __restrict__ KVT,
                                               float* __restrict__ PART)
{
  int s = blockIdx.x, h = blockIdx.y, b = blockIdx.z;
  int tid = threadIdx.x;
  __shared__ __align__(16) float qL[PQ][16];
  __shared__ __align__(16) float oL[PQ][16];
  __shared__ float mL[PQ], lL[PQ];
  __shared__ __align__(16) float kjL[32][16];
  __shared__ __align__(16) float vjL[32][16];
  __shared__ float sL[PQ][32];
  for (int e = tid; e < PQ * 16; e += 256) {
    int q = e >> 4, d = e & 15;
    qL[q][d] = QH[((long)(b * PQ + q)) * HIDDEN + h * 16 + d] * 0.25f;
    oL[q][d] = 0.f;
  }
  if (tid < PQ) { mL[tid] = -1e30f; lL[tid] = 0.f; }
  __syncthreads();
  int nbeg = s * SPLITLEN, nend = nbeg + SPLITLEN;
  const bf16* Kb = KVT + (long)b * 256 * HW + (long)(h * 16) * HW;
  const bf16* Vb = Kb + (long)128 * HW;
  for (int n0 = nbeg; n0 < nend; n0 += 32) {
    int rem = nend - n0;
    for (int e = tid; e < 512; e += 256) {
      int j = e & 31, d = e >> 5;
      float kv = 0.f, vv = 0.f;
      if (j < rem) { kv = b2f(Kb[(long)d * HW + n0 + j]); vv = b2f(Vb[(long)d * HW + n0 + j]); }
      kjL[j][d] = kv; vjL[j][d] = vv;
    }
    __syncthreads();
    {
      int j = tid & 31, qg = tid >> 5;
      float kr[16];
#pragma unroll
      for (int d4 = 0; d4 < 4; d4++) {
        float4 t = *(const float4*)&kjL[j][d4 * 4];
        kr[d4 * 4 + 0] = t.x; kr[d4 * 4 + 1] = t.y; kr[d4 * 4 + 2] = t.z; kr[d4 * 4 + 3] = t.w;
      }
      bool valid = j < rem;
      for (int q = qg; q < PQ; q += 8) {
        float sd = 0.f;
#pragma unroll
        for (int d4 = 0; d4 < 4; d4++) {
          float4 t = *(const float4*)&qL[q][d4 * 4];
          sd = fmaf(t.x, kr[d4 * 4 + 0], sd);
          sd = fmaf(t.y, kr[d4 * 4 + 1], sd);
          sd = fmaf(t.z, kr[d4 * 4 + 2], sd);
          sd = fmaf(t.w, kr[d4 * 4 + 3], sd);
        }
        sL[q][j] = valid ? sd : -1e30f;
      }
    }
    __syncthreads();
    if (tid < PQ) {
      int q = tid;
      float mold = mL[q];
      float mnew = mold;
      for (int j = 0; j < 32; j++) mnew = fmaxf(mnew, sL[q][j]);
      float alpha = expf(mold - mnew);
      float lsum = 0.f;
      for (int j = 0; j < 32; j++) {
        float p = expf(sL[q][j] - mnew);
        sL[q][j] = p;
        lsum += p;
      }
      lL[q] = lL[q] * alpha + lsum;
      mL[q] = mnew;
      float o[16];
#pragma unroll
      for (int d4 = 0; d4 < 4; d4++) {
        float4 t = *(const float4*)&oL[q][d4 * 4];
        o[d4 * 4 + 0] = t.x * alpha; o[d4 * 4 + 1] = t.y * alpha;
        o[d4 * 4 + 2] = t.z * alpha; o[d4 * 4 + 3] = t.w * alpha;
      }
      for (int j = 0; j < 32; j++) {
        float p = sL[q][j];
#pragma unroll
        for (int d4 = 0; d4 < 4; d4++) {
          float4 t = *(const float4*)&vjL[j][d4 * 4];
          o[d4 * 4 + 0] = fmaf(p, t.x, o[d4 * 4 + 0]);
          o[d4 * 4 + 1] = fmaf(p, t.y, o[d4 * 4 + 1]);
          o[d4 * 4 + 2] = fmaf(p, t.z, o[d4 * 4 + 2]);
          o[d4 * 4 + 3] = fmaf(p, t.w, o[d4 * 4 + 3]);
        }
      }
#pragma unroll
      for (int d = 0; d < 16; d++) oL[q][d] = o[d];
    }
    __syncthreads();
  }
  long base = ((((long)(b * 8 + h)) * NSPLIT + s) * PQ) * 18;
  for (int e = tid; e < PQ * 18; e += 256) {
    int q = e / 18, d = e - q * 18;
    float v;
    if (d < 16) v = oL[q][d];
    else if (d == 16) v = mL[q];
    else v = lL[q];
    PART[base + (long)q * 18 + d] = v;
  }
}

__global__ void combine_k(const float* __restrict__ PART, float* __restrict__ CAO)
{
  int t = blockIdx.x * 256 + threadIdx.x;
  if (t >= 2 * 8 * PQ * 16) return;
  int d = t & 15; int r = t >> 4;
  int q = r % PQ; r /= PQ;
  int h = r & 7; int b = r >> 3;
  long base = (((long)(b * 8 + h)) * NSPLIT) * PQ * 18 + (long)q * 18;
  float M = -1e30f;
  for (int s = 0; s < NSPLIT; s++) M = fmaxf(M, PART[base + (long)s * PQ * 18 + 16]);
  float L = 0.f, O = 0.f;
  for (int s = 0; s < NSPLIT; s++) {
    long p0 = base + (long)s * PQ * 18;
    float w = expf(PART[p0 + 16] - M);
    L += PART[p0 + 17] * w;
    O += PART[p0 + d] * w;
  }
  CAO[((long)(b * PQ + q)) * HIDDEN + h * 16 + d] = (L > 0.f) ? O / L : 0.f;
}

__global__ __launch_bounds__(256) void ln_k(const float* __restrict__ PRE,
                                            const float* __restrict__ g,
                                            const float* __restrict__ bta,
                                            float* __restrict__ X)
{
  int row = blockIdx.x * 4 + (threadIdx.x >> 6);
  int lane = threadIdx.x & 63;
  const float* p = PRE + (long)row * HIDDEN;
  float v0 = p[lane], v1 = p[lane + 64];
  float s = v0 + v1;
#pragma unroll
  for (int o = 32; o; o >>= 1) s += __shfl_xor(s, o, 64);
  float mu = s * (1.f / 128.f);
  float d0 = v0 - mu, d1 = v1 - mu;
  float vs = d0 * d0 + d1 * d1;
#pragma unroll
  for (int o = 32; o; o >>= 1) vs += __shfl_xor(vs, o, 64);
  float rs = rsqrtf(vs * (1.f / 128.f) + 1e-5f);
  float* xo = X + (long)row * HIDDEN;
  xo[lane] = d0 * rs * g[lane] + bta[lane];
  xo[lane + 64] = d1 * rs * g[lane + 64] + bta[lane + 64];
}

__global__ __launch_bounds__(128) void conv1d_k(const float* __restrict__ X,
                                                const float* __restrict__ w,
                                                const float* __restrict__ bias,
                                                const float* __restrict__ g,
                                                const float* __restrict__ beta,
                                                float* __restrict__ Y)
{
  int p = blockIdx.x, b = blockIdx.y;
  int co = threadIdx.x;
  __shared__ float xs[3][HIDDEN];
  for (int e = co; e < 3 * HIDDEN; e += HIDDEN) {
    int t = e >> 7, c = e & 127;
    int pp = p + t - 1;
    xs[t][c] = (pp >= 0 && pp < PQ) ? X[((long)(b * PQ + pp)) * HIDDEN + c] : 0.f;
  }
  __syncthreads();
  const float* wr = w + (long)co * HIDDEN * 3;
  float acc = 0.f;
  for (int c = 0; c < HIDDEN; c++) {
    acc = fmaf(xs[0][c], wr[c * 3 + 0], acc);
    acc = fmaf(xs[1][c], wr[c * 3 + 1], acc);
    acc = fmaf(xs[2][c], wr[c * 3 + 2], acc);
  }
  float v = (acc + bias[co]) * g[co] + beta[co];
  Y[((long)(b * PQ + p)) * HIDDEN + co] = fmaxf(v, 0.f);
}

__global__ void head2_k(const float* __restrict__ Y, const float* __restrict__ w,
                        const float* __restrict__ bias, const float* __restrict__ qpos,
                        float* __restrict__ OUT, int N, float* __restrict__ qnext)
{
  int t = blockIdx.x * 256 + threadIdx.x;
  if (t >= 2 * N * PQ) return;
  int p = t % PQ; int r = t / PQ; int co = r % N; int b = r / N;
  const float* wr = w + (long)co * HIDDEN * 3;
  float acc = 0.f;
  for (int tap = 0; tap < 3; tap++) {
    int pp = p + tap - 1;
    if (pp < 0 || pp >= PQ) continue;
    const float* yr = Y + ((long)(b * PQ + pp)) * HIDDEN;
    for (int c = 0; c < HIDDEN; c++)
      acc = fmaf(yr[c], wr[c * 3 + tap], acc);
  }
  float v = acc + bias[co];
  if (qpos) v += qpos[((long)(b * PQ + p)) * 2 + co];
  OUT[((long)(b * N + co)) * PQ + p] = v;
  if (qnext) qnext[((long)(b * PQ + p)) * 2 + co] = v;
}

__global__ void out_k(const float* __restrict__ CENT, const float* __restrict__ HMP,
                      void* __restrict__ out, const unsigned* __restrict__ FLAGS)
{
  int t = blockIdx.x * 256 + threadIdx.x;
  if (t >= 2 * 12 * PQ) return;
  int p = t % PQ; int r = t / PQ; int ch = r % 12; int b = r / 12;
  float v = (ch < 2) ? CENT[((long)(b * 2 + ch)) * PQ + p]
                     : HMP[((long)(b * 10 + ch - 2)) * PQ + p];
  if (FLAGS[0]) ((bf16*)out)[t] = __float2bfloat16(v);
  else          ((float*)out)[t] = v;
}

// ---------------------------------------------------------------------------
extern "C" void kernel_launch(void* const* d_in, const int* in_sizes, int n_in,
                              void* d_out, int out_size, void* d_ws, size_t ws_size,
                              hipStream_t stream)
{
  (void)n_in; (void)out_size; (void)ws_size;

  // ---- workspace layout (~80 MB, fp32 units; lifetime-aliased) ------------
  float* F = (float*)d_ws;
  size_t off = 0;
  // fp32 weight arena (inputs 2..41)
  int aoff[42];
  {
    size_t acc = 0;
    for (int i = 2; i < 42; i++) { aoff[i] = (int)acc; acc += (size_t)in_sizes[i]; }
    off = acc;
  }
  float* ARENA = F;
  float* LIDF = F + off;                        // [2][128][HW] fp32 (dead after gather)
  bf16*  KVT16 = (bf16*)(F + off);              // alias: [2][256][HW] bf16 (decoder)
  off += 8294400;
  float* HBUF = F + off;                        // [1][128][HW] fp32 (per-batch reuse)
  bf16*  KPET16 = (bf16*)(F + off);             // alias: [128][HW] bf16 (decoder)
  off += 4147200;
  bf16*  CAMF16 = (bf16*)(F + off);             // [2][128][HW] bf16 (live all run)
  off += 4147200;
  float* HEAT  = F + off;                       // [2][10][HW] (dead after nms)
  float* SCORE = F + off + 648000;              // (dead after collect)
  float* PART  = F + off;                       // alias: [2][8][NSPLIT][200][18]
  off += 1296000;
  float* X   = F + off; off += 51200;
  float* XQ  = F + off; off += 51200;
  float* QPE = F + off; off += 51200;
  float* T1Q = F + off; off += 51200;
  float* SQKV = F + off; off += 153600;
  float* SAO = F + off; off += 51200;
  float* PRE = F + off; off += 51200;
  float* QH2 = F + off; off += 51200;
  float* CAO = F + off; off += 51200;
  float* FF1 = F + off; off += 102400;
  float* YC  = F + off; off += 51200;
  float* CENT = F + off; off += 800;
  float* HMP = F + off; off += 4000;
  float* QPA = F + off; off += 800;
  float* QPB = F + off; off += 800;
  unsigned* U = (unsigned*)(F + off);
  unsigned* HIST  = U;                          // [0, 8192)
  unsigned* ACNT  = U + 8192;                   // 2
  unsigned* THR   = U + 8194;                   // 2
  unsigned* FLAGS = U + 8196;                   // 2 (NOT zeroed by zero_u32)
  unsigned* TOPC  = U + 8198;                   // 400
  unsigned* TOPI  = U + 8598;                   // 400
  unsigned long long* CAND = (unsigned long long*)(U + 9000); // 2*CAP u64

  auto W = [&](int i) -> const float* { return ARENA + aoff[i]; };

  // ---- dtype detect + weight conversion -----------------------------------
  detect_k<<<1, 256, 0, stream>>>((const unsigned*)d_in[0], FLAGS);
  {
    CvtArgs a;
    for (int i = 2; i < 42; i++) { a.src[i - 2] = d_in[i]; a.n[i - 2] = in_sizes[i]; a.off[i - 2] = aoff[i]; }
    cvt_k<<<dim3(432, 40), 256, 0, stream>>>(a, ARENA, FLAGS);
  }

  auto gemm = [&](const float* A, int lda, const float* Wp, const float* bias, int act,
                  const float* res, float* C, int ldc, int M, int N, int K) {
    dim3 grid((M + 63) / 64, (N + 63) / 64, 1);
    gemm_k<float, float><<<grid, 256, 0, stream>>>(
        A, (const float*)nullptr, lda, 0, 0L, Wp, bias, act, res,
        nullptr, nullptr, nullptr, nullptr, C, ldc, 0, 0L, M, N, K);
  };

  // ---- backbone convs -----------------------------------------------------
  convgemm2d<float><<<dim3(540, 2, 2), 256, 0, stream>>>(
      d_in[0], FLAGS, 0, (long)384 * HW, W(2), W(3), nullptr, nullptr, 0,
      LIDF, (long)128 * HW, 128, 384);
  convgemm2d<bf16><<<dim3(540, 2, 2), 256, 0, stream>>>(
      d_in[1], FLAGS, 0, (long)80 * HW, W(4), W(5), nullptr, nullptr, 0,
      CAMF16, (long)128 * HW, 128, 80);
  for (int b = 0; b < 2; b++) {
    convgemm2d<float><<<dim3(540, 2, 1), 256, 0, stream>>>(
        LIDF + (long)b * 128 * HW, FLAGS, 1, 0L, W(6), W(7), W(8), W(9), 1,
        HBUF, 0L, 128, 128);
    convgemm2d<float><<<dim3(540, 1, 1), 256, 0, stream>>>(
        HBUF, FLAGS, 1, 0L, W(10), W(11), nullptr, nullptr, 2,
        HEAT + (long)b * NCLS * HW, 0L, 10, 128);
  }

  // ---- NMS + exact top-200 ------------------------------------------------
  nms_k<<<(2 * NCLS * HW + 255) / 256, 256, 0, stream>>>(HEAT, SCORE);
  zero_u32<<<(8196 + 255) / 256, 256, 0, stream>>>(U, 8196);
  hist_k<<<dim3(240, 2), 256, 0, stream>>>(SCORE, HIST);
  thresh_k<<<2, 256, 0, stream>>>(HIST, THR);
  collect_k<<<(2 * NCLS * HW + 255) / 256, 256, 0, stream>>>(SCORE, THR, ACNT, CAND);
  select_k<<<2, 64, 0, stream>>>(CAND, ACNT, TOPC, TOPI, QPA);
  gather_k<<<200, 256, 0, stream>>>(LIDF, TOPC, TOPI, W(12), W(13), X);

  // ---- decoder layers -----------------------------------------------------
  for (int i = 0; i < 2; i++) {
    const float* qcur = (i == 0) ? QPA : QPB;
    float* qnext = (i == 0) ? QPB : QPA;
    // query pos-embed
    pe_stage1<<<200, 256, 0, stream>>>(qcur, W(14) + (i * 2 + 0) * 256,
        W(15) + (i * 2 + 0) * 128, W(16) + (i * 2 + 0) * 128, W(17) + (i * 2 + 0) * 128,
        T1Q, 400);
    gemm(T1Q, 128, W(18) + (size_t)(i * 2 + 0) * 16384, W(19) + (i * 2 + 0) * 128,
         0, nullptr, QPE, 128, 400, 128, 128);
    // key pos-embed (BEV grid fused into staging), stored transposed [128][HW] bf16
    gemm_k<float, bf16><<<dim3(507, 2, 1), 256, 0, stream>>>(
        ARENA, (const float*)nullptr, 0, 2, 0L,
        W(18) + (size_t)(i * 2 + 1) * 16384, W(19) + (i * 2 + 1) * 128, 0, nullptr,
        W(14) + (i * 2 + 1) * 256, W(15) + (i * 2 + 1) * 128,
        W(16) + (i * 2 + 1) * 128, W(17) + (i * 2 + 1) * 128,
        KPET16, HW, 1, 0L, 32400, 128, 128);
    // self-attention
    add2_k<<<200, 256, 0, stream>>>(X, QPE, XQ, 51200);
    gemm(XQ, 128, W(20) + (size_t)(i * 2 + 0) * 49152, W(21) + (i * 2 + 0) * 384,
         0, nullptr, SQKV, 384, 400, 384, 128);
    self_attn_k<<<dim3(200, 8, 2), 64, 0, stream>>>(SQKV, SAO);
    gemm(SAO, 128, W(22) + (size_t)(i * 2 + 0) * 16384, W(23) + (i * 2 + 0) * 128,
         0, X, PRE, 128, 400, 128, 128);
    ln_k<<<100, 256, 0, stream>>>(PRE, W(24) + (i * 3 + 0) * 128, W(25) + (i * 3 + 0) * 128, X);
    // cross-attention
    add2_k<<<200, 256, 0, stream>>>(X, QPE, XQ, 51200);
    gemm(XQ, 128, W(20) + (size_t)(i * 2 + 1) * 49152, W(21) + (i * 2 + 1) * 384,
         0, nullptr, QH2, 128, 400, 128, 128);
    gemm_k<bf16, bf16><<<dim3(507, 4, 2), 256, 0, stream>>>(
        CAMF16, KPET16, HW, 1, (long)128 * HW,
        W(20) + (size_t)(i * 2 + 1) * 49152 + 16384, W(21) + (i * 2 + 1) * 384 + 128,
        0, nullptr, nullptr, nullptr, nullptr, nullptr,
        KVT16, HW, 1, (long)256 * HW, 32400, 256, 128);
    flash_k<<<dim3(NSPLIT, 8, 2), 256, 0, stream>>>(QH2, KVT16, PART);
    combine_k<<<200, 256, 0, stream>>>(PART, CAO);
    gemm(CAO, 128, W(22) + (size_t)(i * 2 + 1) * 16384, W(23) + (i * 2 + 1) * 128,
         0, X, PRE, 128, 400, 128, 128);
    ln_k<<<100, 256, 0, stream>>>(PRE, W(24) + (i * 3 + 1) * 128, W(25) + (i * 3 + 1) * 128, X);
    // FFN
    gemm(X, 128, W(26) + (size_t)i * 32768, W(27) + i * 256,
         1, nullptr, FF1, 256, 400, 256, 128);
    gemm(FF1, 256, W(28) + (size_t)i * 32768, W(29) + i * 128,
         0, X, PRE, 128, 400, 128, 256);
    ln_k<<<100, 256, 0, stream>>>(PRE, W(24) + (i * 3 + 2) * 128, W(25) + (i * 3 + 2) * 128, X);
    // prediction heads
    conv1d_k<<<dim3(200, 2), 128, 0, stream>>>(X, W(30) + (size_t)i * 49152,
        W(31) + i * 128, W(32) + i * 128, W(33) + i * 128, YC);
    head2_k<<<4, 256, 0, stream>>>(YC, W(34) + (size_t)i * 768, W(35) + i * 2,
        qcur, CENT, 2, qnext);
    conv1d_k<<<dim3(200, 2), 128, 0, stream>>>(X, W(36) + (size_t)i * 49152,
        W(37) + i * 128, W(38) + i * 128, W(39) + i * 128, YC);
    head2_k<<<16, 256, 0, stream>>>(YC, W(40) + (size_t)i * 3840, W(41) + i * 10,
        nullptr, HMP, 10, nullptr);
  }
  out_k<<<19, 256, 0, stream>>>(CENT, HMP, d_out, FLAGS);
}

// Round 6
// 3283.321 us; speedup vs baseline: 1.6778x; 1.6778x over previous
//
#include <hip/hip_runtime.h>
#include <hip/hip_bf16.h>

typedef __hip_bfloat16 bf16;
typedef _Float16 f16;

#define HW 32400
#define NCLS 10
#define PQ 200
#define HIDDEN 128
#define NSPLIT 20
#define SPLITLEN 1620   // 20*1620 = 32400 exactly
#define CAP 6144
#define NBIN 4096

typedef __attribute__((ext_vector_type(8))) _Float16 half8;
typedef __attribute__((ext_vector_type(4))) short short4v;
typedef __attribute__((ext_vector_type(4))) float f32x4;

__device__ __forceinline__ float b2f(bf16 v) { return __bfloat162float(v); }
__device__ __forceinline__ void stf(float* p, float v) { *p = v; }
__device__ __forceinline__ void stf(bf16* p, float v) { *p = __float2bfloat16(v); }
// runtime-dtype load: isbf!=0 -> bf16 array, else fp32 array
__device__ __forceinline__ float ldsel(const void* p, long i, unsigned isbf) {
  return isbf ? __bfloat162float(((const bf16*)p)[i]) : ((const float*)p)[i];
}
__device__ __forceinline__ float ldf(const float* p, long i) { return p[i]; }
__device__ __forceinline__ float ldf(const bf16* p, long i) { return __bfloat162float(p[i]); }
__device__ __forceinline__ short f2bf_bits(float v) {
  union { bf16 h; short s; } u; u.h = __float2bfloat16(v); return u.s;
}

// ---------------------------------------------------------------------------
// dtype detection (bf16 vs fp32 inputs) -> FLAGS[0]
// ---------------------------------------------------------------------------
__global__ void detect_k(const unsigned* __restrict__ L, unsigned* __restrict__ FLAGS)
{
  __shared__ unsigned cnt[2];
  int tid = threadIdx.x;
  if (tid < 2) cnt[tid] = 0;
  __syncthreads();
  unsigned nz = 0, pl = 0;
  for (int w = tid; w < 4096; w += 256) {
    unsigned u = L[w];
    if (u) {
      nz++;
      unsigned e = (u >> 7) & 0xFF;
      if (e >= 110 && e <= 140) pl++;
    }
  }
  atomicAdd(&cnt[0], nz);
  atomicAdd(&cnt[1], pl);
  __syncthreads();
  if (tid == 0) {
    FLAGS[0] = (2u * cnt[1] > cnt[0]) ? 1u : 0u;
    FLAGS[1] = 0u;
  }
}

// batched weight conversion into fp32 arena (exact in both modes)
struct CvtArgs { const void* src[40]; int n[40]; int off[40]; };
__global__ __launch_bounds__(256) void cvt_k(CvtArgs a, float* __restrict__ dst,
                                             const unsigned* __restrict__ FLAGS)
{
  int j = blockIdx.y;
  unsigned isbf = FLAGS[0];
  int n = a.n[j];
  const void* s = a.src[j];
  float* d = dst + a.off[j];
  for (int t = blockIdx.x * 256 + threadIdx.x; t < n; t += gridDim.x * 256)
    d[t] = ldsel(s, t, isbf);
}

// ---------------------------------------------------------------------------
// Conv weight pre-swizzle into MFMA fragment order, fp16 hi (+scaled lo).
// WB[plane][tap][kb][nt][n16][k32] ; value = W[nt*16+n16][kb*32+k][ty][tx]
// plane1 = fp16((v - hi) * 4096)  (scale keeps lo in fp16 normal range)
// ---------------------------------------------------------------------------
__global__ __launch_bounds__(256) void wprep_k(const float* __restrict__ Wsrc,
    f16* __restrict__ WB, int N, int K, int KB, int NTG, int split)
{
  long total = (long)(split ? 2 : 1) * 9 * KB * NTG * 512;
  for (long t = (long)blockIdx.x * 256 + threadIdx.x; t < total;
       t += (long)gridDim.x * 256) {
    long r = t;
    int k = (int)(r & 31); r >>= 5;
    int n16 = (int)(r & 15); r >>= 4;
    int nt = (int)(r % NTG); r /= NTG;
    int kb = (int)(r % KB); r /= KB;
    int tap = (int)(r % 9); r /= 9;
    int plane = (int)r;
    int n = nt * 16 + n16, kk = kb * 32 + k;
    float v = 0.f;
    if (n < N && kk < K) v = Wsrc[((long)n * K + kk) * 9 + tap];
    f16 h = (f16)v;
    f16 outv = h;
    if (plane == 1) outv = (f16)((v - (float)h) * 4096.0f);
    WB[t] = outv;
  }
}

// ---------------------------------------------------------------------------
// MFMA conv2d 3x3 SAME as 9 shifted GEMMs over 64-pixel row chunks (60 valid).
// SPLIT=3: fp32-accurate fp16 split: acc = Σhi·hi' + (Σ(lo·hi'+hi·lo'))/4096,
// lo pre-scaled by 4096 (fp16-normal). SPLIT=1: plain fp16.
// Wave grid: WM x WN waves; wave does MT m-tiles (16 px) x NT n-tiles (16 och).
// Layouts (verified m89/m92/m120): A[m=lane&15][k=(lane>>4)*8+j],
// B[k][n=lane&15] same k-grouping, C/D col=lane&15 row=(lane>>4)*4+reg.
// ---------------------------------------------------------------------------
template <int SPLIT, int WM, int WN, int MT, int NT, typename CT>
__global__ __launch_bounds__(256) void conv_mfma(
    const void* __restrict__ A, const unsigned* __restrict__ FLAGS, int dyn,
    long abatch,
    const f16* __restrict__ WB, const float* __restrict__ bias,
    const float* __restrict__ g, const float* __restrict__ beta, int act,
    CT* __restrict__ C, long cbatch, int N, int K, int KB, int NTG)
{
  constexpr int AW = 3 * 66 * 40;            // [ty][px][k] k-stride 40 (bank spread)
  __shared__ __align__(16) f16 Ah[AW];
  __shared__ __align__(16) f16 Al[SPLIT == 3 ? AW : 8];
  unsigned isbf = dyn ? FLAGS[0] : 0u;
  int bz = blockIdx.z;
  int y = blockIdx.x / 3;
  int x0 = (blockIdx.x % 3) * 60;
  int tid = threadIdx.x;
  int w = tid >> 6, lane = tid & 63;
  int lane15 = lane & 15, lgrp = lane >> 4;
  int wm = w % WM, wn = w / WM;
  int mbase = wm * MT * 16;
  int nbase = wn * NT * 16;
  f32x4 accM[MT][NT] = {};
  f32x4 accC[SPLIT == 3 ? MT : 1][SPLIT == 3 ? NT : 1] = {};
  long planeStride = (long)9 * KB * NTG * 512;

  for (int kb = 0; kb < KB; kb++) {
    __syncthreads();
    // stage A tile (3 rows x 66 px x 32 chan) as fp16 hi (+scaled lo)
    for (int e = tid; e < 3 * 32 * 66; e += 256) {
      int row = e / (32 * 66);
      int rem = e - row * (32 * 66);
      int k = rem / 66;
      int px = rem - k * 66;
      int gx = x0 + px - 1, gy = y + row - 1;
      int kk = kb * 32 + k;
      float v = 0.f;
      if (gx >= 0 && gx < 180 && gy >= 0 && gy < 180 && kk < K)
        v = ldsel(A, (long)bz * abatch + (long)kk * HW + gy * 180 + gx, isbf);
      f16 h = (f16)v;
      Ah[(row * 66 + px) * 40 + k] = h;
      if constexpr (SPLIT == 3)
        Al[(row * 66 + px) * 40 + k] = (f16)((v - (float)h) * 4096.0f);
    }
    __syncthreads();
#pragma unroll
    for (int tap = 0; tap < 9; tap++) {
      int ty = tap / 3, tx = tap % 3;
      const f16* wb = WB + (((long)tap * KB + kb) * NTG) * 512;
      half8 bh[NT], bl[SPLIT == 3 ? NT : 1];
#pragma unroll
      for (int nt = 0; nt < NT; nt++) {
        long o = (long)(wn * NT + nt) * 512 + lane15 * 32 + lgrp * 8;
        bh[nt] = *(const half8*)(wb + o);
        if constexpr (SPLIT == 3) bl[nt] = *(const half8*)(wb + planeStride + o);
      }
      half8 ah[MT], al[SPLIT == 3 ? MT : 1];
#pragma unroll
      for (int mt = 0; mt < MT; mt++) {
        int px = mbase + mt * 16 + lane15 + tx;
        int o = (ty * 66 + px) * 40 + lgrp * 8;
        ah[mt] = *(const half8*)&Ah[o];
        if constexpr (SPLIT == 3) al[mt] = *(const half8*)&Al[o];
      }
#pragma unroll
      for (int mt = 0; mt < MT; mt++)
#pragma unroll
        for (int nt = 0; nt < NT; nt++) {
          accM[mt][nt] = __builtin_amdgcn_mfma_f32_16x16x32_f16(
              ah[mt], bh[nt], accM[mt][nt], 0, 0, 0);
          if constexpr (SPLIT == 3) {
            accC[mt][nt] = __builtin_amdgcn_mfma_f32_16x16x32_f16(
                al[mt], bh[nt], accC[mt][nt], 0, 0, 0);
            accC[mt][nt] = __builtin_amdgcn_mfma_f32_16x16x32_f16(
                ah[mt], bl[nt], accC[mt][nt], 0, 0, 0);
          }
        }
    }
  }
  // epilogue
  int pixbase = y * 180 + x0;
#pragma unroll
  for (int mt = 0; mt < MT; mt++) {
    int m = mbase + mt * 16 + lgrp * 4;
    if (m >= 60) continue;
#pragma unroll
    for (int nt = 0; nt < NT; nt++) {
      int n = nbase + nt * 16 + lane15;
      if (n >= N) continue;
      float bi = bias[n];
      float gg = g ? g[n] : 1.f;
      float bb = g ? beta[n] : 0.f;
      long base = (long)bz * cbatch + (long)n * HW + pixbase + m;
      if constexpr (sizeof(CT) == 4) {
        f32x4 ov;
#pragma unroll
        for (int r = 0; r < 4; r++) {
          float v = accM[mt][nt][r];
          if constexpr (SPLIT == 3) v += accC[mt][nt][r] * (1.f / 4096.f);
          v += bi;
          if (g) v = v * gg + bb;
          if (act == 1) v = fmaxf(v, 0.f);
          else if (act == 2) v = 1.f / (1.f + expf(-v));
          ov[r] = v;
        }
        *(f32x4*)&C[base] = ov;
      } else {
        short4v ov;
#pragma unroll
        for (int r = 0; r < 4; r++) {
          float v = accM[mt][nt][r];
          if constexpr (SPLIT == 3) v += accC[mt][nt][r] * (1.f / 4096.f);
          v += bi;
          if (g) v = v * gg + bb;
          if (act == 1) v = fmaxf(v, 0.f);
          ov[r] = f2bf_bits(v);
        }
        *(short4v*)&C[base] = ov;
      }
    }
  }
}

// ---------------------------------------------------------------------------
// Generic tiled GEMM: C = act(A @ W^T + bias) (+ res)
// amode 0: A[m*lda+k].  amode 1: A[k*lda+m] (+A2 same layout, un-batched).
// amode 2: A[m][k] = relu((p0*pe1w[2k]+p1*pe1w[2k+1]+pe1b[k])*pe1g[k]+pe1bt[k])
// cmode 0: C[m*ldc+n] ; cmode 1: C[n*ldc+m].  K multiple of 16.
// ---------------------------------------------------------------------------
template <typename AT, typename CT>
__global__ __launch_bounds__(256) void gemm_k(
    const AT* __restrict__ A, const AT* __restrict__ A2, int lda, int amode,
    long abatch,
    const float* __restrict__ W, const float* __restrict__ bias, int act,
    const float* __restrict__ res,
    const float* __restrict__ pe1w, const float* __restrict__ pe1b,
    const float* __restrict__ pe1g, const float* __restrict__ pe1bt,
    CT* __restrict__ C, int ldc, int cmode, long cbatch,
    int M, int N, int K)
{
  __shared__ __align__(16) float As[16][68];
  __shared__ __align__(16) float Ws[16][68];
  int b = blockIdx.z;
  int m0 = blockIdx.x * 64, n0 = blockIdx.y * 64;
  int tid = threadIdx.x;
  int nt = tid & 15, mt = tid >> 4;
  float acc[4][4] = {};
  const AT* Ab = A + (long)b * abatch;
  for (int k0 = 0; k0 < K; k0 += 16) {
    if (amode == 0) {
      for (int e = tid; e < 1024; e += 256) {
        int m = e >> 4, k = e & 15;
        float v = 0.f;
        if (m0 + m < M) v = ldf(Ab, (long)(m0 + m) * lda + k0 + k);
        As[k][m] = v;
      }
    } else if (amode == 1) {
      for (int e = tid; e < 1024; e += 256) {
        int m = e & 63, k = e >> 6;
        float v = 0.f;
        if (m0 + m < M) {
          long idx = (long)(k0 + k) * lda + m0 + m;
          v = ldf(Ab, idx);
          if (A2) v += ldf(A2, idx);
        }
        As[k][m] = v;
      }
    } else {
      for (int e = tid; e < 1024; e += 256) {
        int m = e & 63, k = e >> 6;
        float v = 0.f;
        int gm = m0 + m;
        if (gm < M) {
          float p0 = (float)(gm / 180) + 0.5f;
          float p1 = (float)(gm % 180) + 0.5f;
          int kk = k0 + k;
          float t = p0 * pe1w[kk * 2] + p1 * pe1w[kk * 2 + 1] + pe1b[kk];
          t = t * pe1g[kk] + pe1bt[kk];
          v = fmaxf(t, 0.f);
        }
        As[k][m] = v;
      }
    }
    for (int e = tid; e < 1024; e += 256) {
      int n = e >> 4, k = e & 15;
      float v = 0.f;
      if (n0 + n < N) v = W[(long)(n0 + n) * K + k0 + k];
      Ws[k][n] = v;
    }
    __syncthreads();
#pragma unroll
    for (int kk = 0; kk < 16; kk++) {
      float4 av = *(const float4*)&As[kk][mt * 4];
      float4 wv = *(const float4*)&Ws[kk][nt * 4];
      float am[4] = {av.x, av.y, av.z, av.w};
      float wn[4] = {wv.x, wv.y, wv.z, wv.w};
#pragma unroll
      for (int mi = 0; mi < 4; mi++)
#pragma unroll
        for (int ni = 0; ni < 4; ni++)
          acc[mi][ni] = fmaf(am[mi], wn[ni], acc[mi][ni]);
    }
    __syncthreads();
  }
#pragma unroll
  for (int mi = 0; mi < 4; mi++) {
    int m = m0 + mt * 4 + mi;
    if (m >= M) continue;
#pragma unroll
    for (int ni = 0; ni < 4; ni++) {
      int n = n0 + nt * 4 + ni;
      if (n >= N) continue;
      float v = acc[mi][ni];
      if (bias) v += bias[n];
      if (act == 1) v = fmaxf(v, 0.f);
      if (res) v += res[(long)m * ldc + n];
      long ci = (cmode == 0) ? ((long)b * cbatch + (long)m * ldc + n)
                             : ((long)b * cbatch + (long)n * ldc + m);
      stf(&C[ci], v);
    }
  }
}

// ---------------------------------------------------------------------------
__global__ void nms_k(const float* __restrict__ HEAT, float* __restrict__ SCORE)
{
  int t = blockIdx.x * 256 + threadIdx.x;
  if (t >= 2 * NCLS * HW) return;
  int b = t / (NCLS * HW); int r = t % (NCLS * HW);
  int cls = r / HW; int n = r % HW;
  const float* hb = HEAT + ((long)(b * NCLS + cls)) * HW;
  float v = hb[n];
  bool keep = true;
  if (cls < 8) {
    int y = n / 180, x = n % 180;
    if (y == 0 || y == 179 || x == 0 || x == 179) keep = false;
    else {
      float mx = -1e30f;
#pragma unroll
      for (int dy = -1; dy <= 1; dy++)
#pragma unroll
        for (int dx = -1; dx <= 1; dx++)
          mx = fmaxf(mx, hb[(y + dy) * 180 + x + dx]);
      keep = (v == mx);
    }
  }
  SCORE[(long)b * (NCLS * HW) + r] = keep ? v : 0.f;
}

__global__ void zero_u32(unsigned* p, int n)
{
  int t = blockIdx.x * 256 + threadIdx.x;
  if (t < n) p[t] = 0;
}

__global__ __launch_bounds__(256) void hist_k(const float* __restrict__ SCORE,
                                              unsigned* __restrict__ HIST)
{
  __shared__ unsigned lh[NBIN];
  int b = blockIdx.y;
  for (int e = threadIdx.x; e < NBIN; e += 256) lh[e] = 0;
  __syncthreads();
  int start = blockIdx.x * 1350;
  const float* sb = SCORE + (long)b * (NCLS * HW);
  for (int e = start + threadIdx.x; e < start + 1350; e += 256) {
    unsigned bits = __float_as_uint(sb[e]);
    atomicAdd(&lh[bits >> 18], 1u);
  }
  __syncthreads();
  for (int e = threadIdx.x; e < NBIN; e += 256) {
    unsigned c = lh[e];
    if (c) atomicAdd(&HIST[b * NBIN + e], c);
  }
}

__global__ void thresh_k(const unsigned* __restrict__ HIST, unsigned* __restrict__ THR)
{
  __shared__ unsigned ps[256];
  int b = blockIdx.x;
  const unsigned* hb = HIST + b * NBIN;
  unsigned s = 0;
  for (int j = 0; j < 16; j++) s += hb[threadIdx.x * 16 + j];
  ps[threadIdx.x] = s;
  __syncthreads();
  if (threadIdx.x == 0) {
    unsigned cum = 0; int t = 255;
    for (; t > 0; t--) { if (cum + ps[t] >= PQ) break; cum += ps[t]; }
    int bin = t * 16 + 15;
    for (; bin > t * 16; bin--) { unsigned c = hb[bin]; if (cum + c >= PQ) break; cum += c; }
    if (bin < 1) bin = 1;
    THR[b] = (unsigned)bin;
  }
}

__global__ void collect_k(const float* __restrict__ SCORE, const unsigned* __restrict__ THR,
                          unsigned* __restrict__ ACNT, unsigned long long* __restrict__ CAND)
{
  int t = blockIdx.x * 256 + threadIdx.x;
  if (t >= 2 * NCLS * HW) return;
  int b = t / (NCLS * HW); int r = t % (NCLS * HW);
  float v = SCORE[(long)b * (NCLS * HW) + r];
  unsigned bits = __float_as_uint(v);
  if ((bits >> 18) >= THR[b]) {
    unsigned slot = atomicAdd(&ACNT[b], 1u);
    if (slot < CAP) CAND[(long)b * CAP + slot] =
        ((unsigned long long)bits << 32) | (unsigned)(~r);
  }
}

__global__ __launch_bounds__(64) void select_k(
    const unsigned long long* __restrict__ CAND, const unsigned* __restrict__ ACNT,
    unsigned* __restrict__ TOPC, unsigned* __restrict__ TOPI, float* __restrict__ QPA)
{
  __shared__ unsigned long long cnd[CAP];
  int b = blockIdx.x;
  int lane = threadIdx.x;
  unsigned cnt = ACNT[b]; if (cnt > CAP) cnt = CAP;
  for (int e = lane; e < (int)cnt; e += 64) cnd[e] = CAND[(long)b * CAP + e];
  __syncthreads();
  for (int p = 0; p < PQ; p++) {
    unsigned long long best = 0;
    for (int e = lane; e < (int)cnt; e += 64) { unsigned long long c = cnd[e]; if (c > best) best = c; }
#pragma unroll
    for (int o = 32; o; o >>= 1) {
      unsigned long long other = __shfl_xor(best, o, 64);
      if (other > best) best = other;
    }
    for (int e = lane; e < (int)cnt; e += 64) if (best != 0 && cnd[e] == best) cnd[e] = 0;
    if (lane == 0) {
      unsigned idx = (best == 0) ? 0u : ~(unsigned)(best & 0xFFFFFFFFull);
      if (idx >= NCLS * HW) idx = 0;
      unsigned cls = idx / HW, n = idx % HW;
      TOPC[b * PQ + p] = cls; TOPI[b * PQ + p] = n;
      QPA[((long)(b * PQ + p)) * 2 + 0] = (float)(n / 180) + 0.5f;
      QPA[((long)(b * PQ + p)) * 2 + 1] = (float)(n % 180) + 0.5f;
    }
    __syncthreads();
  }
}

__global__ void gather_k(const float* __restrict__ LIDF, const unsigned* __restrict__ TOPC,
                         const unsigned* __restrict__ TOPI, const float* __restrict__ cew,
                         const float* __restrict__ ceb, float* __restrict__ X)
{
  int t = blockIdx.x * 256 + threadIdx.x;
  if (t >= 2 * PQ * HIDDEN) return;
  int c = t & 127; int r = t >> 7; int p = r % PQ; int b = r / PQ;
  unsigned n = TOPI[b * PQ + p]; unsigned cls = TOPC[b * PQ + p];
  if (n >= HW) n = 0;
  if (cls >= NCLS) cls = 0;
  X[t] = LIDF[((long)(b * HIDDEN + c)) * HW + n] + cew[c * NCLS + cls] + ceb[c];
}

// posembed stage 1 for queries only
__global__ void pe_stage1(const float* __restrict__ qpos,
                          const float* __restrict__ w1, const float* __restrict__ b1,
                          const float* __restrict__ g, const float* __restrict__ bt,
                          float* __restrict__ T1, int M)
{
  int t = blockIdx.x * 256 + threadIdx.x;
  if (t >= M * HIDDEN) return;
  int c = t & 127; int m = t >> 7;
  float p0 = qpos[m * 2], p1 = qpos[m * 2 + 1];
  float v = p0 * w1[c * 2] + p1 * w1[c * 2 + 1] + b1[c];
  v = v * g[c] + bt[c];
  T1[t] = fmaxf(v, 0.f);
}

__global__ void add2_k(const float* __restrict__ a, const float* __restrict__ b,
                       float* __restrict__ o, int n)
{
  int t = blockIdx.x * 256 + threadIdx.x;
  if (t < n) o[t] = a[t] + b[t];
}

__global__ __launch_bounds__(64) void self_attn_k(const float* __restrict__ SQKV,
                                                  float* __restrict__ SAO)
{
  int q = blockIdx.x, h = blockIdx.y, b = blockIdx.z;
  int lane = threadIdx.x;
  const float* qp = SQKV + ((long)(b * PQ + q)) * 384 + h * 16;
  float qv[16];
#pragma unroll
  for (int d = 0; d < 16; d++) qv[d] = qp[d] * 0.25f;
  float sv[4]; int kks[4]; int nk = 0;
  float lmax = -1e30f;
  for (int kk = lane; kk < PQ; kk += 64) {
    const float* kp = SQKV + ((long)(b * PQ + kk)) * 384 + 128 + h * 16;
    float s = 0.f;
#pragma unroll
    for (int d = 0; d < 16; d++) s = fmaf(qv[d], kp[d], s);
    sv[nk] = s; kks[nk] = kk; nk++;
    lmax = fmaxf(lmax, s);
  }
#pragma unroll
  for (int o = 32; o; o >>= 1) lmax = fmaxf(lmax, __shfl_xor(lmax, o, 64));
  float lsum = 0.f; float acc[16] = {};
  for (int t = 0; t < nk; t++) {
    float p = expf(sv[t] - lmax);
    lsum += p;
    const float* vp = SQKV + ((long)(b * PQ + kks[t])) * 384 + 256 + h * 16;
#pragma unroll
    for (int d = 0; d < 16; d++) acc[d] = fmaf(p, vp[d], acc[d]);
  }
#pragma unroll
  for (int o = 32; o; o >>= 1) lsum += __shfl_xor(lsum, o, 64);
#pragma unroll
  for (int d = 0; d < 16; d++) {
    float v = acc[d];
#pragma unroll
    for (int o = 32; o; o >>= 1) v += __shfl_xor(v, o, 64);
    if (lane == 0) SAO[((long)(b * PQ + q)) * HIDDEN + h * 16 + d] = v / lsum;
  }
}

// flash cross-attention, key-split. QH [400][128] fp32, KVT [B][256][HW] bf16.
// PART [B][8][NSPLIT][200][18] = o[16], m, l
__global__ __launch_bounds__(256) void flash_k(const float* __restrict__ QH,
                                               const bf16* __restrict__ KVT,
                                               float* __restrict__ PART)
{
  int s = blockIdx.x, h = blockIdx.y, b = blockIdx.z;
  int tid = threadIdx.x;
  __shared__ __align__(16) float qL[PQ][16];
  __shared__ __align__(16) float oL[PQ][16];
  __shared__ float mL[PQ], lL[PQ];
  __shared__ __align__(16) float kjL[32][16];
  __shared__ __align__(16) float vjL[32][16];
  __shared__ float sL[PQ][32];
  for (int e = tid; e < PQ * 16; e += 256) {
    int q = e >> 4, d = e & 15;
    qL[q][d] = QH[((long)(b * PQ + q)) * HIDDEN + h * 16 + d] * 0.25f;
    oL[q][d] = 0.f;
  }
  if (tid < PQ) { mL[tid] = -1e30f; lL[tid] = 0.f; }
  __syncthreads();
  int nbeg = s * SPLITLEN, nend = nbeg + SPLITLEN;
  const bf16* Kb = KVT + (long)b * 256 * HW + (long)(h * 16) * HW;
  const bf16* Vb = Kb + (long)128 * HW;
  for (int n0 = nbeg; n0 < nend; n0 += 32) {
    int rem = nend - n0;
    for (int e = tid; e < 512; e += 256) {
      int j = e & 31, d = e >> 5;
      float kv = 0.f, vv = 0.f;
      if (j < rem) { kv = b2f(Kb[(long)d * HW + n0 + j]); vv = b2f(Vb[(long)d * HW + n0 + j]); }
      kjL[j][d] = kv; vjL[j][d] = vv;
    }
    __syncthreads();
    {
      int j = tid & 31, qg = tid >> 5;
      float kr[16];
#pragma unroll
      for (int d4 = 0; d4 < 4; d4++) {
        float4 t = *(const float4*)&kjL[j][d4 * 4];
        kr[d4 * 4 + 0] = t.x; kr[d4 * 4 + 1] = t.y; kr[d4 * 4 + 2] = t.z; kr[d4 * 4 + 3] = t.w;
      }
      bool valid = j < rem;
      for (int q = qg; q < PQ; q += 8) {
        float sd = 0.f;
#pragma unroll
        for (int d4 = 0; d4 < 4; d4++) {
          float4 t = *(const float4*)&qL[q][d4 * 4];
          sd = fmaf(t.x, kr[d4 * 4 + 0], sd);
          sd = fmaf(t.y, kr[d4 * 4 + 1], sd);
          sd = fmaf(t.z, kr[d4 * 4 + 2], sd);
          sd = fmaf(t.w, kr[d4 * 4 + 3], sd);
        }
        sL[q][j] = valid ? sd : -1e30f;
      }
    }
    __syncthreads();
    if (tid < PQ) {
      int q = tid;
      float mold = mL[q];
      float mnew = mold;
      for (int j = 0; j < 32; j++) mnew = fmaxf(mnew, sL[q][j]);
      float alpha = expf(mold - mnew);
      float lsum = 0.f;
      for (int j = 0; j < 32; j++) {
        float p = expf(sL[q][j] - mnew);
        sL[q][j] = p;
        lsum += p;
      }
      lL[q] = lL[q] * alpha + lsum;
      mL[q] = mnew;
      float o[16];
#pragma unroll
      for (int d4 = 0; d4 < 4; d4++) {
        float4 t = *(const float4*)&oL[q][d4 * 4];
        o[d4 * 4 + 0] = t.x * alpha; o[d4 * 4 + 1] = t.y * alpha;
        o[d4 * 4 + 2] = t.z * alpha; o[d4 * 4 + 3] = t.w * alpha;
      }
      for (int j = 0; j < 32; j++) {
        float p = sL[q][j];
#pragma unroll
        for (int d4 = 0; d4 < 4; d4++) {
          float4 t = *(const float4*)&vjL[j][d4 * 4];
          o[d4 * 4 + 0] = fmaf(p, t.x, o[d4 * 4 + 0]);
          o[d4 * 4 + 1] = fmaf(p, t.y, o[d4 * 4 + 1]);
          o[d4 * 4 + 2] = fmaf(p, t.z, o[d4 * 4 + 2]);
          o[d4 * 4 + 3] = fmaf(p, t.w, o[d4 * 4 + 3]);
        }
      }
#pragma unroll
      for (int d = 0; d < 16; d++) oL[q][d] = o[d];
    }
    __syncthreads();
  }
  long base = ((((long)(b * 8 + h)) * NSPLIT + s) * PQ) * 18;
  for (int e = tid; e < PQ * 18; e += 256) {
    int q = e / 18, d = e - q * 18;
    float v;
    if (d < 16) v = oL[q][d];
    else if (d == 16) v = mL[q];
    else v = lL[q];
    PART[base + (long)q * 18 + d] = v;
  }
}

__global__ void combine_k(const float* __restrict__ PART, float* __restrict__ CAO)
{
  int t = blockIdx.x * 256 + threadIdx.x;
  if (t >= 2 * 8 * PQ * 16) return;
  int d = t & 15; int r = t >> 4;
  int q = r % PQ; r /= PQ;
  int h = r & 7; int b = r >> 3;
  long base = (((long)(b * 8 + h)) * NSPLIT) * PQ * 18 + (long)q * 18;
  float M = -1e30f;
  for (int s = 0; s < NSPLIT; s++) M = fmaxf(M, PART[base + (long)s * PQ * 18 + 16]);
  float L = 0.f, O = 0.f;
  for (int s = 0; s < NSPLIT; s++) {
    long p0 = base + (long)s * PQ * 18;
    float w = expf(PART[p0 + 16] - M);
    L += PART[p0 + 17] * w;
    O += PART[p0 + d] * w;
  }
  CAO[((long)(b * PQ + q)) * HIDDEN + h * 16 + d] = (L > 0.f) ? O / L : 0.f;
}

__global__ __launch_bounds__(256) void ln_k(const float* __restrict__ PRE,
                                            const float* __restrict__ g,
                                            const float* __restrict__ bta,
                                            float* __restrict__ X)
{
  int row = blockIdx.x * 4 + (threadIdx.x >> 6);
  int lane = threadIdx.x & 63;
  const float* p = PRE + (long)row * HIDDEN;
  float v0 = p[lane], v1 = p[lane + 64];
  float s = v0 + v1;
#pragma unroll
  for (int o = 32; o; o >>= 1) s += __shfl_xor(s, o, 64);
  float mu = s * (1.f / 128.f);
  float d0 = v0 - mu, d1 = v1 - mu;
  float vs = d0 * d0 + d1 * d1;
#pragma unroll
  for (int o = 32; o; o >>= 1) vs += __shfl_xor(vs, o, 64);
  float rs = rsqrtf(vs * (1.f / 128.f) + 1e-5f);
  float* xo = X + (long)row * HIDDEN;
  xo[lane] = d0 * rs * g[lane] + bta[lane];
  xo[lane + 64] = d1 * rs * g[lane + 64] + bta[lane + 64];
}

__global__ __launch_bounds__(128) void conv1d_k(const float* __restrict__ X,
                                                const float* __restrict__ w,
                                                const float* __restrict__ bias,
                                                const float* __restrict__ g,
                                                const float* __restrict__ beta,
                                                float* __restrict__ Y)
{
  int p = blockIdx.x, b = blockIdx.y;
  int co = threadIdx.x;
  __shared__ float xs[3][HIDDEN];
  for (int e = co; e < 3 * HIDDEN; e += HIDDEN) {
    int t = e >> 7, c = e & 127;
    int pp = p + t - 1;
    xs[t][c] = (pp >= 0 && pp < PQ) ? X[((long)(b * PQ + pp)) * HIDDEN + c] : 0.f;
  }
  __syncthreads();
  const float* wr = w + (long)co * HIDDEN * 3;
  float acc = 0.f;
  for (int c = 0; c < HIDDEN; c++) {
    acc = fmaf(xs[0][c], wr[c * 3 + 0], acc);
    acc = fmaf(xs[1][c], wr[c * 3 + 1], acc);
    acc = fmaf(xs[2][c], wr[c * 3 + 2], acc);
  }
  float v = (acc + bias[co]) * g[co] + beta[co];
  Y[((long)(b * PQ + p)) * HIDDEN + co] = fmaxf(v, 0.f);
}

__global__ void head2_k(const float* __restrict__ Y, const float* __restrict__ w,
                        const float* __restrict__ bias, const float* __restrict__ qpos,
                        float* __restrict__ OUT, int N, float* __restrict__ qnext)
{
  int t = blockIdx.x * 256 + threadIdx.x;
  if (t >= 2 * N * PQ) return;
  int p = t % PQ; int r = t / PQ; int co = r % N; int b = r / N;
  const float* wr = w + (long)co * HIDDEN * 3;
  float acc = 0.f;
  for (int tap = 0; tap < 3; tap++) {
    int pp = p + tap - 1;
    if (pp < 0 || pp >= PQ) continue;
    const float* yr = Y + ((long)(b * PQ + pp)) * HIDDEN;
    for (int c = 0; c < HIDDEN; c++)
      acc = fmaf(yr[c], wr[c * 3 + tap], acc);
  }
  float v = acc + bias[co];
  if (qpos) v += qpos[((long)(b * PQ + p)) * 2 + co];
  OUT[((long)(b * N + co)) * PQ + p] = v;
  if (qnext) qnext[((long)(b * PQ + p)) * 2 + co] = v;
}

__global__ void out_k(const float* __restrict__ CENT, const float* __restrict__ HMP,
                      void* __restrict__ out, const unsigned* __restrict__ FLAGS)
{
  int t = blockIdx.x * 256 + threadIdx.x;
  if (t >= 2 * 12 * PQ) return;
  int p = t % PQ; int r = t / PQ; int ch = r % 12; int b = r / 12;
  float v = (ch < 2) ? CENT[((long)(b * 2 + ch)) * PQ + p]
                     : HMP[((long)(b * 10 + ch - 2)) * PQ + p];
  if (FLAGS[0]) ((bf16*)out)[t] = __float2bfloat16(v);
  else          ((float*)out)[t] = v;
}

// ---------------------------------------------------------------------------
extern "C" void kernel_launch(void* const* d_in, const int* in_sizes, int n_in,
                              void* d_out, int out_size, void* d_ws, size_t ws_size,
                              hipStream_t stream)
{
  (void)n_in; (void)out_size; (void)ws_size;

  // ---- workspace layout (~80 MB == R3's validated watermark) --------------
  float* F = (float*)d_ws;
  size_t off = 0;
  int aoff[42];
  {
    size_t acc = 0;
    for (int i = 2; i < 42; i++) { aoff[i] = (int)acc; acc += (size_t)in_sizes[i]; }
    off = acc;
  }
  float* ARENA = F;
  float* LIDF = F + off;                        // [2][128][HW] fp32 (dead after gather)
  bf16*  KVT16 = (bf16*)(F + off);              // alias: [2][256][HW] bf16 (decoder)
  off += 8294400;
  float* HBUF = F + off;                        // [1][128][HW] fp32 (per-batch reuse)
  bf16*  KPET16 = (bf16*)(F + off);             // alias: [128][HW] bf16 (decoder)
  off += 4147200;
  bf16*  CAMF16 = (bf16*)(F + off);             // [2][128][HW] bf16 (live all run)
  off += 4147200;
  float* HEAT  = F + off;                       // [2][10][HW] (dead after nms)
  float* SCORE = F + off + 648000;              // (dead after collect)
  float* PART  = F + off;                       // alias: [2][8][NSPLIT][200][18]
  off += 1296000;
  float* X   = F + off; off += 51200;           // decoder smalls — all dead during
  float* XQ  = F + off; off += 51200;           // convs; WB_* aliases this region
  float* QPE = F + off; off += 51200;
  float* T1Q = F + off; off += 51200;
  float* SQKV = F + off; off += 153600;
  float* SAO = F + off; off += 51200;
  float* PRE = F + off; off += 51200;
  float* QH2 = F + off; off += 51200;
  float* CAO = F + off; off += 51200;
  float* FF1 = F + off; off += 102400;
  float* YC  = F + off; off += 51200;           // X..YC span = 716800 floats
  float* CENT = F + off; off += 800;
  float* HMP = F + off; off += 4000;
  float* QPA = F + off; off += 800;
  float* QPB = F + off; off += 800;
  unsigned* U = (unsigned*)(F + off);
  unsigned* HIST  = U;                          // [0, 8192)
  unsigned* ACNT  = U + 8192;                   // 2
  unsigned* THR   = U + 8194;                   // 2
  unsigned* FLAGS = U + 8196;                   // 2 (NOT zeroed by zero_u32)
  unsigned* TOPC  = U + 8198;                   // 400
  unsigned* TOPI  = U + 8598;                   // 400
  unsigned long long* CAND = (unsigned long long*)(U + 9000); // 2*CAP u64 -> ends U+33576
  // fp16 MFMA weight planes: alias the decoder-smalls region (dead during
  // wprep + convs). 1,327,104 f16 = 663,552 floats (+4 align pad) fits the
  // 716,800-float X..YC span; 16B-aligned for half8 loads.
  f16* WB_LID = (f16*)((((uintptr_t)X) + 15) & ~(uintptr_t)15);
  f16* WB_CAM = WB_LID + 884736;                // 2*9*12*8*512 = 884736
  f16* WB_HM1 = WB_CAM + 110592;                // 1*9*3*8*512  = 110592
  f16* WB_HM2 = WB_HM1 + 294912;                // 2*9*4*8*512  = 294912 (+36864)

  auto W = [&](int i) -> const float* { return ARENA + aoff[i]; };

  // ---- dtype detect + weight conversion -----------------------------------
  detect_k<<<1, 256, 0, stream>>>((const unsigned*)d_in[0], FLAGS);
  {
    CvtArgs a;
    for (int i = 2; i < 42; i++) { a.src[i - 2] = d_in[i]; a.n[i - 2] = in_sizes[i]; a.off[i - 2] = aoff[i]; }
    cvt_k<<<dim3(432, 40), 256, 0, stream>>>(a, ARENA, FLAGS);
  }
  wprep_k<<<3456, 256, 0, stream>>>(W(2), WB_LID, 128, 384, 12, 8, 1);
  wprep_k<<<432, 256, 0, stream>>>(W(4), WB_CAM, 128, 80, 3, 8, 0);
  wprep_k<<<1152, 256, 0, stream>>>(W(6), WB_HM1, 128, 128, 4, 8, 1);
  wprep_k<<<144, 256, 0, stream>>>(W(10), WB_HM2, 10, 128, 4, 1, 1);

  auto gemm = [&](const float* A, int lda, const float* Wp, const float* bias, int act,
                  const float* res, float* C, int ldc, int M, int N, int K) {
    dim3 grid((M + 63) / 64, (N + 63) / 64, 1);
    gemm_k<float, float><<<grid, 256, 0, stream>>>(
        A, (const float*)nullptr, lda, 0, 0L, Wp, bias, act, res,
        nullptr, nullptr, nullptr, nullptr, C, ldc, 0, 0L, M, N, K);
  };

  // ---- backbone convs (MFMA, fp16 split for fp32-class accuracy) ----------
  conv_mfma<3, 1, 4, 4, 2, float><<<dim3(540, 1, 2), 256, 0, stream>>>(
      d_in[0], FLAGS, 1, (long)384 * HW, WB_LID, W(3), nullptr, nullptr, 0,
      LIDF, (long)128 * HW, 128, 384, 12, 8);
  conv_mfma<1, 1, 4, 4, 2, bf16><<<dim3(540, 1, 2), 256, 0, stream>>>(
      d_in[1], FLAGS, 1, (long)80 * HW, WB_CAM, W(5), nullptr, nullptr, 0,
      CAMF16, (long)128 * HW, 128, 80, 3, 8);
  for (int b = 0; b < 2; b++) {
    conv_mfma<3, 1, 4, 4, 2, float><<<dim3(540, 1, 1), 256, 0, stream>>>(
        LIDF + (long)b * 128 * HW, FLAGS, 0, 0L, WB_HM1, W(7), W(8), W(9), 1,
        HBUF, 0L, 128, 128, 4, 8);
    conv_mfma<3, 4, 1, 1, 1, float><<<dim3(540, 1, 1), 256, 0, stream>>>(
        HBUF, FLAGS, 0, 0L, WB_HM2, W(11), nullptr, nullptr, 2,
        HEAT + (long)b * NCLS * HW, 0L, 10, 128, 4, 1);
  }

  // ---- NMS + exact top-200 ------------------------------------------------
  nms_k<<<(2 * NCLS * HW + 255) / 256, 256, 0, stream>>>(HEAT, SCORE);
  zero_u32<<<(8196 + 255) / 256, 256, 0, stream>>>(U, 8196);
  hist_k<<<dim3(240, 2), 256, 0, stream>>>(SCORE, HIST);
  thresh_k<<<2, 256, 0, stream>>>(HIST, THR);
  collect_k<<<(2 * NCLS * HW + 255) / 256, 256, 0, stream>>>(SCORE, THR, ACNT, CAND);
  select_k<<<2, 64, 0, stream>>>(CAND, ACNT, TOPC, TOPI, QPA);
  gather_k<<<200, 256, 0, stream>>>(LIDF, TOPC, TOPI, W(12), W(13), X);

  // ---- decoder layers -----------------------------------------------------
  for (int i = 0; i < 2; i++) {
    const float* qcur = (i == 0) ? QPA : QPB;
    float* qnext = (i == 0) ? QPB : QPA;
    // query pos-embed
    pe_stage1<<<200, 256, 0, stream>>>(qcur, W(14) + (i * 2 + 0) * 256,
        W(15) + (i * 2 + 0) * 128, W(16) + (i * 2 + 0) * 128, W(17) + (i * 2 + 0) * 128,
        T1Q, 400);
    gemm(T1Q, 128, W(18) + (size_t)(i * 2 + 0) * 16384, W(19) + (i * 2 + 0) * 128,
         0, nullptr, QPE, 128, 400, 128, 128);
    // key pos-embed (BEV grid fused into staging), stored transposed [128][HW] bf16
    gemm_k<float, bf16><<<dim3(507, 2, 1), 256, 0, stream>>>(
        ARENA, (const float*)nullptr, 0, 2, 0L,
        W(18) + (size_t)(i * 2 + 1) * 16384, W(19) + (i * 2 + 1) * 128, 0, nullptr,
        W(14) + (i * 2 + 1) * 256, W(15) + (i * 2 + 1) * 128,
        W(16) + (i * 2 + 1) * 128, W(17) + (i * 2 + 1) * 128,
        KPET16, HW, 1, 0L, 32400, 128, 128);
    // self-attention
    add2_k<<<200, 256, 0, stream>>>(X, QPE, XQ, 51200);
    gemm(XQ, 128, W(20) + (size_t)(i * 2 + 0) * 49152, W(21) + (i * 2 + 0) * 384,
         0, nullptr, SQKV, 384, 400, 384, 128);
    self_attn_k<<<dim3(200, 8, 2), 64, 0, stream>>>(SQKV, SAO);
    gemm(SAO, 128, W(22) + (size_t)(i * 2 + 0) * 16384, W(23) + (i * 2 + 0) * 128,
         0, X, PRE, 128, 400, 128, 128);
    ln_k<<<100, 256, 0, stream>>>(PRE, W(24) + (i * 3 + 0) * 128, W(25) + (i * 3 + 0) * 128, X);
    // cross-attention
    add2_k<<<200, 256, 0, stream>>>(X, QPE, XQ, 51200);
    gemm(XQ, 128, W(20) + (size_t)(i * 2 + 1) * 49152, W(21) + (i * 2 + 1) * 384,
         0, nullptr, QH2, 128, 400, 128, 128);
    gemm_k<bf16, bf16><<<dim3(507, 4, 2), 256, 0, stream>>>(
        CAMF16, KPET16, HW, 1, (long)128 * HW,
        W(20) + (size_t)(i * 2 + 1) * 49152 + 16384, W(21) + (i * 2 + 1) * 384 + 128,
        0, nullptr, nullptr, nullptr, nullptr, nullptr,
        KVT16, HW, 1, (long)256 * HW, 32400, 256, 128);
    flash_k<<<dim3(NSPLIT, 8, 2), 256, 0, stream>>>(QH2, KVT16, PART);
    combine_k<<<200, 256, 0, stream>>>(PART, CAO);
    gemm(CAO, 128, W(22) + (size_t)(i * 2 + 1) * 16384, W(23) + (i * 2 + 1) * 128,
         0, X, PRE, 128, 400, 128, 128);
    ln_k<<<100, 256, 0, stream>>>(PRE, W(24) + (i * 3 + 1) * 128, W(25) + (i * 3 + 1) * 128, X);
    // FFN
    gemm(X, 128, W(26) + (size_t)i * 32768, W(27) + i * 256,
         1, nullptr, FF1, 256, 400, 256, 128);
    gemm(FF1, 256, W(28) + (size_t)i * 32768, W(29) + i * 128,
         0, X, PRE, 128, 400, 128, 256);
    ln_k<<<100, 256, 0, stream>>>(PRE, W(24) + (i * 3 + 2) * 128, W(25) + (i * 3 + 2) * 128, X);
    // prediction heads
    conv1d_k<<<dim3(200, 2), 128, 0, stream>>>(X, W(30) + (size_t)i * 49152,
        W(31) + i * 128, W(32) + i * 128, W(33) + i * 128, YC);
    head2_k<<<4, 256, 0, stream>>>(YC, W(34) + (size_t)i * 768, W(35) + i * 2,
        qcur, CENT, 2, qnext);
    conv1d_k<<<dim3(200, 2), 128, 0, stream>>>(X, W(36) + (size_t)i * 49152,
        W(37) + i * 128, W(38) + i * 128, W(39) + i * 128, YC);
    head2_k<<<16, 256, 0, stream>>>(YC, W(40) + (size_t)i * 3840, W(41) + i * 10,
        nullptr, HMP, 10, nullptr);
  }
  out_k<<<19, 256, 0, stream>>>(CENT, HMP, d_out, FLAGS);
}

// Round 7
// 2697.615 us; speedup vs baseline: 2.0420x; 1.2171x over previous
//
#include <hip/hip_runtime.h>
#include <hip/hip_bf16.h>

typedef __hip_bfloat16 bf16;
typedef _Float16 f16;

#define HW 32400
#define NCLS 10
#define PQ 200
#define HIDDEN 128
#define NSPLIT 45
#define SPLITLEN 720    // 45*720 = 32400 exactly
#define QT 100
#define CAP 6144
#define NBIN 4096

typedef __attribute__((ext_vector_type(8))) _Float16 half8;
typedef __attribute__((ext_vector_type(4))) short short4v;
typedef __attribute__((ext_vector_type(4))) float f32x4;

__device__ __forceinline__ float b2f(bf16 v) { return __bfloat162float(v); }
__device__ __forceinline__ void stf(float* p, float v) { *p = v; }
__device__ __forceinline__ void stf(bf16* p, float v) { *p = __float2bfloat16(v); }
// runtime-dtype load: isbf!=0 -> bf16 array, else fp32 array
__device__ __forceinline__ float ldsel(const void* p, long i, unsigned isbf) {
  return isbf ? __bfloat162float(((const bf16*)p)[i]) : ((const float*)p)[i];
}
__device__ __forceinline__ float ldf(const float* p, long i) { return p[i]; }
__device__ __forceinline__ float ldf(const bf16* p, long i) { return __bfloat162float(p[i]); }
__device__ __forceinline__ short f2bf_bits(float v) {
  union { bf16 h; short s; } u; u.h = __float2bfloat16(v); return u.s;
}

// ---------------------------------------------------------------------------
// dtype detection (bf16 vs fp32 inputs) -> FLAGS[0]
// ---------------------------------------------------------------------------
__global__ void detect_k(const unsigned* __restrict__ L, unsigned* __restrict__ FLAGS)
{
  __shared__ unsigned cnt[2];
  int tid = threadIdx.x;
  if (tid < 2) cnt[tid] = 0;
  __syncthreads();
  unsigned nz = 0, pl = 0;
  for (int w = tid; w < 4096; w += 256) {
    unsigned u = L[w];
    if (u) {
      nz++;
      unsigned e = (u >> 7) & 0xFF;
      if (e >= 110 && e <= 140) pl++;
    }
  }
  atomicAdd(&cnt[0], nz);
  atomicAdd(&cnt[1], pl);
  __syncthreads();
  if (tid == 0) {
    FLAGS[0] = (2u * cnt[1] > cnt[0]) ? 1u : 0u;
    FLAGS[1] = 0u;
  }
}

// batched weight conversion into fp32 arena (exact in both modes)
struct CvtArgs { const void* src[40]; int n[40]; int off[40]; };
__global__ __launch_bounds__(256) void cvt_k(CvtArgs a, float* __restrict__ dst,
                                             const unsigned* __restrict__ FLAGS)
{
  int j = blockIdx.y;
  unsigned isbf = FLAGS[0];
  int n = a.n[j];
  const void* s = a.src[j];
  float* d = dst + a.off[j];
  for (int t = blockIdx.x * 256 + threadIdx.x; t < n; t += gridDim.x * 256)
    d[t] = ldsel(s, t, isbf);
}

// ---------------------------------------------------------------------------
// Conv weight pre-swizzle into MFMA fragment order, fp16 hi (+scaled lo).
// WB[plane][tap][kb][nt][n16][k32] ; value = W[nt*16+n16][kb*32+k][ty][tx]
// plane1 = fp16((v - hi) * 4096)  (scale keeps lo in fp16 normal range)
// ---------------------------------------------------------------------------
__global__ __launch_bounds__(256) void wprep_k(const float* __restrict__ Wsrc,
    f16* __restrict__ WB, int N, int K, int KB, int NTG, int split)
{
  long total = (long)(split ? 2 : 1) * 9 * KB * NTG * 512;
  for (long t = (long)blockIdx.x * 256 + threadIdx.x; t < total;
       t += (long)gridDim.x * 256) {
    long r = t;
    int k = (int)(r & 31); r >>= 5;
    int n16 = (int)(r & 15); r >>= 4;
    int nt = (int)(r % NTG); r /= NTG;
    int kb = (int)(r % KB); r /= KB;
    int tap = (int)(r % 9); r /= 9;
    int plane = (int)r;
    int n = nt * 16 + n16, kk = kb * 32 + k;
    float v = 0.f;
    if (n < N && kk < K) v = Wsrc[((long)n * K + kk) * 9 + tap];
    f16 h = (f16)v;
    f16 outv = h;
    if (plane == 1) outv = (f16)((v - (float)h) * 4096.0f);
    WB[t] = outv;
  }
}

// ---------------------------------------------------------------------------
// MFMA conv2d 3x3 SAME as 9 shifted GEMMs over 64-pixel row chunks (60 valid).
// SPLIT=3: fp32-accurate fp16 split: acc = Σhi·hi' + (Σ(lo·hi'+hi·lo'))/4096,
// lo pre-scaled by 4096 (fp16-normal). SPLIT=1: plain fp16.
// ---------------------------------------------------------------------------
template <int SPLIT, int WM, int WN, int MT, int NT, typename CT>
__global__ __launch_bounds__(256) void conv_mfma(
    const void* __restrict__ A, const unsigned* __restrict__ FLAGS, int dyn,
    long abatch,
    const f16* __restrict__ WB, const float* __restrict__ bias,
    const float* __restrict__ g, const float* __restrict__ beta, int act,
    CT* __restrict__ C, long cbatch, int N, int K, int KB, int NTG)
{
  constexpr int AW = 3 * 66 * 40;            // [ty][px][k] k-stride 40 (bank spread)
  __shared__ __align__(16) f16 Ah[AW];
  __shared__ __align__(16) f16 Al[SPLIT == 3 ? AW : 8];
  unsigned isbf = dyn ? FLAGS[0] : 0u;
  int bz = blockIdx.z;
  int y = blockIdx.x / 3;
  int x0 = (blockIdx.x % 3) * 60;
  int tid = threadIdx.x;
  int w = tid >> 6, lane = tid & 63;
  int lane15 = lane & 15, lgrp = lane >> 4;
  int wm = w % WM, wn = w / WM;
  int mbase = wm * MT * 16;
  int nbase = wn * NT * 16;
  f32x4 accM[MT][NT] = {};
  f32x4 accC[SPLIT == 3 ? MT : 1][SPLIT == 3 ? NT : 1] = {};
  long planeStride = (long)9 * KB * NTG * 512;

  for (int kb = 0; kb < KB; kb++) {
    __syncthreads();
    for (int e = tid; e < 3 * 32 * 66; e += 256) {
      int row = e / (32 * 66);
      int rem = e - row * (32 * 66);
      int k = rem / 66;
      int px = rem - k * 66;
      int gx = x0 + px - 1, gy = y + row - 1;
      int kk = kb * 32 + k;
      float v = 0.f;
      if (gx >= 0 && gx < 180 && gy >= 0 && gy < 180 && kk < K)
        v = ldsel(A, (long)bz * abatch + (long)kk * HW + gy * 180 + gx, isbf);
      f16 h = (f16)v;
      Ah[(row * 66 + px) * 40 + k] = h;
      if constexpr (SPLIT == 3)
        Al[(row * 66 + px) * 40 + k] = (f16)((v - (float)h) * 4096.0f);
    }
    __syncthreads();
#pragma unroll
    for (int tap = 0; tap < 9; tap++) {
      int ty = tap / 3, tx = tap % 3;
      const f16* wb = WB + (((long)tap * KB + kb) * NTG) * 512;
      half8 bh[NT], bl[SPLIT == 3 ? NT : 1];
#pragma unroll
      for (int nt = 0; nt < NT; nt++) {
        long o = (long)(wn * NT + nt) * 512 + lane15 * 32 + lgrp * 8;
        bh[nt] = *(const half8*)(wb + o);
        if constexpr (SPLIT == 3) bl[nt] = *(const half8*)(wb + planeStride + o);
      }
      half8 ah[MT], al[SPLIT == 3 ? MT : 1];
#pragma unroll
      for (int mt = 0; mt < MT; mt++) {
        int px = mbase + mt * 16 + lane15 + tx;
        int o = (ty * 66 + px) * 40 + lgrp * 8;
        ah[mt] = *(const half8*)&Ah[o];
        if constexpr (SPLIT == 3) al[mt] = *(const half8*)&Al[o];
      }
#pragma unroll
      for (int mt = 0; mt < MT; mt++)
#pragma unroll
        for (int nt = 0; nt < NT; nt++) {
          accM[mt][nt] = __builtin_amdgcn_mfma_f32_16x16x32_f16(
              ah[mt], bh[nt], accM[mt][nt], 0, 0, 0);
          if constexpr (SPLIT == 3) {
            accC[mt][nt] = __builtin_amdgcn_mfma_f32_16x16x32_f16(
                al[mt], bh[nt], accC[mt][nt], 0, 0, 0);
            accC[mt][nt] = __builtin_amdgcn_mfma_f32_16x16x32_f16(
                ah[mt], bl[nt], accC[mt][nt], 0, 0, 0);
          }
        }
    }
  }
  int pixbase = y * 180 + x0;
#pragma unroll
  for (int mt = 0; mt < MT; mt++) {
    int m = mbase + mt * 16 + lgrp * 4;
    if (m >= 60) continue;
#pragma unroll
    for (int nt = 0; nt < NT; nt++) {
      int n = nbase + nt * 16 + lane15;
      if (n >= N) continue;
      float bi = bias[n];
      float gg = g ? g[n] : 1.f;
      float bb = g ? beta[n] : 0.f;
      long base = (long)bz * cbatch + (long)n * HW + pixbase + m;
      if constexpr (sizeof(CT) == 4) {
        f32x4 ov;
#pragma unroll
        for (int r = 0; r < 4; r++) {
          float v = accM[mt][nt][r];
          if constexpr (SPLIT == 3) v += accC[mt][nt][r] * (1.f / 4096.f);
          v += bi;
          if (g) v = v * gg + bb;
          if (act == 1) v = fmaxf(v, 0.f);
          else if (act == 2) v = 1.f / (1.f + expf(-v));
          ov[r] = v;
        }
        *(f32x4*)&C[base] = ov;
      } else {
        short4v ov;
#pragma unroll
        for (int r = 0; r < 4; r++) {
          float v = accM[mt][nt][r];
          if constexpr (SPLIT == 3) v += accC[mt][nt][r] * (1.f / 4096.f);
          v += bi;
          if (g) v = v * gg + bb;
          if (act == 1) v = fmaxf(v, 0.f);
          ov[r] = f2bf_bits(v);
        }
        *(short4v*)&C[base] = ov;
      }
    }
  }
}

// ---------------------------------------------------------------------------
// Generic tiled GEMM: C = act(A @ W^T + bias) (+ res)
// amode 0: A[m*lda+k].  amode 1: A[k*lda+m] (+A2 same layout, un-batched).
// amode 2: A[m][k] = relu((p0*pe1w[2k]+p1*pe1w[2k+1]+pe1b[k])*pe1g[k]+pe1bt[k])
// cmode 0: C[m*ldc+n] ; cmode 1: C[n*ldc+m].  K multiple of 16.
// ---------------------------------------------------------------------------
template <typename AT, typename CT>
__global__ __launch_bounds__(256) void gemm_k(
    const AT* __restrict__ A, const AT* __restrict__ A2, int lda, int amode,
    long abatch,
    const float* __restrict__ W, const float* __restrict__ bias, int act,
    const float* __restrict__ res,
    const float* __restrict__ pe1w, const float* __restrict__ pe1b,
    const float* __restrict__ pe1g, const float* __restrict__ pe1bt,
    CT* __restrict__ C, int ldc, int cmode, long cbatch,
    int M, int N, int K)
{
  __shared__ __align__(16) float As[16][68];
  __shared__ __align__(16) float Ws[16][68];
  int b = blockIdx.z;
  int m0 = blockIdx.x * 64, n0 = blockIdx.y * 64;
  int tid = threadIdx.x;
  int nt = tid & 15, mt = tid >> 4;
  float acc[4][4] = {};
  const AT* Ab = A + (long)b * abatch;
  for (int k0 = 0; k0 < K; k0 += 16) {
    if (amode == 0) {
      for (int e = tid; e < 1024; e += 256) {
        int m = e >> 4, k = e & 15;
        float v = 0.f;
        if (m0 + m < M) v = ldf(Ab, (long)(m0 + m) * lda + k0 + k);
        As[k][m] = v;
      }
    } else if (amode == 1) {
      for (int e = tid; e < 1024; e += 256) {
        int m = e & 63, k = e >> 6;
        float v = 0.f;
        if (m0 + m < M) {
          long idx = (long)(k0 + k) * lda + m0 + m;
          v = ldf(Ab, idx);
          if (A2) v += ldf(A2, idx);
        }
        As[k][m] = v;
      }
    } else {
      for (int e = tid; e < 1024; e += 256) {
        int m = e & 63, k = e >> 6;
        float v = 0.f;
        int gm = m0 + m;
        if (gm < M) {
          float p0 = (float)(gm / 180) + 0.5f;
          float p1 = (float)(gm % 180) + 0.5f;
          int kk = k0 + k;
          float t = p0 * pe1w[kk * 2] + p1 * pe1w[kk * 2 + 1] + pe1b[kk];
          t = t * pe1g[kk] + pe1bt[kk];
          v = fmaxf(t, 0.f);
        }
        As[k][m] = v;
      }
    }
    for (int e = tid; e < 1024; e += 256) {
      int n = e >> 4, k = e & 15;
      float v = 0.f;
      if (n0 + n < N) v = W[(long)(n0 + n) * K + k0 + k];
      Ws[k][n] = v;
    }
    __syncthreads();
#pragma unroll
    for (int kk = 0; kk < 16; kk++) {
      float4 av = *(const float4*)&As[kk][mt * 4];
      float4 wv = *(const float4*)&Ws[kk][nt * 4];
      float am[4] = {av.x, av.y, av.z, av.w};
      float wn[4] = {wv.x, wv.y, wv.z, wv.w};
#pragma unroll
      for (int mi = 0; mi < 4; mi++)
#pragma unroll
        for (int ni = 0; ni < 4; ni++)
          acc[mi][ni] = fmaf(am[mi], wn[ni], acc[mi][ni]);
    }
    __syncthreads();
  }
#pragma unroll
  for (int mi = 0; mi < 4; mi++) {
    int m = m0 + mt * 4 + mi;
    if (m >= M) continue;
#pragma unroll
    for (int ni = 0; ni < 4; ni++) {
      int n = n0 + nt * 4 + ni;
      if (n >= N) continue;
      float v = acc[mi][ni];
      if (bias) v += bias[n];
      if (act == 1) v = fmaxf(v, 0.f);
      if (res) v += res[(long)m * ldc + n];
      long ci = (cmode == 0) ? ((long)b * cbatch + (long)m * ldc + n)
                             : ((long)b * cbatch + (long)n * ldc + m);
      stf(&C[ci], v);
    }
  }
}

// ---------------------------------------------------------------------------
__global__ void nms_k(const float* __restrict__ HEAT, float* __restrict__ SCORE)
{
  int t = blockIdx.x * 256 + threadIdx.x;
  if (t >= 2 * NCLS * HW) return;
  int b = t / (NCLS * HW); int r = t % (NCLS * HW);
  int cls = r / HW; int n = r % HW;
  const float* hb = HEAT + ((long)(b * NCLS + cls)) * HW;
  float v = hb[n];
  bool keep = true;
  if (cls < 8) {
    int y = n / 180, x = n % 180;
    if (y == 0 || y == 179 || x == 0 || x == 179) keep = false;
    else {
      float mx = -1e30f;
#pragma unroll
      for (int dy = -1; dy <= 1; dy++)
#pragma unroll
        for (int dx = -1; dx <= 1; dx++)
          mx = fmaxf(mx, hb[(y + dy) * 180 + x + dx]);
      keep = (v == mx);
    }
  }
  SCORE[(long)b * (NCLS * HW) + r] = keep ? v : 0.f;
}

__global__ void zero_u32(unsigned* p, int n)
{
  int t = blockIdx.x * 256 + threadIdx.x;
  if (t < n) p[t] = 0;
}

__global__ __launch_bounds__(256) void hist_k(const float* __restrict__ SCORE,
                                              unsigned* __restrict__ HIST)
{
  __shared__ unsigned lh[NBIN];
  int b = blockIdx.y;
  for (int e = threadIdx.x; e < NBIN; e += 256) lh[e] = 0;
  __syncthreads();
  int start = blockIdx.x * 1350;
  const float* sb = SCORE + (long)b * (NCLS * HW);
  for (int e = start + threadIdx.x; e < start + 1350; e += 256) {
    unsigned bits = __float_as_uint(sb[e]);
    atomicAdd(&lh[bits >> 18], 1u);
  }
  __syncthreads();
  for (int e = threadIdx.x; e < NBIN; e += 256) {
    unsigned c = lh[e];
    if (c) atomicAdd(&HIST[b * NBIN + e], c);
  }
}

__global__ void thresh_k(const unsigned* __restrict__ HIST, unsigned* __restrict__ THR)
{
  __shared__ unsigned ps[256];
  int b = blockIdx.x;
  const unsigned* hb = HIST + b * NBIN;
  unsigned s = 0;
  for (int j = 0; j < 16; j++) s += hb[threadIdx.x * 16 + j];
  ps[threadIdx.x] = s;
  __syncthreads();
  if (threadIdx.x == 0) {
    unsigned cum = 0; int t = 255;
    for (; t > 0; t--) { if (cum + ps[t] >= PQ) break; cum += ps[t]; }
    int bin = t * 16 + 15;
    for (; bin > t * 16; bin--) { unsigned c = hb[bin]; if (cum + c >= PQ) break; cum += c; }
    if (bin < 1) bin = 1;
    THR[b] = (unsigned)bin;
  }
}

__global__ void collect_k(const float* __restrict__ SCORE, const unsigned* __restrict__ THR,
                          unsigned* __restrict__ ACNT, unsigned long long* __restrict__ CAND)
{
  int t = blockIdx.x * 256 + threadIdx.x;
  if (t >= 2 * NCLS * HW) return;
  int b = t / (NCLS * HW); int r = t % (NCLS * HW);
  float v = SCORE[(long)b * (NCLS * HW) + r];
  unsigned bits = __float_as_uint(v);
  if ((bits >> 18) >= THR[b]) {
    unsigned slot = atomicAdd(&ACNT[b], 1u);
    if (slot < CAP) CAND[(long)b * CAP + slot] =
        ((unsigned long long)bits << 32) | (unsigned)(~r);
  }
}

__global__ __launch_bounds__(64) void select_k(
    const unsigned long long* __restrict__ CAND, const unsigned* __restrict__ ACNT,
    unsigned* __restrict__ TOPC, unsigned* __restrict__ TOPI, float* __restrict__ QPA)
{
  __shared__ unsigned long long cnd[CAP];
  int b = blockIdx.x;
  int lane = threadIdx.x;
  unsigned cnt = ACNT[b]; if (cnt > CAP) cnt = CAP;
  for (int e = lane; e < (int)cnt; e += 64) cnd[e] = CAND[(long)b * CAP + e];
  __syncthreads();
  for (int p = 0; p < PQ; p++) {
    unsigned long long best = 0;
    for (int e = lane; e < (int)cnt; e += 64) { unsigned long long c = cnd[e]; if (c > best) best = c; }
#pragma unroll
    for (int o = 32; o; o >>= 1) {
      unsigned long long other = __shfl_xor(best, o, 64);
      if (other > best) best = other;
    }
    for (int e = lane; e < (int)cnt; e += 64) if (best != 0 && cnd[e] == best) cnd[e] = 0;
    if (lane == 0) {
      unsigned idx = (best == 0) ? 0u : ~(unsigned)(best & 0xFFFFFFFFull);
      if (idx >= NCLS * HW) idx = 0;
      unsigned cls = idx / HW, n = idx % HW;
      TOPC[b * PQ + p] = cls; TOPI[b * PQ + p] = n;
      QPA[((long)(b * PQ + p)) * 2 + 0] = (float)(n / 180) + 0.5f;
      QPA[((long)(b * PQ + p)) * 2 + 1] = (float)(n % 180) + 0.5f;
    }
    __syncthreads();
  }
}

__global__ void gather_k(const float* __restrict__ LIDF, const unsigned* __restrict__ TOPC,
                         const unsigned* __restrict__ TOPI, const float* __restrict__ cew,
                         const float* __restrict__ ceb, float* __restrict__ X)
{
  int t = blockIdx.x * 256 + threadIdx.x;
  if (t >= 2 * PQ * HIDDEN) return;
  int c = t & 127; int r = t >> 7; int p = r % PQ; int b = r / PQ;
  unsigned n = TOPI[b * PQ + p]; unsigned cls = TOPC[b * PQ + p];
  if (n >= HW) n = 0;
  if (cls >= NCLS) cls = 0;
  X[t] = LIDF[((long)(b * HIDDEN + c)) * HW + n] + cew[c * NCLS + cls] + ceb[c];
}

// posembed stage 1 for queries only
__global__ void pe_stage1(const float* __restrict__ qpos,
                          const float* __restrict__ w1, const float* __restrict__ b1,
                          const float* __restrict__ g, const float* __restrict__ bt,
                          float* __restrict__ T1, int M)
{
  int t = blockIdx.x * 256 + threadIdx.x;
  if (t >= M * HIDDEN) return;
  int c = t & 127; int m = t >> 7;
  float p0 = qpos[m * 2], p1 = qpos[m * 2 + 1];
  float v = p0 * w1[c * 2] + p1 * w1[c * 2 + 1] + b1[c];
  v = v * g[c] + bt[c];
  T1[t] = fmaxf(v, 0.f);
}

__global__ void add2_k(const float* __restrict__ a, const float* __restrict__ b,
                       float* __restrict__ o, int n)
{
  int t = blockIdx.x * 256 + threadIdx.x;
  if (t < n) o[t] = a[t] + b[t];
}

__global__ __launch_bounds__(64) void self_attn_k(const float* __restrict__ SQKV,
                                                  float* __restrict__ SAO)
{
  int q = blockIdx.x, h = blockIdx.y, b = blockIdx.z;
  int lane = threadIdx.x;
  const float* qp = SQKV + ((long)(b * PQ + q)) * 384 + h * 16;
  float qv[16];
#pragma unroll
  for (int d = 0; d < 16; d++) qv[d] = qp[d] * 0.25f;
  float sv[4]; int kks[4]; int nk = 0;
  float lmax = -1e30f;
  for (int kk = lane; kk < PQ; kk += 64) {
    const float* kp = SQKV + ((long)(b * PQ + kk)) * 384 + 128 + h * 16;
    float s = 0.f;
#pragma unroll
    for (int d = 0; d < 16; d++) s = fmaf(qv[d], kp[d], s);
    sv[nk] = s; kks[nk] = kk; nk++;
    lmax = fmaxf(lmax, s);
  }
#pragma unroll
  for (int o = 32; o; o >>= 1) lmax = fmaxf(lmax, __shfl_xor(lmax, o, 64));
  float lsum = 0.f; float acc[16] = {};
  for (int t = 0; t < nk; t++) {
    float p = expf(sv[t] - lmax);
    lsum += p;
    const float* vp = SQKV + ((long)(b * PQ + kks[t])) * 384 + 256 + h * 16;
#pragma unroll
    for (int d = 0; d < 16; d++) acc[d] = fmaf(p, vp[d], acc[d]);
  }
#pragma unroll
  for (int o = 32; o; o >>= 1) lsum += __shfl_xor(lsum, o, 64);
#pragma unroll
  for (int d = 0; d < 16; d++) {
    float v = acc[d];
#pragma unroll
    for (int o = 32; o; o >>= 1) v += __shfl_xor(v, o, 64);
    if (lane == 0) SAO[((long)(b * PQ + q)) * HIDDEN + h * 16 + d] = v / lsum;
  }
}

// ---------------------------------------------------------------------------
// flash cross-attention, key-split, bank-conflict-free layouts.
// QH [400][128] fp32, KVT [B][256][HW] bf16 (K rows 0..127, V rows 128..255).
// Block = (split s, head h, z = b*2 + qhalf); QT=100 queries per block.
// Phase1: 4q x 4j register tile, float4 LDS reads (qtL d-major, kjL d-major).
// Phase2a: softmax stats, 2 threads/q + shfl. Phase2b: 4q x 2d x 4j, O in
// registers across tiles (q interleaved stride 25 so sL float4 reads spread
// banks). PART [B][8][NSPLIT][200][18] = o[16], m, l.
// ---------------------------------------------------------------------------
__global__ __launch_bounds__(256) void flash_k(const float* __restrict__ QH,
                                               const bf16* __restrict__ KVT,
                                               float* __restrict__ PART)
{
  int s = blockIdx.x, h = blockIdx.y;
  int b = blockIdx.z >> 1, qh = blockIdx.z & 1;
  int tid = threadIdx.x;
  __shared__ __align__(16) float sL[QT][36];
  __shared__ __align__(16) float qtL[16][104];
  __shared__ __align__(16) float kjL[16][36];
  __shared__ __align__(16) float vjL[16][36];
  __shared__ float mL[QT], lL[QT], aL[QT];
  int qbase = qh * QT;
  for (int e = tid; e < QT * 16; e += 256) {
    int q = e >> 4, d = e & 15;
    qtL[d][q] = QH[((long)(b * PQ + qbase + q)) * HIDDEN + h * 16 + d] * 0.25f;
  }
  if (tid < QT) { mL[tid] = -1e30f; lL[tid] = 0.f; }
  // per-thread O accumulator (phase2b mapping: q = qg + 25*i, d = d0 + k)
  float ovr[4][2] = {};
  int pq = tid >> 3, pd = (tid & 7) * 2;   // pq in 0..24(+junk if tid>=200), 4 q each
  int nbeg = s * SPLITLEN, nend = nbeg + SPLITLEN;
  const bf16* Kb = KVT + (long)b * 256 * HW + (long)(h * 16) * HW;
  const bf16* Vb = Kb + (long)128 * HW;
  __syncthreads();
  for (int n0 = nbeg; n0 < nend; n0 += 32) {
    int rem = nend - n0;
    // ---- stage K,V d-major [16][36]
    for (int e = tid; e < 512; e += 256) {
      int d = e >> 5, j = e & 31;
      float kv = 0.f, vv = 0.f;
      if (j < rem) { kv = b2f(Kb[(long)d * HW + n0 + j]); vv = b2f(Vb[(long)d * HW + n0 + j]); }
      kjL[d][j] = kv; vjL[d][j] = vv;
    }
    __syncthreads();
    // ---- phase 1: S = Q K^T  (4q x 4j per item)
    if (tid < 200) {
      int qg = tid >> 3, jg = tid & 7;
      int q0 = qg * 4, j0 = jg * 4;
      float acc[4][4] = {};
#pragma unroll
      for (int d = 0; d < 16; d++) {
        float4 kv = *(const float4*)&kjL[d][j0];
        float4 qv = *(const float4*)&qtL[d][q0];
        float qa[4] = {qv.x, qv.y, qv.z, qv.w};
        float ka[4] = {kv.x, kv.y, kv.z, kv.w};
#pragma unroll
        for (int i = 0; i < 4; i++)
#pragma unroll
          for (int jj = 0; jj < 4; jj++)
            acc[i][jj] = fmaf(qa[i], ka[jj], acc[i][jj]);
      }
#pragma unroll
      for (int i = 0; i < 4; i++) {
        float4 ov;
        ov.x = (j0 + 0 < rem) ? acc[i][0] : -1e30f;
        ov.y = (j0 + 1 < rem) ? acc[i][1] : -1e30f;
        ov.z = (j0 + 2 < rem) ? acc[i][2] : -1e30f;
        ov.w = (j0 + 3 < rem) ? acc[i][3] : -1e30f;
        *(float4*)&sL[q0 + i][j0] = ov;
      }
    }
    __syncthreads();
    // ---- phase 2a: softmax stats (2 threads per q)
    if (tid < 2 * QT) {
      int q = tid >> 1, hf = tid & 1;
      int jb = hf * 16;
      float mx = -1e30f;
#pragma unroll
      for (int j = 0; j < 16; j++) mx = fmaxf(mx, sL[q][jb + j]);
      float mo = __shfl_xor(mx, 1, 64);
      float mold = mL[q];
      float mnew = fmaxf(fmaxf(mx, mo), mold);
      float lsum = 0.f;
#pragma unroll
      for (int j = 0; j < 16; j++) {
        float p = expf(sL[q][jb + j] - mnew);
        sL[q][jb + j] = p;
        lsum += p;
      }
      lsum += __shfl_xor(lsum, 1, 64);
      if (hf == 0) {
        float alpha = expf(mold - mnew);
        lL[q] = lL[q] * alpha + lsum;
        mL[q] = mnew;
        aL[q] = alpha;
      }
    }
    __syncthreads();
    // ---- phase 2b: O = O*alpha + P V  (4q x 2d x 4j, O in registers)
    if (tid < 200) {
#pragma unroll
      for (int i = 0; i < 4; i++) {
        float a = aL[pq + 25 * i];
        ovr[i][0] *= a; ovr[i][1] *= a;
      }
#pragma unroll
      for (int j0 = 0; j0 < 32; j0 += 4) {
        float4 v0 = *(const float4*)&vjL[pd][j0];
        float4 v1 = *(const float4*)&vjL[pd + 1][j0];
#pragma unroll
        for (int i = 0; i < 4; i++) {
          float4 p = *(const float4*)&sL[pq + 25 * i][j0];
          ovr[i][0] = fmaf(p.x, v0.x, ovr[i][0]);
          ovr[i][0] = fmaf(p.y, v0.y, ovr[i][0]);
          ovr[i][0] = fmaf(p.z, v0.z, ovr[i][0]);
          ovr[i][0] = fmaf(p.w, v0.w, ovr[i][0]);
          ovr[i][1] = fmaf(p.x, v1.x, ovr[i][1]);
          ovr[i][1] = fmaf(p.y, v1.y, ovr[i][1]);
          ovr[i][1] = fmaf(p.z, v1.z, ovr[i][1]);
          ovr[i][1] = fmaf(p.w, v1.w, ovr[i][1]);
        }
      }
    }
    __syncthreads();
  }
  long base = ((((long)(b * 8 + h)) * NSPLIT + s) * PQ) * 18;
  if (tid < 200) {
#pragma unroll
    for (int i = 0; i < 4; i++) {
      long ro = base + (long)(qbase + pq + 25 * i) * 18;
      PART[ro + pd] = ovr[i][0];
      PART[ro + pd + 1] = ovr[i][1];
    }
  }
  if (tid < QT) {
    long ro = base + (long)(qbase + tid) * 18;
    PART[ro + 16] = mL[tid];
    PART[ro + 17] = lL[tid];
  }
}

__global__ void combine_k(const float* __restrict__ PART, float* __restrict__ CAO)
{
  int t = blockIdx.x * 256 + threadIdx.x;
  if (t >= 2 * 8 * PQ * 16) return;
  int d = t & 15; int r = t >> 4;
  int q = r % PQ; r /= PQ;
  int h = r & 7; int b = r >> 3;
  long base = (((long)(b * 8 + h)) * NSPLIT) * PQ * 18 + (long)q * 18;
  float M = -1e30f;
  for (int s = 0; s < NSPLIT; s++) M = fmaxf(M, PART[base + (long)s * PQ * 18 + 16]);
  float L = 0.f, O = 0.f;
  for (int s = 0; s < NSPLIT; s++) {
    long p0 = base + (long)s * PQ * 18;
    float w = expf(PART[p0 + 16] - M);
    L += PART[p0 + 17] * w;
    O += PART[p0 + d] * w;
  }
  CAO[((long)(b * PQ + q)) * HIDDEN + h * 16 + d] = (L > 0.f) ? O / L : 0.f;
}

__global__ __launch_bounds__(256) void ln_k(const float* __restrict__ PRE,
                                            const float* __restrict__ g,
                                            const float* __restrict__ bta,
                                            float* __restrict__ X)
{
  int row = blockIdx.x * 4 + (threadIdx.x >> 6);
  int lane = threadIdx.x & 63;
  const float* p = PRE + (long)row * HIDDEN;
  float v0 = p[lane], v1 = p[lane + 64];
  float s = v0 + v1;
#pragma unroll
  for (int o = 32; o; o >>= 1) s += __shfl_xor(s, o, 64);
  float mu = s * (1.f / 128.f);
  float d0 = v0 - mu, d1 = v1 - mu;
  float vs = d0 * d0 + d1 * d1;
#pragma unroll
  for (int o = 32; o; o >>= 1) vs += __shfl_xor(vs, o, 64);
  float rs = rsqrtf(vs * (1.f / 128.f) + 1e-5f);
  float* xo = X + (long)row * HIDDEN;
  xo[lane] = d0 * rs * g[lane] + bta[lane];
  xo[lane + 64] = d1 * rs * g[lane + 64] + bta[lane + 64];
}

__global__ __launch_bounds__(128) void conv1d_k(const float* __restrict__ X,
                                                const float* __restrict__ w,
                                                const float* __restrict__ bias,
                                                const float* __restrict__ g,
                                                const float* __restrict__ beta,
                                                float* __restrict__ Y)
{
  int p = blockIdx.x, b = blockIdx.y;
  int co = threadIdx.x;
  __shared__ float xs[3][HIDDEN];
  for (int e = co; e < 3 * HIDDEN; e += HIDDEN) {
    int t = e >> 7, c = e & 127;
    int pp = p + t - 1;
    xs[t][c] = (pp >= 0 && pp < PQ) ? X[((long)(b * PQ + pp)) * HIDDEN + c] : 0.f;
  }
  __syncthreads();
  const float* wr = w + (long)co * HIDDEN * 3;
  float acc = 0.f;
  for (int c = 0; c < HIDDEN; c++) {
    acc = fmaf(xs[0][c], wr[c * 3 + 0], acc);
    acc = fmaf(xs[1][c], wr[c * 3 + 1], acc);
    acc = fmaf(xs[2][c], wr[c * 3 + 2], acc);
  }
  float v = (acc + bias[co]) * g[co] + beta[co];
  Y[((long)(b * PQ + p)) * HIDDEN + co] = fmaxf(v, 0.f);
}

__global__ void head2_k(const float* __restrict__ Y, const float* __restrict__ w,
                        const float* __restrict__ bias, const float* __restrict__ qpos,
                        float* __restrict__ OUT, int N, float* __restrict__ qnext)
{
  int t = blockIdx.x * 256 + threadIdx.x;
  if (t >= 2 * N * PQ) return;
  int p = t % PQ; int r = t / PQ; int co = r % N; int b = r / N;
  const float* wr = w + (long)co * HIDDEN * 3;
  float acc = 0.f;
  for (int tap = 0; tap < 3; tap++) {
    int pp = p + tap - 1;
    if (pp < 0 || pp >= PQ) continue;
    const float* yr = Y + ((long)(b * PQ + pp)) * HIDDEN;
    for (int c = 0; c < HIDDEN; c++)
      acc = fmaf(yr[c], wr[c * 3 + tap], acc);
  }
  float v = acc + bias[co];
  if (qpos) v += qpos[((long)(b * PQ + p)) * 2 + co];
  OUT[((long)(b * N + co)) * PQ + p] = v;
  if (qnext) qnext[((long)(b * PQ + p)) * 2 + co] = v;
}

__global__ void out_k(const float* __restrict__ CENT, const float* __restrict__ HMP,
                      void* __restrict__ out, const unsigned* __restrict__ FLAGS)
{
  int t = blockIdx.x * 256 + threadIdx.x;
  if (t >= 2 * 12 * PQ) return;
  int p = t % PQ; int r = t / PQ; int ch = r % 12; int b = r / 12;
  float v = (ch < 2) ? CENT[((long)(b * 2 + ch)) * PQ + p]
                     : HMP[((long)(b * 10 + ch - 2)) * PQ + p];
  if (FLAGS[0]) ((bf16*)out)[t] = __float2bfloat16(v);
  else          ((float*)out)[t] = v;
}

// ---------------------------------------------------------------------------
extern "C" void kernel_launch(void* const* d_in, const int* in_sizes, int n_in,
                              void* d_out, int out_size, void* d_ws, size_t ws_size,
                              hipStream_t stream)
{
  (void)n_in; (void)out_size; (void)ws_size;

  // ---- workspace layout (~80 MB == R3's validated watermark) --------------
  float* F = (float*)d_ws;
  size_t off = 0;
  int aoff[42];
  {
    size_t acc = 0;
    for (int i = 2; i < 42; i++) { aoff[i] = (int)acc; acc += (size_t)in_sizes[i]; }
    off = acc;
  }
  float* ARENA = F;
  float* LIDF = F + off;                        // [2][128][HW] fp32 (dead after gather)
  bf16*  KVT16 = (bf16*)(F + off);              // alias: [2][256][HW] bf16 (decoder)
  off += 8294400;
  float* HBUF = F + off;                        // [1][128][HW] fp32 (per-batch reuse)
  bf16*  KPET16 = (bf16*)(F + off);             // alias: [128][HW] bf16 (decoder)
  float* PART  = F + off;                       // alias: [2][8][NSPLIT][200][18]
                                                // (KPE write -> KV gemm read ->
                                                //  flash write PART -> combine:
                                                //  time-disjoint within a layer)
  off += 4147200;
  bf16*  CAMF16 = (bf16*)(F + off);             // [2][128][HW] bf16 (live all run)
  off += 4147200;
  float* HEAT  = F + off;                       // [2][10][HW] (dead after nms)
  float* SCORE = F + off + 648000;              // (dead after collect)
  off += 1296000;
  float* X   = F + off; off += 51200;           // decoder smalls — all dead during
  float* XQ  = F + off; off += 51200;           // convs; WB_* aliases this region
  float* QPE = F + off; off += 51200;
  float* T1Q = F + off; off += 51200;
  float* SQKV = F + off; off += 153600;
  float* SAO = F + off; off += 51200;
  float* PRE = F + off; off += 51200;
  float* QH2 = F + off; off += 51200;
  float* CAO = F + off; off += 51200;
  float* FF1 = F + off; off += 102400;
  float* YC  = F + off; off += 51200;           // X..YC span = 716800 floats
  float* CENT = F + off; off += 800;
  float* HMP = F + off; off += 4000;
  float* QPA = F + off; off += 800;
  float* QPB = F + off; off += 800;
  unsigned* U = (unsigned*)(F + off);
  unsigned* HIST  = U;                          // [0, 8192)
  unsigned* ACNT  = U + 8192;                   // 2
  unsigned* THR   = U + 8194;                   // 2
  unsigned* FLAGS = U + 8196;                   // 2 (NOT zeroed by zero_u32)
  unsigned* TOPC  = U + 8198;                   // 400
  unsigned* TOPI  = U + 8598;                   // 400
  unsigned long long* CAND = (unsigned long long*)(U + 9000); // 2*CAP u64
  // fp16 MFMA weight planes: alias the decoder-smalls region (dead during
  // wprep + convs). 1,327,104 f16 = 663,552 floats fits 716,800-float span.
  f16* WB_LID = (f16*)((((uintptr_t)X) + 15) & ~(uintptr_t)15);
  f16* WB_CAM = WB_LID + 884736;                // 2*9*12*8*512 = 884736
  f16* WB_HM1 = WB_CAM + 110592;                // 1*9*3*8*512  = 110592
  f16* WB_HM2 = WB_HM1 + 294912;                // 2*9*4*8*512  = 294912 (+36864)

  auto W = [&](int i) -> const float* { return ARENA + aoff[i]; };

  // ---- dtype detect + weight conversion -----------------------------------
  detect_k<<<1, 256, 0, stream>>>((const unsigned*)d_in[0], FLAGS);
  {
    CvtArgs a;
    for (int i = 2; i < 42; i++) { a.src[i - 2] = d_in[i]; a.n[i - 2] = in_sizes[i]; a.off[i - 2] = aoff[i]; }
    cvt_k<<<dim3(432, 40), 256, 0, stream>>>(a, ARENA, FLAGS);
  }
  wprep_k<<<3456, 256, 0, stream>>>(W(2), WB_LID, 128, 384, 12, 8, 1);
  wprep_k<<<432, 256, 0, stream>>>(W(4), WB_CAM, 128, 80, 3, 8, 0);
  wprep_k<<<1152, 256, 0, stream>>>(W(6), WB_HM1, 128, 128, 4, 8, 1);
  wprep_k<<<144, 256, 0, stream>>>(W(10), WB_HM2, 10, 128, 4, 1, 1);

  auto gemm = [&](const float* A, int lda, const float* Wp, const float* bias, int act,
                  const float* res, float* C, int ldc, int M, int N, int K) {
    dim3 grid((M + 63) / 64, (N + 63) / 64, 1);
    gemm_k<float, float><<<grid, 256, 0, stream>>>(
        A, (const float*)nullptr, lda, 0, 0L, Wp, bias, act, res,
        nullptr, nullptr, nullptr, nullptr, C, ldc, 0, 0L, M, N, K);
  };

  // ---- backbone convs (MFMA, fp16 split for fp32-class accuracy) ----------
  conv_mfma<3, 1, 4, 4, 2, float><<<dim3(540, 1, 2), 256, 0, stream>>>(
      d_in[0], FLAGS, 1, (long)384 * HW, WB_LID, W(3), nullptr, nullptr, 0,
      LIDF, (long)128 * HW, 128, 384, 12, 8);
  conv_mfma<1, 1, 4, 4, 2, bf16><<<dim3(540, 1, 2), 256, 0, stream>>>(
      d_in[1], FLAGS, 1, (long)80 * HW, WB_CAM, W(5), nullptr, nullptr, 0,
      CAMF16, (long)128 * HW, 128, 80, 3, 8);
  for (int b = 0; b < 2; b++) {
    conv_mfma<3, 1, 4, 4, 2, float><<<dim3(540, 1, 1), 256, 0, stream>>>(
        LIDF + (long)b * 128 * HW, FLAGS, 0, 0L, WB_HM1, W(7), W(8), W(9), 1,
        HBUF, 0L, 128, 128, 4, 8);
    conv_mfma<3, 4, 1, 1, 1, float><<<dim3(540, 1, 1), 256, 0, stream>>>(
        HBUF, FLAGS, 0, 0L, WB_HM2, W(11), nullptr, nullptr, 2,
        HEAT + (long)b * NCLS * HW, 0L, 10, 128, 4, 1);
  }

  // ---- NMS + exact top-200 ------------------------------------------------
  nms_k<<<(2 * NCLS * HW + 255) / 256, 256, 0, stream>>>(HEAT, SCORE);
  zero_u32<<<(8196 + 255) / 256, 256, 0, stream>>>(U, 8196);
  hist_k<<<dim3(240, 2), 256, 0, stream>>>(SCORE, HIST);
  thresh_k<<<2, 256, 0, stream>>>(HIST, THR);
  collect_k<<<(2 * NCLS * HW + 255) / 256, 256, 0, stream>>>(SCORE, THR, ACNT, CAND);
  select_k<<<2, 64, 0, stream>>>(CAND, ACNT, TOPC, TOPI, QPA);
  gather_k<<<200, 256, 0, stream>>>(LIDF, TOPC, TOPI, W(12), W(13), X);

  // ---- decoder layers -----------------------------------------------------
  for (int i = 0; i < 2; i++) {
    const float* qcur = (i == 0) ? QPA : QPB;
    float* qnext = (i == 0) ? QPB : QPA;
    // query pos-embed
    pe_stage1<<<200, 256, 0, stream>>>(qcur, W(14) + (i * 2 + 0) * 256,
        W(15) + (i * 2 + 0) * 128, W(16) + (i * 2 + 0) * 128, W(17) + (i * 2 + 0) * 128,
        T1Q, 400);
    gemm(T1Q, 128, W(18) + (size_t)(i * 2 + 0) * 16384, W(19) + (i * 2 + 0) * 128,
         0, nullptr, QPE, 128, 400, 128, 128);
    // key pos-embed (BEV grid fused into staging), stored transposed [128][HW] bf16
    gemm_k<float, bf16><<<dim3(507, 2, 1), 256, 0, stream>>>(
        ARENA, (const float*)nullptr, 0, 2, 0L,
        W(18) + (size_t)(i * 2 + 1) * 16384, W(19) + (i * 2 + 1) * 128, 0, nullptr,
        W(14) + (i * 2 + 1) * 256, W(15) + (i * 2 + 1) * 128,
        W(16) + (i * 2 + 1) * 128, W(17) + (i * 2 + 1) * 128,
        KPET16, HW, 1, 0L, 32400, 128, 128);
    // self-attention
    add2_k<<<200, 256, 0, stream>>>(X, QPE, XQ, 51200);
    gemm(XQ, 128, W(20) + (size_t)(i * 2 + 0) * 49152, W(21) + (i * 2 + 0) * 384,
         0, nullptr, SQKV, 384, 400, 384, 128);
    self_attn_k<<<dim3(200, 8, 2), 64, 0, stream>>>(SQKV, SAO);
    gemm(SAO, 128, W(22) + (size_t)(i * 2 + 0) * 16384, W(23) + (i * 2 + 0) * 128,
         0, X, PRE, 128, 400, 128, 128);
    ln_k<<<100, 256, 0, stream>>>(PRE, W(24) + (i * 3 + 0) * 128, W(25) + (i * 3 + 0) * 128, X);
    // cross-attention
    add2_k<<<200, 256, 0, stream>>>(X, QPE, XQ, 51200);
    gemm(XQ, 128, W(20) + (size_t)(i * 2 + 1) * 49152, W(21) + (i * 2 + 1) * 384,
         0, nullptr, QH2, 128, 400, 128, 128);
    gemm_k<bf16, bf16><<<dim3(507, 4, 2), 256, 0, stream>>>(
        CAMF16, KPET16, HW, 1, (long)128 * HW,
        W(20) + (size_t)(i * 2 + 1) * 49152 + 16384, W(21) + (i * 2 + 1) * 384 + 128,
        0, nullptr, nullptr, nullptr, nullptr, nullptr,
        KVT16, HW, 1, (long)256 * HW, 32400, 256, 128);
    flash_k<<<dim3(NSPLIT, 8, 4), 256, 0, stream>>>(QH2, KVT16, PART);
    combine_k<<<200, 256, 0, stream>>>(PART, CAO);
    gemm(CAO, 128, W(22) + (size_t)(i * 2 + 1) * 16384, W(23) + (i * 2 + 1) * 128,
         0, X, PRE, 128, 400, 128, 128);
    ln_k<<<100, 256, 0, stream>>>(PRE, W(24) + (i * 3 + 1) * 128, W(25) + (i * 3 + 1) * 128, X);
    // FFN
    gemm(X, 128, W(26) + (size_t)i * 32768, W(27) + i * 256,
         1, nullptr, FF1, 256, 400, 256, 128);
    gemm(FF1, 256, W(28) + (size_t)i * 32768, W(29) + i * 128,
         0, X, PRE, 128, 400, 128, 256);
    ln_k<<<100, 256, 0, stream>>>(PRE, W(24) + (i * 3 + 2) * 128, W(25) + (i * 3 + 2) * 128, X);
    // prediction heads
    conv1d_k<<<dim3(200, 2), 128, 0, stream>>>(X, W(30) + (size_t)i * 49152,
        W(31) + i * 128, W(32) + i * 128, W(33) + i * 128, YC);
    head2_k<<<4, 256, 0, stream>>>(YC, W(34) + (size_t)i * 768, W(35) + i * 2,
        qcur, CENT, 2, qnext);
    conv1d_k<<<dim3(200, 2), 128, 0, stream>>>(X, W(36) + (size_t)i * 49152,
        W(37) + i * 128, W(38) + i * 128, W(39) + i * 128, YC);
    head2_k<<<16, 256, 0, stream>>>(YC, W(40) + (size_t)i * 3840, W(41) + i * 10,
        nullptr, HMP, 10, nullptr);
  }
  out_k<<<19, 256, 0, stream>>>(CENT, HMP, d_out, FLAGS);
}

// Round 8
// 2638.640 us; speedup vs baseline: 2.0877x; 1.0224x over previous
//
#include <hip/hip_runtime.h>
#include <hip/hip_bf16.h>

typedef __hip_bfloat16 bf16;
typedef _Float16 f16;

#define HW 32400
#define NCLS 10
#define PQ 200
#define HIDDEN 128
#define NSPLIT 45
#define SPLITLEN 720    // 45*720 = 32400 exactly
#define QT 100
#define CAP 6144
#define NBIN 4096

typedef __attribute__((ext_vector_type(8))) _Float16 half8;
typedef __attribute__((ext_vector_type(8))) short short8;
typedef __attribute__((ext_vector_type(4))) short short4v;
typedef __attribute__((ext_vector_type(4))) float f32x4;

__device__ __forceinline__ float b2f(bf16 v) { return __bfloat162float(v); }
__device__ __forceinline__ void stf(float* p, float v) { *p = v; }
__device__ __forceinline__ void stf(bf16* p, float v) { *p = __float2bfloat16(v); }
// runtime-dtype load: isbf!=0 -> bf16 array, else fp32 array
__device__ __forceinline__ float ldsel(const void* p, long i, unsigned isbf) {
  return isbf ? __bfloat162float(((const bf16*)p)[i]) : ((const float*)p)[i];
}
__device__ __forceinline__ float ldf(const float* p, long i) { return p[i]; }
__device__ __forceinline__ float ldf(const bf16* p, long i) { return __bfloat162float(p[i]); }
__device__ __forceinline__ short f2bf_bits(float v) {
  union { bf16 h; short s; } u; u.h = __float2bfloat16(v); return u.s;
}

// ---------------------------------------------------------------------------
// dtype detection (bf16 vs fp32 inputs) -> FLAGS[0]
// ---------------------------------------------------------------------------
__global__ void detect_k(const unsigned* __restrict__ L, unsigned* __restrict__ FLAGS)
{
  __shared__ unsigned cnt[2];
  int tid = threadIdx.x;
  if (tid < 2) cnt[tid] = 0;
  __syncthreads();
  unsigned nz = 0, pl = 0;
  for (int w = tid; w < 4096; w += 256) {
    unsigned u = L[w];
    if (u) {
      nz++;
      unsigned e = (u >> 7) & 0xFF;
      if (e >= 110 && e <= 140) pl++;
    }
  }
  atomicAdd(&cnt[0], nz);
  atomicAdd(&cnt[1], pl);
  __syncthreads();
  if (tid == 0) {
    FLAGS[0] = (2u * cnt[1] > cnt[0]) ? 1u : 0u;
    FLAGS[1] = 0u;
  }
}

// batched weight conversion into fp32 arena (exact in both modes)
struct CvtArgs { const void* src[40]; int n[40]; int off[40]; };
__global__ __launch_bounds__(256) void cvt_k(CvtArgs a, float* __restrict__ dst,
                                             const unsigned* __restrict__ FLAGS)
{
  int j = blockIdx.y;
  unsigned isbf = FLAGS[0];
  int n = a.n[j];
  const void* s = a.src[j];
  float* d = dst + a.off[j];
  for (int t = blockIdx.x * 256 + threadIdx.x; t < n; t += gridDim.x * 256)
    d[t] = ldsel(s, t, isbf);
}

// ---------------------------------------------------------------------------
// Conv weight pre-swizzle into MFMA fragment order, fp16 hi (+scaled lo).
// WB[plane][tap][kb][nt][n16][k32] ; value = W[nt*16+n16][kb*32+k][ty][tx]
// plane1 = fp16((v - hi) * 4096)  (scale keeps lo in fp16 normal range)
// ---------------------------------------------------------------------------
__global__ __launch_bounds__(256) void wprep_k(const float* __restrict__ Wsrc,
    f16* __restrict__ WB, int N, int K, int KB, int NTG, int split)
{
  long total = (long)(split ? 2 : 1) * 9 * KB * NTG * 512;
  for (long t = (long)blockIdx.x * 256 + threadIdx.x; t < total;
       t += (long)gridDim.x * 256) {
    long r = t;
    int k = (int)(r & 31); r >>= 5;
    int n16 = (int)(r & 15); r >>= 4;
    int nt = (int)(r % NTG); r /= NTG;
    int kb = (int)(r % KB); r /= KB;
    int tap = (int)(r % 9); r /= 9;
    int plane = (int)r;
    int n = nt * 16 + n16, kk = kb * 32 + k;
    float v = 0.f;
    if (n < N && kk < K) v = Wsrc[((long)n * K + kk) * 9 + tap];
    f16 h = (f16)v;
    f16 outv = h;
    if (plane == 1) outv = (f16)((v - (float)h) * 4096.0f);
    WB[t] = outv;
  }
}

// ---------------------------------------------------------------------------
// MFMA conv2d 3x3 SAME as 9 shifted GEMMs over 64-pixel row chunks (60 valid).
// SPLIT=3: fp32-accurate fp16 split: acc = Σhi·hi' + (Σ(lo·hi'+hi·lo'))/4096,
// lo pre-scaled by 4096 (fp16-normal). SPLIT=1: plain fp16.
// Wave tiling (WM,WN,MT,NT): R8 uses (2,2,2,4) — halves per-MFMA LDS reads
// vs (1,4,4,2) by amortizing each A-fragment over 64 output columns.
// ---------------------------------------------------------------------------
template <int SPLIT, int WM, int WN, int MT, int NT, typename CT>
__global__ __launch_bounds__(256) void conv_mfma(
    const void* __restrict__ A, const unsigned* __restrict__ FLAGS, int dyn,
    long abatch,
    const f16* __restrict__ WB, const float* __restrict__ bias,
    const float* __restrict__ g, const float* __restrict__ beta, int act,
    CT* __restrict__ C, long cbatch, int N, int K, int KB, int NTG)
{
  constexpr int AW = 3 * 66 * 40;            // [ty][px][k] k-stride 40 (bank spread)
  __shared__ __align__(16) f16 Ah[AW];
  __shared__ __align__(16) f16 Al[SPLIT == 3 ? AW : 8];
  unsigned isbf = dyn ? FLAGS[0] : 0u;
  int bz = blockIdx.z;
  int y = blockIdx.x / 3;
  int x0 = (blockIdx.x % 3) * 60;
  int tid = threadIdx.x;
  int w = tid >> 6, lane = tid & 63;
  int lane15 = lane & 15, lgrp = lane >> 4;
  int wm = w % WM, wn = w / WM;
  int mbase = wm * MT * 16;
  int nbase = wn * NT * 16;
  f32x4 accM[MT][NT] = {};
  f32x4 accC[SPLIT == 3 ? MT : 1][SPLIT == 3 ? NT : 1] = {};
  long planeStride = (long)9 * KB * NTG * 512;

  for (int kb = 0; kb < KB; kb++) {
    __syncthreads();
    for (int e = tid; e < 3 * 32 * 66; e += 256) {
      int row = e / (32 * 66);
      int rem = e - row * (32 * 66);
      int k = rem / 66;
      int px = rem - k * 66;
      int gx = x0 + px - 1, gy = y + row - 1;
      int kk = kb * 32 + k;
      float v = 0.f;
      if (gx >= 0 && gx < 180 && gy >= 0 && gy < 180 && kk < K)
        v = ldsel(A, (long)bz * abatch + (long)kk * HW + gy * 180 + gx, isbf);
      f16 h = (f16)v;
      Ah[(row * 66 + px) * 40 + k] = h;
      if constexpr (SPLIT == 3)
        Al[(row * 66 + px) * 40 + k] = (f16)((v - (float)h) * 4096.0f);
    }
    __syncthreads();
#pragma unroll
    for (int tap = 0; tap < 9; tap++) {
      int ty = tap / 3, tx = tap % 3;
      const f16* wb = WB + (((long)tap * KB + kb) * NTG) * 512;
      half8 bh[NT], bl[SPLIT == 3 ? NT : 1];
#pragma unroll
      for (int nt = 0; nt < NT; nt++) {
        long o = (long)(wn * NT + nt) * 512 + lane15 * 32 + lgrp * 8;
        bh[nt] = *(const half8*)(wb + o);
        if constexpr (SPLIT == 3) bl[nt] = *(const half8*)(wb + planeStride + o);
      }
      half8 ah[MT], al[SPLIT == 3 ? MT : 1];
#pragma unroll
      for (int mt = 0; mt < MT; mt++) {
        int px = mbase + mt * 16 + lane15 + tx;
        int o = (ty * 66 + px) * 40 + lgrp * 8;
        ah[mt] = *(const half8*)&Ah[o];
        if constexpr (SPLIT == 3) al[mt] = *(const half8*)&Al[o];
      }
#pragma unroll
      for (int mt = 0; mt < MT; mt++)
#pragma unroll
        for (int nt = 0; nt < NT; nt++) {
          accM[mt][nt] = __builtin_amdgcn_mfma_f32_16x16x32_f16(
              ah[mt], bh[nt], accM[mt][nt], 0, 0, 0);
          if constexpr (SPLIT == 3) {
            accC[mt][nt] = __builtin_amdgcn_mfma_f32_16x16x32_f16(
                al[mt], bh[nt], accC[mt][nt], 0, 0, 0);
            accC[mt][nt] = __builtin_amdgcn_mfma_f32_16x16x32_f16(
                ah[mt], bl[nt], accC[mt][nt], 0, 0, 0);
          }
        }
    }
  }
  int pixbase = y * 180 + x0;
#pragma unroll
  for (int mt = 0; mt < MT; mt++) {
    int m = mbase + mt * 16 + lgrp * 4;
    if (m >= 60) continue;
#pragma unroll
    for (int nt = 0; nt < NT; nt++) {
      int n = nbase + nt * 16 + lane15;
      if (n >= N) continue;
      float bi = bias[n];
      float gg = g ? g[n] : 1.f;
      float bb = g ? beta[n] : 0.f;
      long base = (long)bz * cbatch + (long)n * HW + pixbase + m;
      if constexpr (sizeof(CT) == 4) {
        f32x4 ov;
#pragma unroll
        for (int r = 0; r < 4; r++) {
          float v = accM[mt][nt][r];
          if constexpr (SPLIT == 3) v += accC[mt][nt][r] * (1.f / 4096.f);
          v += bi;
          if (g) v = v * gg + bb;
          if (act == 1) v = fmaxf(v, 0.f);
          else if (act == 2) v = 1.f / (1.f + expf(-v));
          ov[r] = v;
        }
        *(f32x4*)&C[base] = ov;
      } else {
        short4v ov;
#pragma unroll
        for (int r = 0; r < 4; r++) {
          float v = accM[mt][nt][r];
          if constexpr (SPLIT == 3) v += accC[mt][nt][r] * (1.f / 4096.f);
          v += bi;
          if (g) v = v * gg + bb;
          if (act == 1) v = fmaxf(v, 0.f);
          ov[r] = f2bf_bits(v);
        }
        *(short4v*)&C[base] = ov;
      }
    }
  }
}

// ---------------------------------------------------------------------------
// bf16 MFMA KV projection: C = (A1+A2) @ W^T + bias.
// A1 bf16 [b][128][HW] (CAMF16), A2 bf16 [128][HW] (KPET16), W fp32 row-major
// [n][128] (k contiguous -> B-fragment read straight from global + cvt),
// C bf16 [b][256][HW]. Block: 64m x 64n, 4 waves (2x2), wave 32m x 32n.
// ---------------------------------------------------------------------------
__global__ __launch_bounds__(256) void kvproj_k(
    const bf16* __restrict__ A1, const bf16* __restrict__ A2,
    const float* __restrict__ Wf, const float* __restrict__ bias,
    bf16* __restrict__ C)
{
  __shared__ __align__(16) short As[64 * 40];
  int m0 = blockIdx.x * 64;
  int n0 = blockIdx.y * 64;
  int b = blockIdx.z;
  int tid = threadIdx.x;
  int w = tid >> 6, lane = tid & 63;
  int lane15 = lane & 15, lgrp = lane >> 4;
  int wm = w & 1, wn = w >> 1;
  const bf16* A1b = A1 + (long)b * 128 * HW;
  f32x4 acc[2][2] = {};
  for (int kb = 0; kb < 4; kb++) {
    __syncthreads();
    for (int e = tid; e < 2048; e += 256) {
      int k = e >> 6, m = e & 63;
      int gm = m0 + m;
      float v = 0.f;
      if (gm < HW) {
        long idx = (long)(kb * 32 + k) * HW + gm;
        v = b2f(A1b[idx]) + b2f(A2[idx]);
      }
      As[m * 40 + k] = f2bf_bits(v);
    }
    __syncthreads();
    short8 bh[2];
#pragma unroll
    for (int nt = 0; nt < 2; nt++) {
      int n = n0 + wn * 32 + nt * 16 + lane15;
      const float* wr = Wf + (long)n * 128 + kb * 32 + lgrp * 8;
      float4 w0 = *(const float4*)wr;
      float4 w1 = *(const float4*)(wr + 4);
      short8 t;
      t[0] = f2bf_bits(w0.x); t[1] = f2bf_bits(w0.y);
      t[2] = f2bf_bits(w0.z); t[3] = f2bf_bits(w0.w);
      t[4] = f2bf_bits(w1.x); t[5] = f2bf_bits(w1.y);
      t[6] = f2bf_bits(w1.z); t[7] = f2bf_bits(w1.w);
      bh[nt] = t;
    }
    short8 ah[2];
#pragma unroll
    for (int mt = 0; mt < 2; mt++) {
      int m = wm * 32 + mt * 16 + lane15;
      ah[mt] = *(const short8*)&As[m * 40 + lgrp * 8];
    }
#pragma unroll
    for (int mt = 0; mt < 2; mt++)
#pragma unroll
      for (int nt = 0; nt < 2; nt++)
        acc[mt][nt] = __builtin_amdgcn_mfma_f32_16x16x32_bf16(
            ah[mt], bh[nt], acc[mt][nt], 0, 0, 0);
  }
#pragma unroll
  for (int mt = 0; mt < 2; mt++) {
    int mq = m0 + wm * 32 + mt * 16 + lgrp * 4;
    if (mq >= HW) continue;
#pragma unroll
    for (int nt = 0; nt < 2; nt++) {
      int n = n0 + wn * 32 + nt * 16 + lane15;
      float bi = bias[n];
      short4v ov;
#pragma unroll
      for (int r = 0; r < 4; r++) ov[r] = f2bf_bits(acc[mt][nt][r] + bi);
      *(short4v*)&C[(long)b * 256 * HW + (long)n * HW + mq] = ov;
    }
  }
}

// ---------------------------------------------------------------------------
// Generic tiled GEMM: C = act(A @ W^T + bias) (+ res)
// amode 0: A[m*lda+k].  amode 2: fused BEV pos-embed stage-1 as A.
// cmode 0: C[m*ldc+n] ; cmode 1: C[n*ldc+m].  K multiple of 16.
// ---------------------------------------------------------------------------
template <typename AT, typename CT>
__global__ __launch_bounds__(256) void gemm_k(
    const AT* __restrict__ A, const AT* __restrict__ A2, int lda, int amode,
    long abatch,
    const float* __restrict__ W, const float* __restrict__ bias, int act,
    const float* __restrict__ res,
    const float* __restrict__ pe1w, const float* __restrict__ pe1b,
    const float* __restrict__ pe1g, const float* __restrict__ pe1bt,
    CT* __restrict__ C, int ldc, int cmode, long cbatch,
    int M, int N, int K)
{
  __shared__ __align__(16) float As[16][68];
  __shared__ __align__(16) float Ws[16][68];
  int b = blockIdx.z;
  int m0 = blockIdx.x * 64, n0 = blockIdx.y * 64;
  int tid = threadIdx.x;
  int nt = tid & 15, mt = tid >> 4;
  float acc[4][4] = {};
  const AT* Ab = A + (long)b * abatch;
  for (int k0 = 0; k0 < K; k0 += 16) {
    if (amode == 0) {
      for (int e = tid; e < 1024; e += 256) {
        int m = e >> 4, k = e & 15;
        float v = 0.f;
        if (m0 + m < M) v = ldf(Ab, (long)(m0 + m) * lda + k0 + k);
        As[k][m] = v;
      }
    } else if (amode == 1) {
      for (int e = tid; e < 1024; e += 256) {
        int m = e & 63, k = e >> 6;
        float v = 0.f;
        if (m0 + m < M) {
          long idx = (long)(k0 + k) * lda + m0 + m;
          v = ldf(Ab, idx);
          if (A2) v += ldf(A2, idx);
        }
        As[k][m] = v;
      }
    } else {
      for (int e = tid; e < 1024; e += 256) {
        int m = e & 63, k = e >> 6;
        float v = 0.f;
        int gm = m0 + m;
        if (gm < M) {
          float p0 = (float)(gm / 180) + 0.5f;
          float p1 = (float)(gm % 180) + 0.5f;
          int kk = k0 + k;
          float t = p0 * pe1w[kk * 2] + p1 * pe1w[kk * 2 + 1] + pe1b[kk];
          t = t * pe1g[kk] + pe1bt[kk];
          v = fmaxf(t, 0.f);
        }
        As[k][m] = v;
      }
    }
    for (int e = tid; e < 1024; e += 256) {
      int n = e >> 4, k = e & 15;
      float v = 0.f;
      if (n0 + n < N) v = W[(long)(n0 + n) * K + k0 + k];
      Ws[k][n] = v;
    }
    __syncthreads();
#pragma unroll
    for (int kk = 0; kk < 16; kk++) {
      float4 av = *(const float4*)&As[kk][mt * 4];
      float4 wv = *(const float4*)&Ws[kk][nt * 4];
      float am[4] = {av.x, av.y, av.z, av.w};
      float wn[4] = {wv.x, wv.y, wv.z, wv.w};
#pragma unroll
      for (int mi = 0; mi < 4; mi++)
#pragma unroll
        for (int ni = 0; ni < 4; ni++)
          acc[mi][ni] = fmaf(am[mi], wn[ni], acc[mi][ni]);
    }
    __syncthreads();
  }
#pragma unroll
  for (int mi = 0; mi < 4; mi++) {
    int m = m0 + mt * 4 + mi;
    if (m >= M) continue;
#pragma unroll
    for (int ni = 0; ni < 4; ni++) {
      int n = n0 + nt * 4 + ni;
      if (n >= N) continue;
      float v = acc[mi][ni];
      if (bias) v += bias[n];
      if (act == 1) v = fmaxf(v, 0.f);
      if (res) v += res[(long)m * ldc + n];
      long ci = (cmode == 0) ? ((long)b * cbatch + (long)m * ldc + n)
                             : ((long)b * cbatch + (long)n * ldc + m);
      stf(&C[ci], v);
    }
  }
}

// ---------------------------------------------------------------------------
__global__ void nms_k(const float* __restrict__ HEAT, float* __restrict__ SCORE)
{
  int t = blockIdx.x * 256 + threadIdx.x;
  if (t >= 2 * NCLS * HW) return;
  int b = t / (NCLS * HW); int r = t % (NCLS * HW);
  int cls = r / HW; int n = r % HW;
  const float* hb = HEAT + ((long)(b * NCLS + cls)) * HW;
  float v = hb[n];
  bool keep = true;
  if (cls < 8) {
    int y = n / 180, x = n % 180;
    if (y == 0 || y == 179 || x == 0 || x == 179) keep = false;
    else {
      float mx = -1e30f;
#pragma unroll
      for (int dy = -1; dy <= 1; dy++)
#pragma unroll
        for (int dx = -1; dx <= 1; dx++)
          mx = fmaxf(mx, hb[(y + dy) * 180 + x + dx]);
      keep = (v == mx);
    }
  }
  SCORE[(long)b * (NCLS * HW) + r] = keep ? v : 0.f;
}

__global__ void zero_u32(unsigned* p, int n)
{
  int t = blockIdx.x * 256 + threadIdx.x;
  if (t < n) p[t] = 0;
}

__global__ __launch_bounds__(256) void hist_k(const float* __restrict__ SCORE,
                                              unsigned* __restrict__ HIST)
{
  __shared__ unsigned lh[NBIN];
  int b = blockIdx.y;
  for (int e = threadIdx.x; e < NBIN; e += 256) lh[e] = 0;
  __syncthreads();
  int start = blockIdx.x * 1350;
  const float* sb = SCORE + (long)b * (NCLS * HW);
  for (int e = start + threadIdx.x; e < start + 1350; e += 256) {
    unsigned bits = __float_as_uint(sb[e]);
    atomicAdd(&lh[bits >> 18], 1u);
  }
  __syncthreads();
  for (int e = threadIdx.x; e < NBIN; e += 256) {
    unsigned c = lh[e];
    if (c) atomicAdd(&HIST[b * NBIN + e], c);
  }
}

__global__ void thresh_k(const unsigned* __restrict__ HIST, unsigned* __restrict__ THR)
{
  __shared__ unsigned ps[256];
  int b = blockIdx.x;
  const unsigned* hb = HIST + b * NBIN;
  unsigned s = 0;
  for (int j = 0; j < 16; j++) s += hb[threadIdx.x * 16 + j];
  ps[threadIdx.x] = s;
  __syncthreads();
  if (threadIdx.x == 0) {
    unsigned cum = 0; int t = 255;
    for (; t > 0; t--) { if (cum + ps[t] >= PQ) break; cum += ps[t]; }
    int bin = t * 16 + 15;
    for (; bin > t * 16; bin--) { unsigned c = hb[bin]; if (cum + c >= PQ) break; cum += c; }
    if (bin < 1) bin = 1;
    THR[b] = (unsigned)bin;
  }
}

__global__ void collect_k(const float* __restrict__ SCORE, const unsigned* __restrict__ THR,
                          unsigned* __restrict__ ACNT, unsigned long long* __restrict__ CAND)
{
  int t = blockIdx.x * 256 + threadIdx.x;
  if (t >= 2 * NCLS * HW) return;
  int b = t / (NCLS * HW); int r = t % (NCLS * HW);
  float v = SCORE[(long)b * (NCLS * HW) + r];
  unsigned bits = __float_as_uint(v);
  if ((bits >> 18) >= THR[b]) {
    unsigned slot = atomicAdd(&ACNT[b], 1u);
    if (slot < CAP) CAND[(long)b * CAP + slot] =
        ((unsigned long long)bits << 32) | (unsigned)(~r);
  }
}

__global__ __launch_bounds__(64) void select_k(
    const unsigned long long* __restrict__ CAND, const unsigned* __restrict__ ACNT,
    unsigned* __restrict__ TOPC, unsigned* __restrict__ TOPI, float* __restrict__ QPA)
{
  __shared__ unsigned long long cnd[CAP];
  int b = blockIdx.x;
  int lane = threadIdx.x;
  unsigned cnt = ACNT[b]; if (cnt > CAP) cnt = CAP;
  for (int e = lane; e < (int)cnt; e += 64) cnd[e] = CAND[(long)b * CAP + e];
  __syncthreads();
  for (int p = 0; p < PQ; p++) {
    unsigned long long best = 0;
    for (int e = lane; e < (int)cnt; e += 64) { unsigned long long c = cnd[e]; if (c > best) best = c; }
#pragma unroll
    for (int o = 32; o; o >>= 1) {
      unsigned long long other = __shfl_xor(best, o, 64);
      if (other > best) best = other;
    }
    for (int e = lane; e < (int)cnt; e += 64) if (best != 0 && cnd[e] == best) cnd[e] = 0;
    if (lane == 0) {
      unsigned idx = (best == 0) ? 0u : ~(unsigned)(best & 0xFFFFFFFFull);
      if (idx >= NCLS * HW) idx = 0;
      unsigned cls = idx / HW, n = idx % HW;
      TOPC[b * PQ + p] = cls; TOPI[b * PQ + p] = n;
      QPA[((long)(b * PQ + p)) * 2 + 0] = (float)(n / 180) + 0.5f;
      QPA[((long)(b * PQ + p)) * 2 + 1] = (float)(n % 180) + 0.5f;
    }
    __syncthreads();
  }
}

__global__ void gather_k(const float* __restrict__ LIDF, const unsigned* __restrict__ TOPC,
                         const unsigned* __restrict__ TOPI, const float* __restrict__ cew,
                         const float* __restrict__ ceb, float* __restrict__ X)
{
  int t = blockIdx.x * 256 + threadIdx.x;
  if (t >= 2 * PQ * HIDDEN) return;
  int c = t & 127; int r = t >> 7; int p = r % PQ; int b = r / PQ;
  unsigned n = TOPI[b * PQ + p]; unsigned cls = TOPC[b * PQ + p];
  if (n >= HW) n = 0;
  if (cls >= NCLS) cls = 0;
  X[t] = LIDF[((long)(b * HIDDEN + c)) * HW + n] + cew[c * NCLS + cls] + ceb[c];
}

// posembed stage 1 for queries only
__global__ void pe_stage1(const float* __restrict__ qpos,
                          const float* __restrict__ w1, const float* __restrict__ b1,
                          const float* __restrict__ g, const float* __restrict__ bt,
                          float* __restrict__ T1, int M)
{
  int t = blockIdx.x * 256 + threadIdx.x;
  if (t >= M * HIDDEN) return;
  int c = t & 127; int m = t >> 7;
  float p0 = qpos[m * 2], p1 = qpos[m * 2 + 1];
  float v = p0 * w1[c * 2] + p1 * w1[c * 2 + 1] + b1[c];
  v = v * g[c] + bt[c];
  T1[t] = fmaxf(v, 0.f);
}

__global__ void add2_k(const float* __restrict__ a, const float* __restrict__ b,
                       float* __restrict__ o, int n)
{
  int t = blockIdx.x * 256 + threadIdx.x;
  if (t < n) o[t] = a[t] + b[t];
}

__global__ __launch_bounds__(64) void self_attn_k(const float* __restrict__ SQKV,
                                                  float* __restrict__ SAO)
{
  int q = blockIdx.x, h = blockIdx.y, b = blockIdx.z;
  int lane = threadIdx.x;
  const float* qp = SQKV + ((long)(b * PQ + q)) * 384 + h * 16;
  float qv[16];
#pragma unroll
  for (int d = 0; d < 16; d++) qv[d] = qp[d] * 0.25f;
  float sv[4]; int kks[4]; int nk = 0;
  float lmax = -1e30f;
  for (int kk = lane; kk < PQ; kk += 64) {
    const float* kp = SQKV + ((long)(b * PQ + kk)) * 384 + 128 + h * 16;
    float s = 0.f;
#pragma unroll
    for (int d = 0; d < 16; d++) s = fmaf(qv[d], kp[d], s);
    sv[nk] = s; kks[nk] = kk; nk++;
    lmax = fmaxf(lmax, s);
  }
#pragma unroll
  for (int o = 32; o; o >>= 1) lmax = fmaxf(lmax, __shfl_xor(lmax, o, 64));
  float lsum = 0.f; float acc[16] = {};
  for (int t = 0; t < nk; t++) {
    float p = expf(sv[t] - lmax);
    lsum += p;
    const float* vp = SQKV + ((long)(b * PQ + kks[t])) * 384 + 256 + h * 16;
#pragma unroll
    for (int d = 0; d < 16; d++) acc[d] = fmaf(p, vp[d], acc[d]);
  }
#pragma unroll
  for (int o = 32; o; o >>= 1) lsum += __shfl_xor(lsum, o, 64);
#pragma unroll
  for (int d = 0; d < 16; d++) {
    float v = acc[d];
#pragma unroll
    for (int o = 32; o; o >>= 1) v += __shfl_xor(v, o, 64);
    if (lane == 0) SAO[((long)(b * PQ + q)) * HIDDEN + h * 16 + d] = v / lsum;
  }
}

// ---------------------------------------------------------------------------
// flash cross-attention, key-split, bank-conflict-free layouts (R7 design).
// ---------------------------------------------------------------------------
__global__ __launch_bounds__(256) void flash_k(const float* __restrict__ QH,
                                               const bf16* __restrict__ KVT,
                                               float* __restrict__ PART)
{
  int s = blockIdx.x, h = blockIdx.y;
  int b = blockIdx.z >> 1, qh = blockIdx.z & 1;
  int tid = threadIdx.x;
  __shared__ __align__(16) float sL[QT][36];
  __shared__ __align__(16) float qtL[16][104];
  __shared__ __align__(16) float kjL[16][36];
  __shared__ __align__(16) float vjL[16][36];
  __shared__ float mL[QT], lL[QT], aL[QT];
  int qbase = qh * QT;
  for (int e = tid; e < QT * 16; e += 256) {
    int q = e >> 4, d = e & 15;
    qtL[d][q] = QH[((long)(b * PQ + qbase + q)) * HIDDEN + h * 16 + d] * 0.25f;
  }
  if (tid < QT) { mL[tid] = -1e30f; lL[tid] = 0.f; }
  float ovr[4][2] = {};
  int pq = tid >> 3, pd = (tid & 7) * 2;
  int nbeg = s * SPLITLEN, nend = nbeg + SPLITLEN;
  const bf16* Kb = KVT + (long)b * 256 * HW + (long)(h * 16) * HW;
  const bf16* Vb = Kb + (long)128 * HW;
  __syncthreads();
  for (int n0 = nbeg; n0 < nend; n0 += 32) {
    int rem = nend - n0;
    for (int e = tid; e < 512; e += 256) {
      int d = e >> 5, j = e & 31;
      float kv = 0.f, vv = 0.f;
      if (j < rem) { kv = b2f(Kb[(long)d * HW + n0 + j]); vv = b2f(Vb[(long)d * HW + n0 + j]); }
      kjL[d][j] = kv; vjL[d][j] = vv;
    }
    __syncthreads();
    if (tid < 200) {
      int qg = tid >> 3, jg = tid & 7;
      int q0 = qg * 4, j0 = jg * 4;
      float acc[4][4] = {};
#pragma unroll
      for (int d = 0; d < 16; d++) {
        float4 kv = *(const float4*)&kjL[d][j0];
        float4 qv = *(const float4*)&qtL[d][q0];
        float qa[4] = {qv.x, qv.y, qv.z, qv.w};
        float ka[4] = {kv.x, kv.y, kv.z, kv.w};
#pragma unroll
        for (int i = 0; i < 4; i++)
#pragma unroll
          for (int jj = 0; jj < 4; jj++)
            acc[i][jj] = fmaf(qa[i], ka[jj], acc[i][jj]);
      }
#pragma unroll
      for (int i = 0; i < 4; i++) {
        float4 ov;
        ov.x = (j0 + 0 < rem) ? acc[i][0] : -1e30f;
        ov.y = (j0 + 1 < rem) ? acc[i][1] : -1e30f;
        ov.z = (j0 + 2 < rem) ? acc[i][2] : -1e30f;
        ov.w = (j0 + 3 < rem) ? acc[i][3] : -1e30f;
        *(float4*)&sL[q0 + i][j0] = ov;
      }
    }
    __syncthreads();
    if (tid < 2 * QT) {
      int q = tid >> 1, hf = tid & 1;
      int jb = hf * 16;
      float mx = -1e30f;
#pragma unroll
      for (int j = 0; j < 16; j++) mx = fmaxf(mx, sL[q][jb + j]);
      float mo = __shfl_xor(mx, 1, 64);
      float mold = mL[q];
      float mnew = fmaxf(fmaxf(mx, mo), mold);
      float lsum = 0.f;
#pragma unroll
      for (int j = 0; j < 16; j++) {
        float p = expf(sL[q][jb + j] - mnew);
        sL[q][jb + j] = p;
        lsum += p;
      }
      lsum += __shfl_xor(lsum, 1, 64);
      if (hf == 0) {
        float alpha = expf(mold - mnew);
        lL[q] = lL[q] * alpha + lsum;
        mL[q] = mnew;
        aL[q] = alpha;
      }
    }
    __syncthreads();
    if (tid < 200) {
#pragma unroll
      for (int i = 0; i < 4; i++) {
        float a = aL[pq + 25 * i];
        ovr[i][0] *= a; ovr[i][1] *= a;
      }
#pragma unroll
      for (int j0 = 0; j0 < 32; j0 += 4) {
        float4 v0 = *(const float4*)&vjL[pd][j0];
        float4 v1 = *(const float4*)&vjL[pd + 1][j0];
#pragma unroll
        for (int i = 0; i < 4; i++) {
          float4 p = *(const float4*)&sL[pq + 25 * i][j0];
          ovr[i][0] = fmaf(p.x, v0.x, ovr[i][0]);
          ovr[i][0] = fmaf(p.y, v0.y, ovr[i][0]);
          ovr[i][0] = fmaf(p.z, v0.z, ovr[i][0]);
          ovr[i][0] = fmaf(p.w, v0.w, ovr[i][0]);
          ovr[i][1] = fmaf(p.x, v1.x, ovr[i][1]);
          ovr[i][1] = fmaf(p.y, v1.y, ovr[i][1]);
          ovr[i][1] = fmaf(p.z, v1.z, ovr[i][1]);
          ovr[i][1] = fmaf(p.w, v1.w, ovr[i][1]);
        }
      }
    }
    __syncthreads();
  }
  long base = ((((long)(b * 8 + h)) * NSPLIT + s) * PQ) * 18;
  if (tid < 200) {
#pragma unroll
    for (int i = 0; i < 4; i++) {
      long ro = base + (long)(qbase + pq + 25 * i) * 18;
      PART[ro + pd] = ovr[i][0];
      PART[ro + pd + 1] = ovr[i][1];
    }
  }
  if (tid < QT) {
    long ro = base + (long)(qbase + tid) * 18;
    PART[ro + 16] = mL[tid];
    PART[ro + 17] = lL[tid];
  }
}

__global__ void combine_k(const float* __restrict__ PART, float* __restrict__ CAO)
{
  int t = blockIdx.x * 256 + threadIdx.x;
  if (t >= 2 * 8 * PQ * 16) return;
  int d = t & 15; int r = t >> 4;
  int q = r % PQ; r /= PQ;
  int h = r & 7; int b = r >> 3;
  long base = (((long)(b * 8 + h)) * NSPLIT) * PQ * 18 + (long)q * 18;
  float M = -1e30f;
  for (int s = 0; s < NSPLIT; s++) M = fmaxf(M, PART[base + (long)s * PQ * 18 + 16]);
  float L = 0.f, O = 0.f;
  for (int s = 0; s < NSPLIT; s++) {
    long p0 = base + (long)s * PQ * 18;
    float w = expf(PART[p0 + 16] - M);
    L += PART[p0 + 17] * w;
    O += PART[p0 + d] * w;
  }
  CAO[((long)(b * PQ + q)) * HIDDEN + h * 16 + d] = (L > 0.f) ? O / L : 0.f;
}

__global__ __launch_bounds__(256) void ln_k(const float* __restrict__ PRE,
                                            const float* __restrict__ g,
                                            const float* __restrict__ bta,
                                            float* __restrict__ X)
{
  int row = blockIdx.x * 4 + (threadIdx.x >> 6);
  int lane = threadIdx.x & 63;
  const float* p = PRE + (long)row * HIDDEN;
  float v0 = p[lane], v1 = p[lane + 64];
  float s = v0 + v1;
#pragma unroll
  for (int o = 32; o; o >>= 1) s += __shfl_xor(s, o, 64);
  float mu = s * (1.f / 128.f);
  float d0 = v0 - mu, d1 = v1 - mu;
  float vs = d0 * d0 + d1 * d1;
#pragma unroll
  for (int o = 32; o; o >>= 1) vs += __shfl_xor(vs, o, 64);
  float rs = rsqrtf(vs * (1.f / 128.f) + 1e-5f);
  float* xo = X + (long)row * HIDDEN;
  xo[lane] = d0 * rs * g[lane] + bta[lane];
  xo[lane + 64] = d1 * rs * g[lane + 64] + bta[lane + 64];
}

__global__ __launch_bounds__(128) void conv1d_k(const float* __restrict__ X,
                                                const float* __restrict__ w,
                                                const float* __restrict__ bias,
                                                const float* __restrict__ g,
                                                const float* __restrict__ beta,
                                                float* __restrict__ Y)
{
  int p = blockIdx.x, b = blockIdx.y;
  int co = threadIdx.x;
  __shared__ float xs[3][HIDDEN];
  for (int e = co; e < 3 * HIDDEN; e += HIDDEN) {
    int t = e >> 7, c = e & 127;
    int pp = p + t - 1;
    xs[t][c] = (pp >= 0 && pp < PQ) ? X[((long)(b * PQ + pp)) * HIDDEN + c] : 0.f;
  }
  __syncthreads();
  const float* wr = w + (long)co * HIDDEN * 3;
  float acc = 0.f;
  for (int c = 0; c < HIDDEN; c++) {
    acc = fmaf(xs[0][c], wr[c * 3 + 0], acc);
    acc = fmaf(xs[1][c], wr[c * 3 + 1], acc);
    acc = fmaf(xs[2][c], wr[c * 3 + 2], acc);
  }
  float v = (acc + bias[co]) * g[co] + beta[co];
  Y[((long)(b * PQ + p)) * HIDDEN + co] = fmaxf(v, 0.f);
}

__global__ void head2_k(const float* __restrict__ Y, const float* __restrict__ w,
                        const float* __restrict__ bias, const float* __restrict__ qpos,
                        float* __restrict__ OUT, int N, float* __restrict__ qnext)
{
  int t = blockIdx.x * 256 + threadIdx.x;
  if (t >= 2 * N * PQ) return;
  int p = t % PQ; int r = t / PQ; int co = r % N; int b = r / N;
  const float* wr = w + (long)co * HIDDEN * 3;
  float acc = 0.f;
  for (int tap = 0; tap < 3; tap++) {
    int pp = p + tap - 1;
    if (pp < 0 || pp >= PQ) continue;
    const float* yr = Y + ((long)(b * PQ + pp)) * HIDDEN;
    for (int c = 0; c < HIDDEN; c++)
      acc = fmaf(yr[c], wr[c * 3 + tap], acc);
  }
  float v = acc + bias[co];
  if (qpos) v += qpos[((long)(b * PQ + p)) * 2 + co];
  OUT[((long)(b * N + co)) * PQ + p] = v;
  if (qnext) qnext[((long)(b * PQ + p)) * 2 + co] = v;
}

__global__ void out_k(const float* __restrict__ CENT, const float* __restrict__ HMP,
                      void* __restrict__ out, const unsigned* __restrict__ FLAGS)
{
  int t = blockIdx.x * 256 + threadIdx.x;
  if (t >= 2 * 12 * PQ) return;
  int p = t % PQ; int r = t / PQ; int ch = r % 12; int b = r / 12;
  float v = (ch < 2) ? CENT[((long)(b * 2 + ch)) * PQ + p]
                     : HMP[((long)(b * 10 + ch - 2)) * PQ + p];
  if (FLAGS[0]) ((bf16*)out)[t] = __float2bfloat16(v);
  else          ((float*)out)[t] = v;
}

// ---------------------------------------------------------------------------
extern "C" void kernel_launch(void* const* d_in, const int* in_sizes, int n_in,
                              void* d_out, int out_size, void* d_ws, size_t ws_size,
                              hipStream_t stream)
{
  (void)n_in; (void)out_size; (void)ws_size;

  // ---- workspace layout (~80 MB == R3's validated watermark) --------------
  float* F = (float*)d_ws;
  size_t off = 0;
  int aoff[42];
  {
    size_t acc = 0;
    for (int i = 2; i < 42; i++) { aoff[i] = (int)acc; acc += (size_t)in_sizes[i]; }
    off = acc;
  }
  float* ARENA = F;
  float* LIDF = F + off;                        // [2][128][HW] fp32 (dead after gather)
  bf16*  KVT16 = (bf16*)(F + off);              // alias: [2][256][HW] bf16 (decoder)
  off += 8294400;
  float* HBUF = F + off;                        // [1][128][HW] fp32 (per-batch reuse)
  bf16*  KPET16 = (bf16*)(F + off);             // alias: [128][HW] bf16 (decoder)
  float* PART  = F + off;                       // alias: [2][8][NSPLIT][200][18]
  off += 4147200;
  bf16*  CAMF16 = (bf16*)(F + off);             // [2][128][HW] bf16 (live all run)
  off += 4147200;
  float* HEAT  = F + off;                       // [2][10][HW] (dead after nms)
  float* SCORE = F + off + 648000;              // (dead after collect)
  off += 1296000;
  float* X   = F + off; off += 51200;           // decoder smalls — all dead during
  float* XQ  = F + off; off += 51200;           // convs; WB_* aliases this region
  float* QPE = F + off; off += 51200;
  float* T1Q = F + off; off += 51200;
  float* SQKV = F + off; off += 153600;
  float* SAO = F + off; off += 51200;
  float* PRE = F + off; off += 51200;
  float* QH2 = F + off; off += 51200;
  float* CAO = F + off; off += 51200;
  float* FF1 = F + off; off += 102400;
  float* YC  = F + off; off += 51200;           // X..YC span = 716800 floats
  float* CENT = F + off; off += 800;
  float* HMP = F + off; off += 4000;
  float* QPA = F + off; off += 800;
  float* QPB = F + off; off += 800;
  unsigned* U = (unsigned*)(F + off);
  unsigned* HIST  = U;                          // [0, 8192)
  unsigned* ACNT  = U + 8192;                   // 2
  unsigned* THR   = U + 8194;                   // 2
  unsigned* FLAGS = U + 8196;                   // 2 (NOT zeroed by zero_u32)
  unsigned* TOPC  = U + 8198;                   // 400
  unsigned* TOPI  = U + 8598;                   // 400
  unsigned long long* CAND = (unsigned long long*)(U + 9000); // 2*CAP u64
  // fp16 MFMA weight planes: alias the decoder-smalls region (dead during
  // wprep + convs). 1,327,104 f16 = 663,552 floats fits 716,800-float span.
  f16* WB_LID = (f16*)((((uintptr_t)X) + 15) & ~(uintptr_t)15);
  f16* WB_CAM = WB_LID + 884736;                // 2*9*12*8*512 = 884736
  f16* WB_HM1 = WB_CAM + 110592;                // 1*9*3*8*512  = 110592
  f16* WB_HM2 = WB_HM1 + 294912;                // 2*9*4*8*512  = 294912 (+36864)

  auto W = [&](int i) -> const float* { return ARENA + aoff[i]; };

  // ---- dtype detect + weight conversion -----------------------------------
  detect_k<<<1, 256, 0, stream>>>((const unsigned*)d_in[0], FLAGS);
  {
    CvtArgs a;
    for (int i = 2; i < 42; i++) { a.src[i - 2] = d_in[i]; a.n[i - 2] = in_sizes[i]; a.off[i - 2] = aoff[i]; }
    cvt_k<<<dim3(432, 40), 256, 0, stream>>>(a, ARENA, FLAGS);
  }
  wprep_k<<<3456, 256, 0, stream>>>(W(2), WB_LID, 128, 384, 12, 8, 1);
  wprep_k<<<432, 256, 0, stream>>>(W(4), WB_CAM, 128, 80, 3, 8, 0);
  wprep_k<<<1152, 256, 0, stream>>>(W(6), WB_HM1, 128, 128, 4, 8, 1);
  wprep_k<<<144, 256, 0, stream>>>(W(10), WB_HM2, 10, 128, 4, 1, 1);

  auto gemm = [&](const float* A, int lda, const float* Wp, const float* bias, int act,
                  const float* res, float* C, int ldc, int M, int N, int K) {
    dim3 grid((M + 63) / 64, (N + 63) / 64, 1);
    gemm_k<float, float><<<grid, 256, 0, stream>>>(
        A, (const float*)nullptr, lda, 0, 0L, Wp, bias, act, res,
        nullptr, nullptr, nullptr, nullptr, C, ldc, 0, 0L, M, N, K);
  };

  // ---- backbone convs (MFMA, fp16 split, R8 wave tiling 2x2x2x4) ----------
  conv_mfma<3, 2, 2, 2, 4, float><<<dim3(540, 1, 2), 256, 0, stream>>>(
      d_in[0], FLAGS, 1, (long)384 * HW, WB_LID, W(3), nullptr, nullptr, 0,
      LIDF, (long)128 * HW, 128, 384, 12, 8);
  conv_mfma<1, 2, 2, 2, 4, bf16><<<dim3(540, 1, 2), 256, 0, stream>>>(
      d_in[1], FLAGS, 1, (long)80 * HW, WB_CAM, W(5), nullptr, nullptr, 0,
      CAMF16, (long)128 * HW, 128, 80, 3, 8);
  for (int b = 0; b < 2; b++) {
    conv_mfma<3, 2, 2, 2, 4, float><<<dim3(540, 1, 1), 256, 0, stream>>>(
        LIDF + (long)b * 128 * HW, FLAGS, 0, 0L, WB_HM1, W(7), W(8), W(9), 1,
        HBUF, 0L, 128, 128, 4, 8);
    conv_mfma<3, 4, 1, 1, 1, float><<<dim3(540, 1, 1), 256, 0, stream>>>(
        HBUF, FLAGS, 0, 0L, WB_HM2, W(11), nullptr, nullptr, 2,
        HEAT + (long)b * NCLS * HW, 0L, 10, 128, 4, 1);
  }

  // ---- NMS + exact top-200 ------------------------------------------------
  nms_k<<<(2 * NCLS * HW + 255) / 256, 256, 0, stream>>>(HEAT, SCORE);
  zero_u32<<<(8196 + 255) / 256, 256, 0, stream>>>(U, 8196);
  hist_k<<<dim3(240, 2), 256, 0, stream>>>(SCORE, HIST);
  thresh_k<<<2, 256, 0, stream>>>(HIST, THR);
  collect_k<<<(2 * NCLS * HW + 255) / 256, 256, 0, stream>>>(SCORE, THR, ACNT, CAND);
  select_k<<<2, 64, 0, stream>>>(CAND, ACNT, TOPC, TOPI, QPA);
  gather_k<<<200, 256, 0, stream>>>(LIDF, TOPC, TOPI, W(12), W(13), X);

  // ---- decoder layers -----------------------------------------------------
  for (int i = 0; i < 2; i++) {
    const float* qcur = (i == 0) ? QPA : QPB;
    float* qnext = (i == 0) ? QPB : QPA;
    // query pos-embed
    pe_stage1<<<200, 256, 0, stream>>>(qcur, W(14) + (i * 2 + 0) * 256,
        W(15) + (i * 2 + 0) * 128, W(16) + (i * 2 + 0) * 128, W(17) + (i * 2 + 0) * 128,
        T1Q, 400);
    gemm(T1Q, 128, W(18) + (size_t)(i * 2 + 0) * 16384, W(19) + (i * 2 + 0) * 128,
         0, nullptr, QPE, 128, 400, 128, 128);
    // key pos-embed (BEV grid fused into staging), stored transposed [128][HW] bf16
    gemm_k<float, bf16><<<dim3(507, 2, 1), 256, 0, stream>>>(
        ARENA, (const float*)nullptr, 0, 2, 0L,
        W(18) + (size_t)(i * 2 + 1) * 16384, W(19) + (i * 2 + 1) * 128, 0, nullptr,
        W(14) + (i * 2 + 1) * 256, W(15) + (i * 2 + 1) * 128,
        W(16) + (i * 2 + 1) * 128, W(17) + (i * 2 + 1) * 128,
        KPET16, HW, 1, 0L, 32400, 128, 128);
    // self-attention
    add2_k<<<200, 256, 0, stream>>>(X, QPE, XQ, 51200);
    gemm(XQ, 128, W(20) + (size_t)(i * 2 + 0) * 49152, W(21) + (i * 2 + 0) * 384,
         0, nullptr, SQKV, 384, 400, 384, 128);
    self_attn_k<<<dim3(200, 8, 2), 64, 0, stream>>>(SQKV, SAO);
    gemm(SAO, 128, W(22) + (size_t)(i * 2 + 0) * 16384, W(23) + (i * 2 + 0) * 128,
         0, X, PRE, 128, 400, 128, 128);
    ln_k<<<100, 256, 0, stream>>>(PRE, W(24) + (i * 3 + 0) * 128, W(25) + (i * 3 + 0) * 128, X);
    // cross-attention
    add2_k<<<200, 256, 0, stream>>>(X, QPE, XQ, 51200);
    gemm(XQ, 128, W(20) + (size_t)(i * 2 + 1) * 49152, W(21) + (i * 2 + 1) * 384,
         0, nullptr, QH2, 128, 400, 128, 128);
    kvproj_k<<<dim3(507, 4, 2), 256, 0, stream>>>(
        CAMF16, KPET16,
        W(20) + (size_t)(i * 2 + 1) * 49152 + 16384,
        W(21) + (i * 2 + 1) * 384 + 128, KVT16);
    flash_k<<<dim3(NSPLIT, 8, 4), 256, 0, stream>>>(QH2, KVT16, PART);
    combine_k<<<200, 256, 0, stream>>>(PART, CAO);
    gemm(CAO, 128, W(22) + (size_t)(i * 2 + 1) * 16384, W(23) + (i * 2 + 1) * 128,
         0, X, PRE, 128, 400, 128, 128);
    ln_k<<<100, 256, 0, stream>>>(PRE, W(24) + (i * 3 + 1) * 128, W(25) + (i * 3 + 1) * 128, X);
    // FFN
    gemm(X, 128, W(26) + (size_t)i * 32768, W(27) + i * 256,
         1, nullptr, FF1, 256, 400, 256, 128);
    gemm(FF1, 256, W(28) + (size_t)i * 32768, W(29) + i * 128,
         0, X, PRE, 128, 400, 128, 256);
    ln_k<<<100, 256, 0, stream>>>(PRE, W(24) + (i * 3 + 2) * 128, W(25) + (i * 3 + 2) * 128, X);
    // prediction heads
    conv1d_k<<<dim3(200, 2), 128, 0, stream>>>(X, W(30) + (size_t)i * 49152,
        W(31) + i * 128, W(32) + i * 128, W(33) + i * 128, YC);
    head2_k<<<4, 256, 0, stream>>>(YC, W(34) + (size_t)i * 768, W(35) + i * 2,
        qcur, CENT, 2, qnext);
    conv1d_k<<<dim3(200, 2), 128, 0, stream>>>(X, W(36) + (size_t)i * 49152,
        W(37) + i * 128, W(38) + i * 128, W(39) + i * 128, YC);
    head2_k<<<16, 256, 0, stream>>>(YC, W(40) + (size_t)i * 3840, W(41) + i * 10,
        nullptr, HMP, 10, nullptr);
  }
  out_k<<<19, 256, 0, stream>>>(CENT, HMP, d_out, FLAGS);
}

// Round 9
// 2448.347 us; speedup vs baseline: 2.2499x; 1.0777x over previous
//
#include <hip/hip_runtime.h>
#include <hip/hip_bf16.h>

typedef __hip_bfloat16 bf16;
typedef _Float16 f16;

#define HW 32400
#define NCLS 10
#define PQ 200
#define HIDDEN 128
#define NSPLIT 45
#define SPLITLEN 720    // 45*720 = 32400 exactly
#define QT 100
#define CAP 6144
#define NBIN 4096

typedef __attribute__((ext_vector_type(8))) _Float16 half8;
typedef __attribute__((ext_vector_type(8))) short short8;
typedef __attribute__((ext_vector_type(4))) short short4v;
typedef __attribute__((ext_vector_type(4))) float f32x4;

__device__ __forceinline__ float b2f(bf16 v) { return __bfloat162float(v); }
__device__ __forceinline__ void stf(float* p, float v) { *p = v; }
__device__ __forceinline__ void stf(bf16* p, float v) { *p = __float2bfloat16(v); }
// runtime-dtype load: isbf!=0 -> bf16 array, else fp32 array
__device__ __forceinline__ float ldsel(const void* p, long i, unsigned isbf) {
  return isbf ? __bfloat162float(((const bf16*)p)[i]) : ((const float*)p)[i];
}
__device__ __forceinline__ float ldf(const float* p, long i) { return p[i]; }
__device__ __forceinline__ float ldf(const bf16* p, long i) { return __bfloat162float(p[i]); }
__device__ __forceinline__ short f2bf_bits(float v) {
  union { bf16 h; short s; } u; u.h = __float2bfloat16(v); return u.s;
}

// ---------------------------------------------------------------------------
// dtype detection (bf16 vs fp32 inputs) -> FLAGS[0]
// ---------------------------------------------------------------------------
__global__ void detect_k(const unsigned* __restrict__ L, unsigned* __restrict__ FLAGS)
{
  __shared__ unsigned cnt[2];
  int tid = threadIdx.x;
  if (tid < 2) cnt[tid] = 0;
  __syncthreads();
  unsigned nz = 0, pl = 0;
  for (int w = tid; w < 4096; w += 256) {
    unsigned u = L[w];
    if (u) {
      nz++;
      unsigned e = (u >> 7) & 0xFF;
      if (e >= 110 && e <= 140) pl++;
    }
  }
  atomicAdd(&cnt[0], nz);
  atomicAdd(&cnt[1], pl);
  __syncthreads();
  if (tid == 0) {
    FLAGS[0] = (2u * cnt[1] > cnt[0]) ? 1u : 0u;
    FLAGS[1] = 0u;
  }
}

// batched weight conversion into fp32 arena (exact in both modes)
struct CvtArgs { const void* src[40]; int n[40]; int off[40]; };
__global__ __launch_bounds__(256) void cvt_k(CvtArgs a, float* __restrict__ dst,
                                             const unsigned* __restrict__ FLAGS)
{
  int j = blockIdx.y;
  unsigned isbf = FLAGS[0];
  int n = a.n[j];
  const void* s = a.src[j];
  float* d = dst + a.off[j];
  for (int t = blockIdx.x * 256 + threadIdx.x; t < n; t += gridDim.x * 256)
    d[t] = ldsel(s, t, isbf);
}

// ---------------------------------------------------------------------------
// Conv weight pre-swizzle into MFMA fragment order, fp16 hi (+scaled lo).
// WB[plane][tap][kb][nt][n16][k32] ; value = W[nt*16+n16][kb*32+k][ty][tx]
// plane1 = fp16((v - hi) * 4096)  (scale keeps lo in fp16 normal range)
// ---------------------------------------------------------------------------
__global__ __launch_bounds__(256) void wprep_k(const float* __restrict__ Wsrc,
    f16* __restrict__ WB, int N, int K, int KB, int NTG, int split)
{
  long total = (long)(split ? 2 : 1) * 9 * KB * NTG * 512;
  for (long t = (long)blockIdx.x * 256 + threadIdx.x; t < total;
       t += (long)gridDim.x * 256) {
    long r = t;
    int k = (int)(r & 31); r >>= 5;
    int n16 = (int)(r & 15); r >>= 4;
    int nt = (int)(r % NTG); r /= NTG;
    int kb = (int)(r % KB); r /= KB;
    int tap = (int)(r % 9); r /= 9;
    int plane = (int)r;
    int n = nt * 16 + n16, kk = kb * 32 + k;
    float v = 0.f;
    if (n < N && kk < K) v = Wsrc[((long)n * K + kk) * 9 + tap];
    f16 h = (f16)v;
    f16 outv = h;
    if (plane == 1) outv = (f16)((v - (float)h) * 4096.0f);
    WB[t] = outv;
  }
}

// ---------------------------------------------------------------------------
// MFMA conv2d 3x3 SAME as 9 shifted GEMMs over 64-pixel row chunks (60 valid).
// SPLIT=3: fp32-accurate fp16 split: acc = Σhi·hi' + (Σ(lo·hi'+hi·lo'))/4096,
// lo pre-scaled by 4096 (fp16-normal). SPLIT=1: plain fp16.
// Wave tiling (1,4,4,2) — A/B-measured best (R7 448µs vs R8 493µs).
// ---------------------------------------------------------------------------
template <int SPLIT, int WM, int WN, int MT, int NT, typename CT>
__global__ __launch_bounds__(256) void conv_mfma(
    const void* __restrict__ A, const unsigned* __restrict__ FLAGS, int dyn,
    long abatch,
    const f16* __restrict__ WB, const float* __restrict__ bias,
    const float* __restrict__ g, const float* __restrict__ beta, int act,
    CT* __restrict__ C, long cbatch, int N, int K, int KB, int NTG)
{
  constexpr int AW = 3 * 66 * 40;            // [ty][px][k] k-stride 40 (bank spread)
  __shared__ __align__(16) f16 Ah[AW];
  __shared__ __align__(16) f16 Al[SPLIT == 3 ? AW : 8];
  unsigned isbf = dyn ? FLAGS[0] : 0u;
  int bz = blockIdx.z;
  int y = blockIdx.x / 3;
  int x0 = (blockIdx.x % 3) * 60;
  int tid = threadIdx.x;
  int w = tid >> 6, lane = tid & 63;
  int lane15 = lane & 15, lgrp = lane >> 4;
  int wm = w % WM, wn = w / WM;
  int mbase = wm * MT * 16;
  int nbase = wn * NT * 16;
  f32x4 accM[MT][NT] = {};
  f32x4 accC[SPLIT == 3 ? MT : 1][SPLIT == 3 ? NT : 1] = {};
  long planeStride = (long)9 * KB * NTG * 512;

  for (int kb = 0; kb < KB; kb++) {
    __syncthreads();
    for (int e = tid; e < 3 * 32 * 66; e += 256) {
      int row = e / (32 * 66);
      int rem = e - row * (32 * 66);
      int k = rem / 66;
      int px = rem - k * 66;
      int gx = x0 + px - 1, gy = y + row - 1;
      int kk = kb * 32 + k;
      float v = 0.f;
      if (gx >= 0 && gx < 180 && gy >= 0 && gy < 180 && kk < K)
        v = ldsel(A, (long)bz * abatch + (long)kk * HW + gy * 180 + gx, isbf);
      f16 h = (f16)v;
      Ah[(row * 66 + px) * 40 + k] = h;
      if constexpr (SPLIT == 3)
        Al[(row * 66 + px) * 40 + k] = (f16)((v - (float)h) * 4096.0f);
    }
    __syncthreads();
#pragma unroll
    for (int tap = 0; tap < 9; tap++) {
      int ty = tap / 3, tx = tap % 3;
      const f16* wb = WB + (((long)tap * KB + kb) * NTG) * 512;
      half8 bh[NT], bl[SPLIT == 3 ? NT : 1];
#pragma unroll
      for (int nt = 0; nt < NT; nt++) {
        long o = (long)(wn * NT + nt) * 512 + lane15 * 32 + lgrp * 8;
        bh[nt] = *(const half8*)(wb + o);
        if constexpr (SPLIT == 3) bl[nt] = *(const half8*)(wb + planeStride + o);
      }
      half8 ah[MT], al[SPLIT == 3 ? MT : 1];
#pragma unroll
      for (int mt = 0; mt < MT; mt++) {
        int px = mbase + mt * 16 + lane15 + tx;
        int o = (ty * 66 + px) * 40 + lgrp * 8;
        ah[mt] = *(const half8*)&Ah[o];
        if constexpr (SPLIT == 3) al[mt] = *(const half8*)&Al[o];
      }
#pragma unroll
      for (int mt = 0; mt < MT; mt++)
#pragma unroll
        for (int nt = 0; nt < NT; nt++) {
          accM[mt][nt] = __builtin_amdgcn_mfma_f32_16x16x32_f16(
              ah[mt], bh[nt], accM[mt][nt], 0, 0, 0);
          if constexpr (SPLIT == 3) {
            accC[mt][nt] = __builtin_amdgcn_mfma_f32_16x16x32_f16(
                al[mt], bh[nt], accC[mt][nt], 0, 0, 0);
            accC[mt][nt] = __builtin_amdgcn_mfma_f32_16x16x32_f16(
                ah[mt], bl[nt], accC[mt][nt], 0, 0, 0);
          }
        }
    }
  }
  int pixbase = y * 180 + x0;
#pragma unroll
  for (int mt = 0; mt < MT; mt++) {
    int m = mbase + mt * 16 + lgrp * 4;
    if (m >= 60) continue;
#pragma unroll
    for (int nt = 0; nt < NT; nt++) {
      int n = nbase + nt * 16 + lane15;
      if (n >= N) continue;
      float bi = bias[n];
      float gg = g ? g[n] : 1.f;
      float bb = g ? beta[n] : 0.f;
      long base = (long)bz * cbatch + (long)n * HW + pixbase + m;
      if constexpr (sizeof(CT) == 4) {
        f32x4 ov;
#pragma unroll
        for (int r = 0; r < 4; r++) {
          float v = accM[mt][nt][r];
          if constexpr (SPLIT == 3) v += accC[mt][nt][r] * (1.f / 4096.f);
          v += bi;
          if (g) v = v * gg + bb;
          if (act == 1) v = fmaxf(v, 0.f);
          else if (act == 2) v = 1.f / (1.f + expf(-v));
          ov[r] = v;
        }
        *(f32x4*)&C[base] = ov;
      } else {
        short4v ov;
#pragma unroll
        for (int r = 0; r < 4; r++) {
          float v = accM[mt][nt][r];
          if constexpr (SPLIT == 3) v += accC[mt][nt][r] * (1.f / 4096.f);
          v += bi;
          if (g) v = v * gg + bb;
          if (act == 1) v = fmaxf(v, 0.f);
          ov[r] = f2bf_bits(v);
        }
        *(short4v*)&C[base] = ov;
      }
    }
  }
}

// ---------------------------------------------------------------------------
// bf16 MFMA KV projection: C = (A1+A2) @ W^T + bias.
// ---------------------------------------------------------------------------
__global__ __launch_bounds__(256) void kvproj_k(
    const bf16* __restrict__ A1, const bf16* __restrict__ A2,
    const float* __restrict__ Wf, const float* __restrict__ bias,
    bf16* __restrict__ C)
{
  __shared__ __align__(16) short As[64 * 40];
  int m0 = blockIdx.x * 64;
  int n0 = blockIdx.y * 64;
  int b = blockIdx.z;
  int tid = threadIdx.x;
  int w = tid >> 6, lane = tid & 63;
  int lane15 = lane & 15, lgrp = lane >> 4;
  int wm = w & 1, wn = w >> 1;
  const bf16* A1b = A1 + (long)b * 128 * HW;
  f32x4 acc[2][2] = {};
  for (int kb = 0; kb < 4; kb++) {
    __syncthreads();
    for (int e = tid; e < 2048; e += 256) {
      int k = e >> 6, m = e & 63;
      int gm = m0 + m;
      float v = 0.f;
      if (gm < HW) {
        long idx = (long)(kb * 32 + k) * HW + gm;
        v = b2f(A1b[idx]) + b2f(A2[idx]);
      }
      As[m * 40 + k] = f2bf_bits(v);
    }
    __syncthreads();
    short8 bh[2];
#pragma unroll
    for (int nt = 0; nt < 2; nt++) {
      int n = n0 + wn * 32 + nt * 16 + lane15;
      const float* wr = Wf + (long)n * 128 + kb * 32 + lgrp * 8;
      float4 w0 = *(const float4*)wr;
      float4 w1 = *(const float4*)(wr + 4);
      short8 t;
      t[0] = f2bf_bits(w0.x); t[1] = f2bf_bits(w0.y);
      t[2] = f2bf_bits(w0.z); t[3] = f2bf_bits(w0.w);
      t[4] = f2bf_bits(w1.x); t[5] = f2bf_bits(w1.y);
      t[6] = f2bf_bits(w1.z); t[7] = f2bf_bits(w1.w);
      bh[nt] = t;
    }
    short8 ah[2];
#pragma unroll
    for (int mt = 0; mt < 2; mt++) {
      int m = wm * 32 + mt * 16 + lane15;
      ah[mt] = *(const short8*)&As[m * 40 + lgrp * 8];
    }
#pragma unroll
    for (int mt = 0; mt < 2; mt++)
#pragma unroll
      for (int nt = 0; nt < 2; nt++)
        acc[mt][nt] = __builtin_amdgcn_mfma_f32_16x16x32_bf16(
            ah[mt], bh[nt], acc[mt][nt], 0, 0, 0);
  }
#pragma unroll
  for (int mt = 0; mt < 2; mt++) {
    int mq = m0 + wm * 32 + mt * 16 + lgrp * 4;
    if (mq >= HW) continue;
#pragma unroll
    for (int nt = 0; nt < 2; nt++) {
      int n = n0 + wn * 32 + nt * 16 + lane15;
      float bi = bias[n];
      short4v ov;
#pragma unroll
      for (int r = 0; r < 4; r++) ov[r] = f2bf_bits(acc[mt][nt][r] + bi);
      *(short4v*)&C[(long)b * 256 * HW + (long)n * HW + mq] = ov;
    }
  }
}

// ---------------------------------------------------------------------------
// Generic tiled GEMM: C = act(A @ W^T + bias) (+ res)
// amode 0: A[m*lda+k].  amode 2: fused BEV pos-embed stage-1 as A.
// cmode 0: C[m*ldc+n] ; cmode 1: C[n*ldc+m].  K multiple of 16.
// ---------------------------------------------------------------------------
template <typename AT, typename CT>
__global__ __launch_bounds__(256) void gemm_k(
    const AT* __restrict__ A, const AT* __restrict__ A2, int lda, int amode,
    long abatch,
    const float* __restrict__ W, const float* __restrict__ bias, int act,
    const float* __restrict__ res,
    const float* __restrict__ pe1w, const float* __restrict__ pe1b,
    const float* __restrict__ pe1g, const float* __restrict__ pe1bt,
    CT* __restrict__ C, int ldc, int cmode, long cbatch,
    int M, int N, int K)
{
  __shared__ __align__(16) float As[16][68];
  __shared__ __align__(16) float Ws[16][68];
  int b = blockIdx.z;
  int m0 = blockIdx.x * 64, n0 = blockIdx.y * 64;
  int tid = threadIdx.x;
  int nt = tid & 15, mt = tid >> 4;
  float acc[4][4] = {};
  const AT* Ab = A + (long)b * abatch;
  for (int k0 = 0; k0 < K; k0 += 16) {
    if (amode == 0) {
      for (int e = tid; e < 1024; e += 256) {
        int m = e >> 4, k = e & 15;
        float v = 0.f;
        if (m0 + m < M) v = ldf(Ab, (long)(m0 + m) * lda + k0 + k);
        As[k][m] = v;
      }
    } else if (amode == 1) {
      for (int e = tid; e < 1024; e += 256) {
        int m = e & 63, k = e >> 6;
        float v = 0.f;
        if (m0 + m < M) {
          long idx = (long)(k0 + k) * lda + m0 + m;
          v = ldf(Ab, idx);
          if (A2) v += ldf(A2, idx);
        }
        As[k][m] = v;
      }
    } else {
      for (int e = tid; e < 1024; e += 256) {
        int m = e & 63, k = e >> 6;
        float v = 0.f;
        int gm = m0 + m;
        if (gm < M) {
          float p0 = (float)(gm / 180) + 0.5f;
          float p1 = (float)(gm % 180) + 0.5f;
          int kk = k0 + k;
          float t = p0 * pe1w[kk * 2] + p1 * pe1w[kk * 2 + 1] + pe1b[kk];
          t = t * pe1g[kk] + pe1bt[kk];
          v = fmaxf(t, 0.f);
        }
        As[k][m] = v;
      }
    }
    for (int e = tid; e < 1024; e += 256) {
      int n = e >> 4, k = e & 15;
      float v = 0.f;
      if (n0 + n < N) v = W[(long)(n0 + n) * K + k0 + k];
      Ws[k][n] = v;
    }
    __syncthreads();
#pragma unroll
    for (int kk = 0; kk < 16; kk++) {
      float4 av = *(const float4*)&As[kk][mt * 4];
      float4 wv = *(const float4*)&Ws[kk][nt * 4];
      float am[4] = {av.x, av.y, av.z, av.w};
      float wn[4] = {wv.x, wv.y, wv.z, wv.w};
#pragma unroll
      for (int mi = 0; mi < 4; mi++)
#pragma unroll
        for (int ni = 0; ni < 4; ni++)
          acc[mi][ni] = fmaf(am[mi], wn[ni], acc[mi][ni]);
    }
    __syncthreads();
  }
#pragma unroll
  for (int mi = 0; mi < 4; mi++) {
    int m = m0 + mt * 4 + mi;
    if (m >= M) continue;
#pragma unroll
    for (int ni = 0; ni < 4; ni++) {
      int n = n0 + nt * 4 + ni;
      if (n >= N) continue;
      float v = acc[mi][ni];
      if (bias) v += bias[n];
      if (act == 1) v = fmaxf(v, 0.f);
      if (res) v += res[(long)m * ldc + n];
      long ci = (cmode == 0) ? ((long)b * cbatch + (long)m * ldc + n)
                             : ((long)b * cbatch + (long)n * ldc + m);
      stf(&C[ci], v);
    }
  }
}

// ---------------------------------------------------------------------------
__global__ void nms_k(const float* __restrict__ HEAT, float* __restrict__ SCORE)
{
  int t = blockIdx.x * 256 + threadIdx.x;
  if (t >= 2 * NCLS * HW) return;
  int b = t / (NCLS * HW); int r = t % (NCLS * HW);
  int cls = r / HW; int n = r % HW;
  const float* hb = HEAT + ((long)(b * NCLS + cls)) * HW;
  float v = hb[n];
  bool keep = true;
  if (cls < 8) {
    int y = n / 180, x = n % 180;
    if (y == 0 || y == 179 || x == 0 || x == 179) keep = false;
    else {
      float mx = -1e30f;
#pragma unroll
      for (int dy = -1; dy <= 1; dy++)
#pragma unroll
        for (int dx = -1; dx <= 1; dx++)
          mx = fmaxf(mx, hb[(y + dy) * 180 + x + dx]);
      keep = (v == mx);
    }
  }
  SCORE[(long)b * (NCLS * HW) + r] = keep ? v : 0.f;
}

__global__ void zero_u32(unsigned* p, int n)
{
  int t = blockIdx.x * 256 + threadIdx.x;
  if (t < n) p[t] = 0;
}

__global__ __launch_bounds__(256) void hist_k(const float* __restrict__ SCORE,
                                              unsigned* __restrict__ HIST)
{
  __shared__ unsigned lh[NBIN];
  int b = blockIdx.y;
  for (int e = threadIdx.x; e < NBIN; e += 256) lh[e] = 0;
  __syncthreads();
  int start = blockIdx.x * 1350;
  const float* sb = SCORE + (long)b * (NCLS * HW);
  for (int e = start + threadIdx.x; e < start + 1350; e += 256) {
    unsigned bits = __float_as_uint(sb[e]);
    atomicAdd(&lh[bits >> 18], 1u);
  }
  __syncthreads();
  for (int e = threadIdx.x; e < NBIN; e += 256) {
    unsigned c = lh[e];
    if (c) atomicAdd(&HIST[b * NBIN + e], c);
  }
}

__global__ void thresh_k(const unsigned* __restrict__ HIST, unsigned* __restrict__ THR)
{
  __shared__ unsigned ps[256];
  int b = blockIdx.x;
  const unsigned* hb = HIST + b * NBIN;
  unsigned s = 0;
  for (int j = 0; j < 16; j++) s += hb[threadIdx.x * 16 + j];
  ps[threadIdx.x] = s;
  __syncthreads();
  if (threadIdx.x == 0) {
    unsigned cum = 0; int t = 255;
    for (; t > 0; t--) { if (cum + ps[t] >= PQ) break; cum += ps[t]; }
    int bin = t * 16 + 15;
    for (; bin > t * 16; bin--) { unsigned c = hb[bin]; if (cum + c >= PQ) break; cum += c; }
    if (bin < 1) bin = 1;
    THR[b] = (unsigned)bin;
  }
}

__global__ void collect_k(const float* __restrict__ SCORE, const unsigned* __restrict__ THR,
                          unsigned* __restrict__ ACNT, unsigned long long* __restrict__ CAND)
{
  int t = blockIdx.x * 256 + threadIdx.x;
  if (t >= 2 * NCLS * HW) return;
  int b = t / (NCLS * HW); int r = t % (NCLS * HW);
  float v = SCORE[(long)b * (NCLS * HW) + r];
  unsigned bits = __float_as_uint(v);
  if ((bits >> 18) >= THR[b]) {
    unsigned slot = atomicAdd(&ACNT[b], 1u);
    if (slot < CAP) CAND[(long)b * CAP + slot] =
        ((unsigned long long)bits << 32) | (unsigned)(~r);
  }
}

__global__ __launch_bounds__(64) void select_k(
    const unsigned long long* __restrict__ CAND, const unsigned* __restrict__ ACNT,
    unsigned* __restrict__ TOPC, unsigned* __restrict__ TOPI, float* __restrict__ QPA)
{
  __shared__ unsigned long long cnd[CAP];
  int b = blockIdx.x;
  int lane = threadIdx.x;
  unsigned cnt = ACNT[b]; if (cnt > CAP) cnt = CAP;
  for (int e = lane; e < (int)cnt; e += 64) cnd[e] = CAND[(long)b * CAP + e];
  __syncthreads();
  for (int p = 0; p < PQ; p++) {
    unsigned long long best = 0;
    for (int e = lane; e < (int)cnt; e += 64) { unsigned long long c = cnd[e]; if (c > best) best = c; }
#pragma unroll
    for (int o = 32; o; o >>= 1) {
      unsigned long long other = __shfl_xor(best, o, 64);
      if (other > best) best = other;
    }
    for (int e = lane; e < (int)cnt; e += 64) if (best != 0 && cnd[e] == best) cnd[e] = 0;
    if (lane == 0) {
      unsigned idx = (best == 0) ? 0u : ~(unsigned)(best & 0xFFFFFFFFull);
      if (idx >= NCLS * HW) idx = 0;
      unsigned cls = idx / HW, n = idx % HW;
      TOPC[b * PQ + p] = cls; TOPI[b * PQ + p] = n;
      QPA[((long)(b * PQ + p)) * 2 + 0] = (float)(n / 180) + 0.5f;
      QPA[((long)(b * PQ + p)) * 2 + 1] = (float)(n % 180) + 0.5f;
    }
    __syncthreads();
  }
}

__global__ void gather_k(const float* __restrict__ LIDF, const unsigned* __restrict__ TOPC,
                         const unsigned* __restrict__ TOPI, const float* __restrict__ cew,
                         const float* __restrict__ ceb, float* __restrict__ X)
{
  int t = blockIdx.x * 256 + threadIdx.x;
  if (t >= 2 * PQ * HIDDEN) return;
  int c = t & 127; int r = t >> 7; int p = r % PQ; int b = r / PQ;
  unsigned n = TOPI[b * PQ + p]; unsigned cls = TOPC[b * PQ + p];
  if (n >= HW) n = 0;
  if (cls >= NCLS) cls = 0;
  X[t] = LIDF[((long)(b * HIDDEN + c)) * HW + n] + cew[c * NCLS + cls] + ceb[c];
}

// posembed stage 1 for queries only
__global__ void pe_stage1(const float* __restrict__ qpos,
                          const float* __restrict__ w1, const float* __restrict__ b1,
                          const float* __restrict__ g, const float* __restrict__ bt,
                          float* __restrict__ T1, int M)
{
  int t = blockIdx.x * 256 + threadIdx.x;
  if (t >= M * HIDDEN) return;
  int c = t & 127; int m = t >> 7;
  float p0 = qpos[m * 2], p1 = qpos[m * 2 + 1];
  float v = p0 * w1[c * 2] + p1 * w1[c * 2 + 1] + b1[c];
  v = v * g[c] + bt[c];
  T1[t] = fmaxf(v, 0.f);
}

__global__ void add2_k(const float* __restrict__ a, const float* __restrict__ b,
                       float* __restrict__ o, int n)
{
  int t = blockIdx.x * 256 + threadIdx.x;
  if (t < n) o[t] = a[t] + b[t];
}

__global__ __launch_bounds__(64) void self_attn_k(const float* __restrict__ SQKV,
                                                  float* __restrict__ SAO)
{
  int q = blockIdx.x, h = blockIdx.y, b = blockIdx.z;
  int lane = threadIdx.x;
  const float* qp = SQKV + ((long)(b * PQ + q)) * 384 + h * 16;
  float qv[16];
#pragma unroll
  for (int d = 0; d < 16; d++) qv[d] = qp[d] * 0.25f;
  float sv[4]; int kks[4]; int nk = 0;
  float lmax = -1e30f;
  for (int kk = lane; kk < PQ; kk += 64) {
    const float* kp = SQKV + ((long)(b * PQ + kk)) * 384 + 128 + h * 16;
    float s = 0.f;
#pragma unroll
    for (int d = 0; d < 16; d++) s = fmaf(qv[d], kp[d], s);
    sv[nk] = s; kks[nk] = kk; nk++;
    lmax = fmaxf(lmax, s);
  }
#pragma unroll
  for (int o = 32; o; o >>= 1) lmax = fmaxf(lmax, __shfl_xor(lmax, o, 64));
  float lsum = 0.f; float acc[16] = {};
  for (int t = 0; t < nk; t++) {
    float p = expf(sv[t] - lmax);
    lsum += p;
    const float* vp = SQKV + ((long)(b * PQ + kks[t])) * 384 + 256 + h * 16;
#pragma unroll
    for (int d = 0; d < 16; d++) acc[d] = fmaf(p, vp[d], acc[d]);
  }
#pragma unroll
  for (int o = 32; o; o >>= 1) lsum += __shfl_xor(lsum, o, 64);
#pragma unroll
  for (int d = 0; d < 16; d++) {
    float v = acc[d];
#pragma unroll
    for (int o = 32; o; o >>= 1) v += __shfl_xor(v, o, 64);
    if (lane == 0) SAO[((long)(b * PQ + q)) * HIDDEN + h * 16 + d] = v / lsum;
  }
}

// ---------------------------------------------------------------------------
// flash cross-attention, key-split. R9: QK and online-softmax merged into one
// phase (row stats via __shfl_xor within the 8-lane q-group — consecutive
// lanes, one wave), K/V staging ping-pong buffered so tile t+1 stages during
// tile t's QK. 2 barriers/tile (was 4). PART [B][8][NSPLIT][200][18].
// ---------------------------------------------------------------------------
__global__ __launch_bounds__(256) void flash_k(const float* __restrict__ QH,
                                               const bf16* __restrict__ KVT,
                                               float* __restrict__ PART)
{
  int s = blockIdx.x, h = blockIdx.y;
  int b = blockIdx.z >> 1, qh = blockIdx.z & 1;
  int tid = threadIdx.x;
  __shared__ __align__(16) float sL[QT][36];
  __shared__ __align__(16) float qtL[16][104];
  __shared__ __align__(16) float kjL[2][16][36];
  __shared__ __align__(16) float vjL[2][16][36];
  __shared__ float mL[QT], lL[QT], aL[QT];
  int qbase = qh * QT;
  for (int e = tid; e < QT * 16; e += 256) {
    int q = e >> 4, d = e & 15;
    qtL[d][q] = QH[((long)(b * PQ + qbase + q)) * HIDDEN + h * 16 + d] * 0.25f;
  }
  if (tid < QT) { mL[tid] = -1e30f; lL[tid] = 0.f; }
  float ovr[4][2] = {};
  int qg = tid >> 3, jg = tid & 7;        // q-group 0..24 (tid<200), j-lane 0..7
  int q0 = qg * 4, j0 = jg * 4;
  int pd = (tid & 7) * 2;                 // PV d-index; PV q-mapping = qg + 25*i
  int nbeg = s * SPLITLEN;
  const bf16* Kb = KVT + (long)b * 256 * HW + (long)(h * 16) * HW;
  const bf16* Vb = Kb + (long)128 * HW;
  int sd = tid >> 4, sj = (tid & 15) * 2; // staging: d 0..15, j pair
  // stage tile 0 into buf 0 (tile 0 always full: SPLITLEN >= 32)
  {
    long o = (long)sd * HW + nbeg + sj;
    float2 kv, vv;
    kv.x = b2f(Kb[o]);     kv.y = b2f(Kb[o + 1]);
    vv.x = b2f(Vb[o]);     vv.y = b2f(Vb[o + 1]);
    *(float2*)&kjL[0][sd][sj] = kv;
    *(float2*)&vjL[0][sd][sj] = vv;
  }
  __syncthreads();
  const int ntiles = (SPLITLEN + 31) / 32;
  for (int t = 0; t < ntiles; t++) {
    int cur = t & 1;
    // ---- stage tile t+1 into buf cur^1 (loads overlap QK below)
    if (t + 1 < ntiles) {
      int n0 = nbeg + (t + 1) * 32;
      int rem = SPLITLEN - (t + 1) * 32; if (rem > 32) rem = 32;
      float2 kv = {0.f, 0.f}, vv = {0.f, 0.f};
      if (sj < rem) {
        long o = (long)sd * HW + n0 + sj;
        kv.x = b2f(Kb[o]); vv.x = b2f(Vb[o]);
        if (sj + 1 < rem) { kv.y = b2f(Kb[o + 1]); vv.y = b2f(Vb[o + 1]); }
      }
      *(float2*)&kjL[cur ^ 1][sd][sj] = kv;
      *(float2*)&vjL[cur ^ 1][sd][sj] = vv;
    }
    // ---- QK + online softmax (register shuffles, no sL round-trip of raw s)
    int remt = SPLITLEN - t * 32; if (remt > 32) remt = 32;
    if (tid < 200) {
      float acc[4][4] = {};
#pragma unroll
      for (int d = 0; d < 16; d++) {
        float4 kv = *(const float4*)&kjL[cur][d][j0];
        float4 qv = *(const float4*)&qtL[d][q0];
        float qa[4] = {qv.x, qv.y, qv.z, qv.w};
        float ka[4] = {kv.x, kv.y, kv.z, kv.w};
#pragma unroll
        for (int i = 0; i < 4; i++)
#pragma unroll
          for (int jj = 0; jj < 4; jj++)
            acc[i][jj] = fmaf(qa[i], ka[jj], acc[i][jj]);
      }
      if (remt < 32) {
#pragma unroll
        for (int i = 0; i < 4; i++)
#pragma unroll
          for (int jj = 0; jj < 4; jj++)
            if (j0 + jj >= remt) acc[i][jj] = -1e30f;
      }
#pragma unroll
      for (int i = 0; i < 4; i++) {
        float mx = fmaxf(fmaxf(acc[i][0], acc[i][1]), fmaxf(acc[i][2], acc[i][3]));
        mx = fmaxf(mx, __shfl_xor(mx, 1, 64));
        mx = fmaxf(mx, __shfl_xor(mx, 2, 64));
        mx = fmaxf(mx, __shfl_xor(mx, 4, 64));
        float mold = mL[q0 + i];
        float mnew = fmaxf(mx, mold);
        float ls = 0.f;
#pragma unroll
        for (int jj = 0; jj < 4; jj++) {
          float p = expf(acc[i][jj] - mnew);
          acc[i][jj] = p;
          ls += p;
        }
        ls += __shfl_xor(ls, 1, 64);
        ls += __shfl_xor(ls, 2, 64);
        ls += __shfl_xor(ls, 4, 64);
        if (jg == 0) {
          float al = expf(mold - mnew);
          lL[q0 + i] = lL[q0 + i] * al + ls;
          mL[q0 + i] = mnew;
          aL[q0 + i] = al;
        }
        float4 ov;
        ov.x = acc[i][0]; ov.y = acc[i][1]; ov.z = acc[i][2]; ov.w = acc[i][3];
        *(float4*)&sL[q0 + i][j0] = ov;
      }
    }
    __syncthreads();
    // ---- PV: O = O*alpha + P V  (q interleaved stride 25, O in registers)
    if (tid < 200) {
#pragma unroll
      for (int i = 0; i < 4; i++) {
        float a = aL[qg + 25 * i];
        ovr[i][0] *= a; ovr[i][1] *= a;
      }
#pragma unroll
      for (int j00 = 0; j00 < 32; j00 += 4) {
        float4 v0 = *(const float4*)&vjL[cur][pd][j00];
        float4 v1 = *(const float4*)&vjL[cur][pd + 1][j00];
#pragma unroll
        for (int i = 0; i < 4; i++) {
          float4 p = *(const float4*)&sL[qg + 25 * i][j00];
          ovr[i][0] = fmaf(p.x, v0.x, ovr[i][0]);
          ovr[i][0] = fmaf(p.y, v0.y, ovr[i][0]);
          ovr[i][0] = fmaf(p.z, v0.z, ovr[i][0]);
          ovr[i][0] = fmaf(p.w, v0.w, ovr[i][0]);
          ovr[i][1] = fmaf(p.x, v1.x, ovr[i][1]);
          ovr[i][1] = fmaf(p.y, v1.y, ovr[i][1]);
          ovr[i][1] = fmaf(p.z, v1.z, ovr[i][1]);
          ovr[i][1] = fmaf(p.w, v1.w, ovr[i][1]);
        }
      }
    }
    __syncthreads();
  }
  long base = ((((long)(b * 8 + h)) * NSPLIT + s) * PQ) * 18;
  if (tid < 200) {
#pragma unroll
    for (int i = 0; i < 4; i++) {
      long ro = base + (long)(qbase + qg + 25 * i) * 18;
      PART[ro + pd] = ovr[i][0];
      PART[ro + pd + 1] = ovr[i][1];
    }
  }
  if (tid < QT) {
    long ro = base + (long)(qbase + tid) * 18;
    PART[ro + 16] = mL[tid];
    PART[ro + 17] = lL[tid];
  }
}

__global__ void combine_k(const float* __restrict__ PART, float* __restrict__ CAO)
{
  int t = blockIdx.x * 256 + threadIdx.x;
  if (t >= 2 * 8 * PQ * 16) return;
  int d = t & 15; int r = t >> 4;
  int q = r % PQ; r /= PQ;
  int h = r & 7; int b = r >> 3;
  long base = (((long)(b * 8 + h)) * NSPLIT) * PQ * 18 + (long)q * 18;
  float M = -1e30f;
  for (int s = 0; s < NSPLIT; s++) M = fmaxf(M, PART[base + (long)s * PQ * 18 + 16]);
  float L = 0.f, O = 0.f;
  for (int s = 0; s < NSPLIT; s++) {
    long p0 = base + (long)s * PQ * 18;
    float w = expf(PART[p0 + 16] - M);
    L += PART[p0 + 17] * w;
    O += PART[p0 + d] * w;
  }
  CAO[((long)(b * PQ + q)) * HIDDEN + h * 16 + d] = (L > 0.f) ? O / L : 0.f;
}

__global__ __launch_bounds__(256) void ln_k(const float* __restrict__ PRE,
                                            const float* __restrict__ g,
                                            const float* __restrict__ bta,
                                            float* __restrict__ X)
{
  int row = blockIdx.x * 4 + (threadIdx.x >> 6);
  int lane = threadIdx.x & 63;
  const float* p = PRE + (long)row * HIDDEN;
  float v0 = p[lane], v1 = p[lane + 64];
  float s = v0 + v1;
#pragma unroll
  for (int o = 32; o; o >>= 1) s += __shfl_xor(s, o, 64);
  float mu = s * (1.f / 128.f);
  float d0 = v0 - mu, d1 = v1 - mu;
  float vs = d0 * d0 + d1 * d1;
#pragma unroll
  for (int o = 32; o; o >>= 1) vs += __shfl_xor(vs, o, 64);
  float rs = rsqrtf(vs * (1.f / 128.f) + 1e-5f);
  float* xo = X + (long)row * HIDDEN;
  xo[lane] = d0 * rs * g[lane] + bta[lane];
  xo[lane + 64] = d1 * rs * g[lane + 64] + bta[lane + 64];
}

__global__ __launch_bounds__(128) void conv1d_k(const float* __restrict__ X,
                                                const float* __restrict__ w,
                                                const float* __restrict__ bias,
                                                const float* __restrict__ g,
                                                const float* __restrict__ beta,
                                                float* __restrict__ Y)
{
  int p = blockIdx.x, b = blockIdx.y;
  int co = threadIdx.x;
  __shared__ float xs[3][HIDDEN];
  for (int e = co; e < 3 * HIDDEN; e += HIDDEN) {
    int t = e >> 7, c = e & 127;
    int pp = p + t - 1;
    xs[t][c] = (pp >= 0 && pp < PQ) ? X[((long)(b * PQ + pp)) * HIDDEN + c] : 0.f;
  }
  __syncthreads();
  const float* wr = w + (long)co * HIDDEN * 3;
  float acc = 0.f;
  for (int c = 0; c < HIDDEN; c++) {
    acc = fmaf(xs[0][c], wr[c * 3 + 0], acc);
    acc = fmaf(xs[1][c], wr[c * 3 + 1], acc);
    acc = fmaf(xs[2][c], wr[c * 3 + 2], acc);
  }
  float v = (acc + bias[co]) * g[co] + beta[co];
  Y[((long)(b * PQ + p)) * HIDDEN + co] = fmaxf(v, 0.f);
}

__global__ void head2_k(const float* __restrict__ Y, const float* __restrict__ w,
                        const float* __restrict__ bias, const float* __restrict__ qpos,
                        float* __restrict__ OUT, int N, float* __restrict__ qnext)
{
  int t = blockIdx.x * 256 + threadIdx.x;
  if (t >= 2 * N * PQ) return;
  int p = t % PQ; int r = t / PQ; int co = r % N; int b = r / N;
  const float* wr = w + (long)co * HIDDEN * 3;
  float acc = 0.f;
  for (int tap = 0; tap < 3; tap++) {
    int pp = p + tap - 1;
    if (pp < 0 || pp >= PQ) continue;
    const float* yr = Y + ((long)(b * PQ + pp)) * HIDDEN;
    for (int c = 0; c < HIDDEN; c++)
      acc = fmaf(yr[c], wr[c * 3 + tap], acc);
  }
  float v = acc + bias[co];
  if (qpos) v += qpos[((long)(b * PQ + p)) * 2 + co];
  OUT[((long)(b * N + co)) * PQ + p] = v;
  if (qnext) qnext[((long)(b * PQ + p)) * 2 + co] = v;
}

__global__ void out_k(const float* __restrict__ CENT, const float* __restrict__ HMP,
                      void* __restrict__ out, const unsigned* __restrict__ FLAGS)
{
  int t = blockIdx.x * 256 + threadIdx.x;
  if (t >= 2 * 12 * PQ) return;
  int p = t % PQ; int r = t / PQ; int ch = r % 12; int b = r / 12;
  float v = (ch < 2) ? CENT[((long)(b * 2 + ch)) * PQ + p]
                     : HMP[((long)(b * 10 + ch - 2)) * PQ + p];
  if (FLAGS[0]) ((bf16*)out)[t] = __float2bfloat16(v);
  else          ((float*)out)[t] = v;
}

// ---------------------------------------------------------------------------
extern "C" void kernel_launch(void* const* d_in, const int* in_sizes, int n_in,
                              void* d_out, int out_size, void* d_ws, size_t ws_size,
                              hipStream_t stream)
{
  (void)n_in; (void)out_size; (void)ws_size;

  // ---- workspace layout (~80 MB == R3's validated watermark) --------------
  float* F = (float*)d_ws;
  size_t off = 0;
  int aoff[42];
  {
    size_t acc = 0;
    for (int i = 2; i < 42; i++) { aoff[i] = (int)acc; acc += (size_t)in_sizes[i]; }
    off = acc;
  }
  float* ARENA = F;
  float* LIDF = F + off;                        // [2][128][HW] fp32 (dead after gather)
  bf16*  KVT16 = (bf16*)(F + off);              // alias: [2][256][HW] bf16 (decoder)
  off += 8294400;
  float* HBUF = F + off;                        // [1][128][HW] fp32 (per-batch reuse)
  bf16*  KPET16 = (bf16*)(F + off);             // alias: [128][HW] bf16 (decoder)
  float* PART  = F + off;                       // alias: [2][8][NSPLIT][200][18]
  off += 4147200;
  bf16*  CAMF16 = (bf16*)(F + off);             // [2][128][HW] bf16 (live all run)
  off += 4147200;
  float* HEAT  = F + off;                       // [2][10][HW] (dead after nms)
  float* SCORE = F + off + 648000;              // (dead after collect)
  off += 1296000;
  float* X   = F + off; off += 51200;           // decoder smalls — all dead during
  float* XQ  = F + off; off += 51200;           // convs; WB_* aliases this region
  float* QPE = F + off; off += 51200;
  float* T1Q = F + off; off += 51200;
  float* SQKV = F + off; off += 153600;
  float* SAO = F + off; off += 51200;
  float* PRE = F + off; off += 51200;
  float* QH2 = F + off; off += 51200;
  float* CAO = F + off; off += 51200;
  float* FF1 = F + off; off += 102400;
  float* YC  = F + off; off += 51200;           // X..YC span = 716800 floats
  float* CENT = F + off; off += 800;
  float* HMP = F + off; off += 4000;
  float* QPA = F + off; off += 800;
  float* QPB = F + off; off += 800;
  unsigned* U = (unsigned*)(F + off);
  unsigned* HIST  = U;                          // [0, 8192)
  unsigned* ACNT  = U + 8192;                   // 2
  unsigned* THR   = U + 8194;                   // 2
  unsigned* FLAGS = U + 8196;                   // 2 (NOT zeroed by zero_u32)
  unsigned* TOPC  = U + 8198;                   // 400
  unsigned* TOPI  = U + 8598;                   // 400
  unsigned long long* CAND = (unsigned long long*)(U + 9000); // 2*CAP u64
  // fp16 MFMA weight planes: alias the decoder-smalls region (dead during
  // wprep + convs). 1,327,104 f16 = 663,552 floats fits 716,800-float span.
  f16* WB_LID = (f16*)((((uintptr_t)X) + 15) & ~(uintptr_t)15);
  f16* WB_CAM = WB_LID + 884736;                // 2*9*12*8*512 = 884736
  f16* WB_HM1 = WB_CAM + 110592;                // 1*9*3*8*512  = 110592
  f16* WB_HM2 = WB_HM1 + 294912;                // 2*9*4*8*512  = 294912 (+36864)

  auto W = [&](int i) -> const float* { return ARENA + aoff[i]; };

  // ---- dtype detect + weight conversion -----------------------------------
  detect_k<<<1, 256, 0, stream>>>((const unsigned*)d_in[0], FLAGS);
  {
    CvtArgs a;
    for (int i = 2; i < 42; i++) { a.src[i - 2] = d_in[i]; a.n[i - 2] = in_sizes[i]; a.off[i - 2] = aoff[i]; }
    cvt_k<<<dim3(432, 40), 256, 0, stream>>>(a, ARENA, FLAGS);
  }
  wprep_k<<<3456, 256, 0, stream>>>(W(2), WB_LID, 128, 384, 12, 8, 1);
  wprep_k<<<432, 256, 0, stream>>>(W(4), WB_CAM, 128, 80, 3, 8, 0);
  wprep_k<<<1152, 256, 0, stream>>>(W(6), WB_HM1, 128, 128, 4, 8, 1);
  wprep_k<<<144, 256, 0, stream>>>(W(10), WB_HM2, 10, 128, 4, 1, 1);

  auto gemm = [&](const float* A, int lda, const float* Wp, const float* bias, int act,
                  const float* res, float* C, int ldc, int M, int N, int K) {
    dim3 grid((M + 63) / 64, (N + 63) / 64, 1);
    gemm_k<float, float><<<grid, 256, 0, stream>>>(
        A, (const float*)nullptr, lda, 0, 0L, Wp, bias, act, res,
        nullptr, nullptr, nullptr, nullptr, C, ldc, 0, 0L, M, N, K);
  };

  // ---- backbone convs (MFMA, fp16 split, proven (1,4,4,2) tiling) ---------
  conv_mfma<3, 1, 4, 4, 2, float><<<dim3(540, 1, 2), 256, 0, stream>>>(
      d_in[0], FLAGS, 1, (long)384 * HW, WB_LID, W(3), nullptr, nullptr, 0,
      LIDF, (long)128 * HW, 128, 384, 12, 8);
  conv_mfma<1, 1, 4, 4, 2, bf16><<<dim3(540, 1, 2), 256, 0, stream>>>(
      d_in[1], FLAGS, 1, (long)80 * HW, WB_CAM, W(5), nullptr, nullptr, 0,
      CAMF16, (long)128 * HW, 128, 80, 3, 8);
  for (int b = 0; b < 2; b++) {
    conv_mfma<3, 1, 4, 4, 2, float><<<dim3(540, 1, 1), 256, 0, stream>>>(
        LIDF + (long)b * 128 * HW, FLAGS, 0, 0L, WB_HM1, W(7), W(8), W(9), 1,
        HBUF, 0L, 128, 128, 4, 8);
    conv_mfma<3, 4, 1, 1, 1, float><<<dim3(540, 1, 1), 256, 0, stream>>>(
        HBUF, FLAGS, 0, 0L, WB_HM2, W(11), nullptr, nullptr, 2,
        HEAT + (long)b * NCLS * HW, 0L, 10, 128, 4, 1);
  }

  // ---- NMS + exact top-200 ------------------------------------------------
  nms_k<<<(2 * NCLS * HW + 255) / 256, 256, 0, stream>>>(HEAT, SCORE);
  zero_u32<<<(8196 + 255) / 256, 256, 0, stream>>>(U, 8196);
  hist_k<<<dim3(240, 2), 256, 0, stream>>>(SCORE, HIST);
  thresh_k<<<2, 256, 0, stream>>>(HIST, THR);
  collect_k<<<(2 * NCLS * HW + 255) / 256, 256, 0, stream>>>(SCORE, THR, ACNT, CAND);
  select_k<<<2, 64, 0, stream>>>(CAND, ACNT, TOPC, TOPI, QPA);
  gather_k<<<200, 256, 0, stream>>>(LIDF, TOPC, TOPI, W(12), W(13), X);

  // ---- decoder layers -----------------------------------------------------
  for (int i = 0; i < 2; i++) {
    const float* qcur = (i == 0) ? QPA : QPB;
    float* qnext = (i == 0) ? QPB : QPA;
    // query pos-embed
    pe_stage1<<<200, 256, 0, stream>>>(qcur, W(14) + (i * 2 + 0) * 256,
        W(15) + (i * 2 + 0) * 128, W(16) + (i * 2 + 0) * 128, W(17) + (i * 2 + 0) * 128,
        T1Q, 400);
    gemm(T1Q, 128, W(18) + (size_t)(i * 2 + 0) * 16384, W(19) + (i * 2 + 0) * 128,
         0, nullptr, QPE, 128, 400, 128, 128);
    // key pos-embed (BEV grid fused into staging), stored transposed [128][HW] bf16
    gemm_k<float, bf16><<<dim3(507, 2, 1), 256, 0, stream>>>(
        ARENA, (const float*)nullptr, 0, 2, 0L,
        W(18) + (size_t)(i * 2 + 1) * 16384, W(19) + (i * 2 + 1) * 128, 0, nullptr,
        W(14) + (i * 2 + 1) * 256, W(15) + (i * 2 + 1) * 128,
        W(16) + (i * 2 + 1) * 128, W(17) + (i * 2 + 1) * 128,
        KPET16, HW, 1, 0L, 32400, 128, 128);
    // self-attention
    add2_k<<<200, 256, 0, stream>>>(X, QPE, XQ, 51200);
    gemm(XQ, 128, W(20) + (size_t)(i * 2 + 0) * 49152, W(21) + (i * 2 + 0) * 384,
         0, nullptr, SQKV, 384, 400, 384, 128);
    self_attn_k<<<dim3(200, 8, 2), 64, 0, stream>>>(SQKV, SAO);
    gemm(SAO, 128, W(22) + (size_t)(i * 2 + 0) * 16384, W(23) + (i * 2 + 0) * 128,
         0, X, PRE, 128, 400, 128, 128);
    ln_k<<<100, 256, 0, stream>>>(PRE, W(24) + (i * 3 + 0) * 128, W(25) + (i * 3 + 0) * 128, X);
    // cross-attention
    add2_k<<<200, 256, 0, stream>>>(X, QPE, XQ, 51200);
    gemm(XQ, 128, W(20) + (size_t)(i * 2 + 1) * 49152, W(21) + (i * 2 + 1) * 384,
         0, nullptr, QH2, 128, 400, 128, 128);
    kvproj_k<<<dim3(507, 4, 2), 256, 0, stream>>>(
        CAMF16, KPET16,
        W(20) + (size_t)(i * 2 + 1) * 49152 + 16384,
        W(21) + (i * 2 + 1) * 384 + 128, KVT16);
    flash_k<<<dim3(NSPLIT, 8, 4), 256, 0, stream>>>(QH2, KVT16, PART);
    combine_k<<<200, 256, 0, stream>>>(PART, CAO);
    gemm(CAO, 128, W(22) + (size_t)(i * 2 + 1) * 16384, W(23) + (i * 2 + 1) * 128,
         0, X, PRE, 128, 400, 128, 128);
    ln_k<<<100, 256, 0, stream>>>(PRE, W(24) + (i * 3 + 1) * 128, W(25) + (i * 3 + 1) * 128, X);
    // FFN
    gemm(X, 128, W(26) + (size_t)i * 32768, W(27) + i * 256,
         1, nullptr, FF1, 256, 400, 256, 128);
    gemm(FF1, 256, W(28) + (size_t)i * 32768, W(29) + i * 128,
         0, X, PRE, 128, 400, 128, 256);
    ln_k<<<100, 256, 0, stream>>>(PRE, W(24) + (i * 3 + 2) * 128, W(25) + (i * 3 + 2) * 128, X);
    // prediction heads
    conv1d_k<<<dim3(200, 2), 128, 0, stream>>>(X, W(30) + (size_t)i * 49152,
        W(31) + i * 128, W(32) + i * 128, W(33) + i * 128, YC);
    head2_k<<<4, 256, 0, stream>>>(YC, W(34) + (size_t)i * 768, W(35) + i * 2,
        qcur, CENT, 2, qnext);
    conv1d_k<<<dim3(200, 2), 128, 0, stream>>>(X, W(36) + (size_t)i * 49152,
        W(37) + i * 128, W(38) + i * 128, W(39) + i * 128, YC);
    head2_k<<<16, 256, 0, stream>>>(YC, W(40) + (size_t)i * 3840, W(41) + i * 10,
        nullptr, HMP, 10, nullptr);
  }
  out_k<<<19, 256, 0, stream>>>(CENT, HMP, d_out, FLAGS);
}

// Round 10
// 2412.468 us; speedup vs baseline: 2.2834x; 1.0149x over previous
//
#include <hip/hip_runtime.h>
#include <hip/hip_bf16.h>

typedef __hip_bfloat16 bf16;
typedef _Float16 f16;

#define HW 32400
#define NCLS 10
#define PQ 200
#define HIDDEN 128
#define NSPLIT 45
#define SPLITLEN 720    // 45*720 = 32400 exactly
#define QT 100
#define CAP 6144
#define NBIN 4096

typedef __attribute__((ext_vector_type(8))) _Float16 half8;
typedef __attribute__((ext_vector_type(8))) short short8;
typedef __attribute__((ext_vector_type(4))) short short4v;
typedef __attribute__((ext_vector_type(4))) float f32x4;

__device__ __forceinline__ float b2f(bf16 v) { return __bfloat162float(v); }
__device__ __forceinline__ void stf(float* p, float v) { *p = v; }
__device__ __forceinline__ void stf(bf16* p, float v) { *p = __float2bfloat16(v); }
// runtime-dtype load: isbf!=0 -> bf16 array, else fp32 array
__device__ __forceinline__ float ldsel(const void* p, long i, unsigned isbf) {
  return isbf ? __bfloat162float(((const bf16*)p)[i]) : ((const float*)p)[i];
}
__device__ __forceinline__ float ldf(const float* p, long i) { return p[i]; }
__device__ __forceinline__ float ldf(const bf16* p, long i) { return __bfloat162float(p[i]); }
__device__ __forceinline__ short f2bf_bits(float v) {
  union { bf16 h; short s; } u; u.h = __float2bfloat16(v); return u.s;
}

// ---------------------------------------------------------------------------
// dtype detection (bf16 vs fp32 inputs) -> FLAGS[0]
// ---------------------------------------------------------------------------
__global__ void detect_k(const unsigned* __restrict__ L, unsigned* __restrict__ FLAGS)
{
  __shared__ unsigned cnt[2];
  int tid = threadIdx.x;
  if (tid < 2) cnt[tid] = 0;
  __syncthreads();
  unsigned nz = 0, pl = 0;
  for (int w = tid; w < 4096; w += 256) {
    unsigned u = L[w];
    if (u) {
      nz++;
      unsigned e = (u >> 7) & 0xFF;
      if (e >= 110 && e <= 140) pl++;
    }
  }
  atomicAdd(&cnt[0], nz);
  atomicAdd(&cnt[1], pl);
  __syncthreads();
  if (tid == 0) {
    FLAGS[0] = (2u * cnt[1] > cnt[0]) ? 1u : 0u;
    FLAGS[1] = 0u;
  }
}

// batched weight conversion into fp32 arena (exact in both modes)
struct CvtArgs { const void* src[40]; int n[40]; int off[40]; };
__global__ __launch_bounds__(256) void cvt_k(CvtArgs a, float* __restrict__ dst,
                                             const unsigned* __restrict__ FLAGS)
{
  int j = blockIdx.y;
  unsigned isbf = FLAGS[0];
  int n = a.n[j];
  const void* s = a.src[j];
  float* d = dst + a.off[j];
  for (int t = blockIdx.x * 256 + threadIdx.x; t < n; t += gridDim.x * 256)
    d[t] = ldsel(s, t, isbf);
}

// ---------------------------------------------------------------------------
// Conv weight pre-swizzle into MFMA fragment order, fp16 hi (+scaled lo).
// WB[plane][tap][kb][nt][n16][k32] ; value = W[nt*16+n16][kb*32+k][ty][tx]
// plane1 = fp16((v - hi) * 4096)  (scale keeps lo in fp16 normal range)
// ---------------------------------------------------------------------------
__global__ __launch_bounds__(256) void wprep_k(const float* __restrict__ Wsrc,
    f16* __restrict__ WB, int N, int K, int KB, int NTG, int split)
{
  long total = (long)(split ? 2 : 1) * 9 * KB * NTG * 512;
  for (long t = (long)blockIdx.x * 256 + threadIdx.x; t < total;
       t += (long)gridDim.x * 256) {
    long r = t;
    int k = (int)(r & 31); r >>= 5;
    int n16 = (int)(r & 15); r >>= 4;
    int nt = (int)(r % NTG); r /= NTG;
    int kb = (int)(r % KB); r /= KB;
    int tap = (int)(r % 9); r /= 9;
    int plane = (int)r;
    int n = nt * 16 + n16, kk = kb * 32 + k;
    float v = 0.f;
    if (n < N && kk < K) v = Wsrc[((long)n * K + kk) * 9 + tap];
    f16 h = (f16)v;
    f16 outv = h;
    if (plane == 1) outv = (f16)((v - (float)h) * 4096.0f);
    WB[t] = outv;
  }
}

// ---------------------------------------------------------------------------
// MFMA conv2d 3x3 SAME as 9 shifted GEMMs over 64-pixel row chunks (60 valid).
// SPLIT=3: fp32-accurate fp16 split. SPLIT=1: plain fp16.
// Wave tiling (1,4,4,2) — A/B-measured best (R7 448µs vs R8 493µs).
// R10: XCD-aware y-band swizzle — blockIdx.x (0..543) remapped so each XCD
// (linear id & 7) owns a contiguous band of row-chunks; 3-row halo then
// reuses within one XCD's L2 (per-XCD L2s are not cross-coherent, so the
// default round-robin order defeats halo reuse).
// ---------------------------------------------------------------------------
template <int SPLIT, int WM, int WN, int MT, int NT, typename CT>
__global__ __launch_bounds__(256) void conv_mfma(
    const void* __restrict__ A, const unsigned* __restrict__ FLAGS, int dyn,
    long abatch,
    const f16* __restrict__ WB, const float* __restrict__ bias,
    const float* __restrict__ g, const float* __restrict__ beta, int act,
    CT* __restrict__ C, long cbatch, int N, int K, int KB, int NTG)
{
  constexpr int AW = 3 * 66 * 40;            // [ty][px][k] k-stride 40 (bank spread)
  __shared__ __align__(16) f16 Ah[AW];
  __shared__ __align__(16) f16 Al[SPLIT == 3 ? AW : 8];
  // XCD band swizzle: idx = (g&7)*68 + (g>>3); bands of 68 chunks per XCD
  int gsw = blockIdx.x;
  int idx = (gsw & 7) * 68 + (gsw >> 3);
  if (idx >= 540) return;
  unsigned isbf = dyn ? FLAGS[0] : 0u;
  int bz = blockIdx.z;
  int y = idx / 3;
  int x0 = (idx % 3) * 60;
  int tid = threadIdx.x;
  int w = tid >> 6, lane = tid & 63;
  int lane15 = lane & 15, lgrp = lane >> 4;
  int wm = w % WM, wn = w / WM;
  int mbase = wm * MT * 16;
  int nbase = wn * NT * 16;
  f32x4 accM[MT][NT] = {};
  f32x4 accC[SPLIT == 3 ? MT : 1][SPLIT == 3 ? NT : 1] = {};
  long planeStride = (long)9 * KB * NTG * 512;

  for (int kb = 0; kb < KB; kb++) {
    __syncthreads();
    for (int e = tid; e < 3 * 32 * 66; e += 256) {
      int row = e / (32 * 66);
      int rem = e - row * (32 * 66);
      int k = rem / 66;
      int px = rem - k * 66;
      int gx = x0 + px - 1, gy = y + row - 1;
      int kk = kb * 32 + k;
      float v = 0.f;
      if (gx >= 0 && gx < 180 && gy >= 0 && gy < 180 && kk < K)
        v = ldsel(A, (long)bz * abatch + (long)kk * HW + gy * 180 + gx, isbf);
      f16 h = (f16)v;
      Ah[(row * 66 + px) * 40 + k] = h;
      if constexpr (SPLIT == 3)
        Al[(row * 66 + px) * 40 + k] = (f16)((v - (float)h) * 4096.0f);
    }
    __syncthreads();
#pragma unroll
    for (int tap = 0; tap < 9; tap++) {
      int ty = tap / 3, tx = tap % 3;
      const f16* wb = WB + (((long)tap * KB + kb) * NTG) * 512;
      half8 bh[NT], bl[SPLIT == 3 ? NT : 1];
#pragma unroll
      for (int nt = 0; nt < NT; nt++) {
        long o = (long)(wn * NT + nt) * 512 + lane15 * 32 + lgrp * 8;
        bh[nt] = *(const half8*)(wb + o);
        if constexpr (SPLIT == 3) bl[nt] = *(const half8*)(wb + planeStride + o);
      }
      half8 ah[MT], al[SPLIT == 3 ? MT : 1];
#pragma unroll
      for (int mt = 0; mt < MT; mt++) {
        int px = mbase + mt * 16 + lane15 + tx;
        int o = (ty * 66 + px) * 40 + lgrp * 8;
        ah[mt] = *(const half8*)&Ah[o];
        if constexpr (SPLIT == 3) al[mt] = *(const half8*)&Al[o];
      }
#pragma unroll
      for (int mt = 0; mt < MT; mt++)
#pragma unroll
        for (int nt = 0; nt < NT; nt++) {
          accM[mt][nt] = __builtin_amdgcn_mfma_f32_16x16x32_f16(
              ah[mt], bh[nt], accM[mt][nt], 0, 0, 0);
          if constexpr (SPLIT == 3) {
            accC[mt][nt] = __builtin_amdgcn_mfma_f32_16x16x32_f16(
                al[mt], bh[nt], accC[mt][nt], 0, 0, 0);
            accC[mt][nt] = __builtin_amdgcn_mfma_f32_16x16x32_f16(
                ah[mt], bl[nt], accC[mt][nt], 0, 0, 0);
          }
        }
    }
  }
  int pixbase = y * 180 + x0;
#pragma unroll
  for (int mt = 0; mt < MT; mt++) {
    int m = mbase + mt * 16 + lgrp * 4;
    if (m >= 60) continue;
#pragma unroll
    for (int nt = 0; nt < NT; nt++) {
      int n = nbase + nt * 16 + lane15;
      if (n >= N) continue;
      float bi = bias[n];
      float gg = g ? g[n] : 1.f;
      float bb = g ? beta[n] : 0.f;
      long base = (long)bz * cbatch + (long)n * HW + pixbase + m;
      if constexpr (sizeof(CT) == 4) {
        f32x4 ov;
#pragma unroll
        for (int r = 0; r < 4; r++) {
          float v = accM[mt][nt][r];
          if constexpr (SPLIT == 3) v += accC[mt][nt][r] * (1.f / 4096.f);
          v += bi;
          if (g) v = v * gg + bb;
          if (act == 1) v = fmaxf(v, 0.f);
          else if (act == 2) v = 1.f / (1.f + expf(-v));
          ov[r] = v;
        }
        *(f32x4*)&C[base] = ov;
      } else {
        short4v ov;
#pragma unroll
        for (int r = 0; r < 4; r++) {
          float v = accM[mt][nt][r];
          if constexpr (SPLIT == 3) v += accC[mt][nt][r] * (1.f / 4096.f);
          v += bi;
          if (g) v = v * gg + bb;
          if (act == 1) v = fmaxf(v, 0.f);
          ov[r] = f2bf_bits(v);
        }
        *(short4v*)&C[base] = ov;
      }
    }
  }
}

// ---------------------------------------------------------------------------
// bf16 MFMA KV projection: C = (A1+A2) @ W^T + bias.
// ---------------------------------------------------------------------------
__global__ __launch_bounds__(256) void kvproj_k(
    const bf16* __restrict__ A1, const bf16* __restrict__ A2,
    const float* __restrict__ Wf, const float* __restrict__ bias,
    bf16* __restrict__ C)
{
  __shared__ __align__(16) short As[64 * 40];
  int m0 = blockIdx.x * 64;
  int n0 = blockIdx.y * 64;
  int b = blockIdx.z;
  int tid = threadIdx.x;
  int w = tid >> 6, lane = tid & 63;
  int lane15 = lane & 15, lgrp = lane >> 4;
  int wm = w & 1, wn = w >> 1;
  const bf16* A1b = A1 + (long)b * 128 * HW;
  f32x4 acc[2][2] = {};
  for (int kb = 0; kb < 4; kb++) {
    __syncthreads();
    for (int e = tid; e < 2048; e += 256) {
      int k = e >> 6, m = e & 63;
      int gm = m0 + m;
      float v = 0.f;
      if (gm < HW) {
        long idx = (long)(kb * 32 + k) * HW + gm;
        v = b2f(A1b[idx]) + b2f(A2[idx]);
      }
      As[m * 40 + k] = f2bf_bits(v);
    }
    __syncthreads();
    short8 bh[2];
#pragma unroll
    for (int nt = 0; nt < 2; nt++) {
      int n = n0 + wn * 32 + nt * 16 + lane15;
      const float* wr = Wf + (long)n * 128 + kb * 32 + lgrp * 8;
      float4 w0 = *(const float4*)wr;
      float4 w1 = *(const float4*)(wr + 4);
      short8 t;
      t[0] = f2bf_bits(w0.x); t[1] = f2bf_bits(w0.y);
      t[2] = f2bf_bits(w0.z); t[3] = f2bf_bits(w0.w);
      t[4] = f2bf_bits(w1.x); t[5] = f2bf_bits(w1.y);
      t[6] = f2bf_bits(w1.z); t[7] = f2bf_bits(w1.w);
      bh[nt] = t;
    }
    short8 ah[2];
#pragma unroll
    for (int mt = 0; mt < 2; mt++) {
      int m = wm * 32 + mt * 16 + lane15;
      ah[mt] = *(const short8*)&As[m * 40 + lgrp * 8];
    }
#pragma unroll
    for (int mt = 0; mt < 2; mt++)
#pragma unroll
      for (int nt = 0; nt < 2; nt++)
        acc[mt][nt] = __builtin_amdgcn_mfma_f32_16x16x32_bf16(
            ah[mt], bh[nt], acc[mt][nt], 0, 0, 0);
  }
#pragma unroll
  for (int mt = 0; mt < 2; mt++) {
    int mq = m0 + wm * 32 + mt * 16 + lgrp * 4;
    if (mq >= HW) continue;
#pragma unroll
    for (int nt = 0; nt < 2; nt++) {
      int n = n0 + wn * 32 + nt * 16 + lane15;
      float bi = bias[n];
      short4v ov;
#pragma unroll
      for (int r = 0; r < 4; r++) ov[r] = f2bf_bits(acc[mt][nt][r] + bi);
      *(short4v*)&C[(long)b * 256 * HW + (long)n * HW + mq] = ov;
    }
  }
}

// ---------------------------------------------------------------------------
// Generic tiled GEMM: C = act((A [+A2]) @ W^T + bias) (+ res)
// amode 0: A[m*lda+k] (+A2 same layout).  amode 2: fused BEV pos-embed as A.
// amode 3: fused QUERY pos-embed: A = qpos [M][2]; row m ->
//          relu((q0*pe1w[2k]+q1*pe1w[2k+1]+pe1b[k])*pe1g[k]+pe1bt[k]).
// cmode 0: C[m*ldc+n] ; cmode 1: C[n*ldc+m].  K multiple of 16.
// ---------------------------------------------------------------------------
template <typename AT, typename CT>
__global__ __launch_bounds__(256) void gemm_k(
    const AT* __restrict__ A, const AT* __restrict__ A2, int lda, int amode,
    long abatch,
    const float* __restrict__ W, const float* __restrict__ bias, int act,
    const float* __restrict__ res,
    const float* __restrict__ pe1w, const float* __restrict__ pe1b,
    const float* __restrict__ pe1g, const float* __restrict__ pe1bt,
    CT* __restrict__ C, int ldc, int cmode, long cbatch,
    int M, int N, int K)
{
  __shared__ __align__(16) float As[16][68];
  __shared__ __align__(16) float Ws[16][68];
  int b = blockIdx.z;
  int m0 = blockIdx.x * 64, n0 = blockIdx.y * 64;
  int tid = threadIdx.x;
  int nt = tid & 15, mt = tid >> 4;
  float acc[4][4] = {};
  const AT* Ab = A + (long)b * abatch;
  for (int k0 = 0; k0 < K; k0 += 16) {
    if (amode == 0) {
      for (int e = tid; e < 1024; e += 256) {
        int m = e >> 4, k = e & 15;
        float v = 0.f;
        if (m0 + m < M) {
          long idx = (long)(m0 + m) * lda + k0 + k;
          v = ldf(Ab, idx);
          if (A2) v += ldf(A2, idx);
        }
        As[k][m] = v;
      }
    } else if (amode == 2) {
      for (int e = tid; e < 1024; e += 256) {
        int m = e & 63, k = e >> 6;
        float v = 0.f;
        int gm = m0 + m;
        if (gm < M) {
          float p0 = (float)(gm / 180) + 0.5f;
          float p1 = (float)(gm % 180) + 0.5f;
          int kk = k0 + k;
          float t = p0 * pe1w[kk * 2] + p1 * pe1w[kk * 2 + 1] + pe1b[kk];
          t = t * pe1g[kk] + pe1bt[kk];
          v = fmaxf(t, 0.f);
        }
        As[k][m] = v;
      }
    } else { // amode 3: query pos-embed, A = qpos (fp32 [M][2])
      const float* qp = (const float*)A;
      for (int e = tid; e < 1024; e += 256) {
        int m = e & 63, k = e >> 6;
        float v = 0.f;
        int gm = m0 + m;
        if (gm < M) {
          float p0 = qp[gm * 2], p1 = qp[gm * 2 + 1];
          int kk = k0 + k;
          float t = p0 * pe1w[kk * 2] + p1 * pe1w[kk * 2 + 1] + pe1b[kk];
          t = t * pe1g[kk] + pe1bt[kk];
          v = fmaxf(t, 0.f);
        }
        As[k][m] = v;
      }
    }
    for (int e = tid; e < 1024; e += 256) {
      int n = e >> 4, k = e & 15;
      float v = 0.f;
      if (n0 + n < N) v = W[(long)(n0 + n) * K + k0 + k];
      Ws[k][n] = v;
    }
    __syncthreads();
#pragma unroll
    for (int kk = 0; kk < 16; kk++) {
      float4 av = *(const float4*)&As[kk][mt * 4];
      float4 wv = *(const float4*)&Ws[kk][nt * 4];
      float am[4] = {av.x, av.y, av.z, av.w};
      float wn[4] = {wv.x, wv.y, wv.z, wv.w};
#pragma unroll
      for (int mi = 0; mi < 4; mi++)
#pragma unroll
        for (int ni = 0; ni < 4; ni++)
          acc[mi][ni] = fmaf(am[mi], wn[ni], acc[mi][ni]);
    }
    __syncthreads();
  }
#pragma unroll
  for (int mi = 0; mi < 4; mi++) {
    int m = m0 + mt * 4 + mi;
    if (m >= M) continue;
#pragma unroll
    for (int ni = 0; ni < 4; ni++) {
      int n = n0 + nt * 4 + ni;
      if (n >= N) continue;
      float v = acc[mi][ni];
      if (bias) v += bias[n];
      if (act == 1) v = fmaxf(v, 0.f);
      if (res) v += res[(long)m * ldc + n];
      long ci = (cmode == 0) ? ((long)b * cbatch + (long)m * ldc + n)
                             : ((long)b * cbatch + (long)n * ldc + m);
      stf(&C[ci], v);
    }
  }
}

// ---------------------------------------------------------------------------
__global__ void nms_k(const float* __restrict__ HEAT, float* __restrict__ SCORE)
{
  int t = blockIdx.x * 256 + threadIdx.x;
  if (t >= 2 * NCLS * HW) return;
  int b = t / (NCLS * HW); int r = t % (NCLS * HW);
  int cls = r / HW; int n = r % HW;
  const float* hb = HEAT + ((long)(b * NCLS + cls)) * HW;
  float v = hb[n];
  bool keep = true;
  if (cls < 8) {
    int y = n / 180, x = n % 180;
    if (y == 0 || y == 179 || x == 0 || x == 179) keep = false;
    else {
      float mx = -1e30f;
#pragma unroll
      for (int dy = -1; dy <= 1; dy++)
#pragma unroll
        for (int dx = -1; dx <= 1; dx++)
          mx = fmaxf(mx, hb[(y + dy) * 180 + x + dx]);
      keep = (v == mx);
    }
  }
  SCORE[(long)b * (NCLS * HW) + r] = keep ? v : 0.f;
}

__global__ void zero_u32(unsigned* p, int n)
{
  int t = blockIdx.x * 256 + threadIdx.x;
  if (t < n) p[t] = 0;
}

__global__ __launch_bounds__(256) void hist_k(const float* __restrict__ SCORE,
                                              unsigned* __restrict__ HIST)
{
  __shared__ unsigned lh[NBIN];
  int b = blockIdx.y;
  for (int e = threadIdx.x; e < NBIN; e += 256) lh[e] = 0;
  __syncthreads();
  int start = blockIdx.x * 1350;
  const float* sb = SCORE + (long)b * (NCLS * HW);
  for (int e = start + threadIdx.x; e < start + 1350; e += 256) {
    unsigned bits = __float_as_uint(sb[e]);
    atomicAdd(&lh[bits >> 18], 1u);
  }
  __syncthreads();
  for (int e = threadIdx.x; e < NBIN; e += 256) {
    unsigned c = lh[e];
    if (c) atomicAdd(&HIST[b * NBIN + e], c);
  }
}

__global__ void thresh_k(const unsigned* __restrict__ HIST, unsigned* __restrict__ THR)
{
  __shared__ unsigned ps[256];
  int b = blockIdx.x;
  const unsigned* hb = HIST + b * NBIN;
  unsigned s = 0;
  for (int j = 0; j < 16; j++) s += hb[threadIdx.x * 16 + j];
  ps[threadIdx.x] = s;
  __syncthreads();
  if (threadIdx.x == 0) {
    unsigned cum = 0; int t = 255;
    for (; t > 0; t--) { if (cum + ps[t] >= PQ) break; cum += ps[t]; }
    int bin = t * 16 + 15;
    for (; bin > t * 16; bin--) { unsigned c = hb[bin]; if (cum + c >= PQ) break; cum += c; }
    if (bin < 1) bin = 1;
    THR[b] = (unsigned)bin;
  }
}

__global__ void collect_k(const float* __restrict__ SCORE, const unsigned* __restrict__ THR,
                          unsigned* __restrict__ ACNT, unsigned long long* __restrict__ CAND)
{
  int t = blockIdx.x * 256 + threadIdx.x;
  if (t >= 2 * NCLS * HW) return;
  int b = t / (NCLS * HW); int r = t % (NCLS * HW);
  float v = SCORE[(long)b * (NCLS * HW) + r];
  unsigned bits = __float_as_uint(v);
  if ((bits >> 18) >= THR[b]) {
    unsigned slot = atomicAdd(&ACNT[b], 1u);
    if (slot < CAP) CAND[(long)b * CAP + slot] =
        ((unsigned long long)bits << 32) | (unsigned)(~r);
  }
}

__global__ __launch_bounds__(64) void select_k(
    const unsigned long long* __restrict__ CAND, const unsigned* __restrict__ ACNT,
    unsigned* __restrict__ TOPC, unsigned* __restrict__ TOPI, float* __restrict__ QPA)
{
  __shared__ unsigned long long cnd[CAP];
  int b = blockIdx.x;
  int lane = threadIdx.x;
  unsigned cnt = ACNT[b]; if (cnt > CAP) cnt = CAP;
  for (int e = lane; e < (int)cnt; e += 64) cnd[e] = CAND[(long)b * CAP + e];
  __syncthreads();
  for (int p = 0; p < PQ; p++) {
    unsigned long long best = 0;
    for (int e = lane; e < (int)cnt; e += 64) { unsigned long long c = cnd[e]; if (c > best) best = c; }
#pragma unroll
    for (int o = 32; o; o >>= 1) {
      unsigned long long other = __shfl_xor(best, o, 64);
      if (other > best) best = other;
    }
    for (int e = lane; e < (int)cnt; e += 64) if (best != 0 && cnd[e] == best) cnd[e] = 0;
    if (lane == 0) {
      unsigned idx = (best == 0) ? 0u : ~(unsigned)(best & 0xFFFFFFFFull);
      if (idx >= NCLS * HW) idx = 0;
      unsigned cls = idx / HW, n = idx % HW;
      TOPC[b * PQ + p] = cls; TOPI[b * PQ + p] = n;
      QPA[((long)(b * PQ + p)) * 2 + 0] = (float)(n / 180) + 0.5f;
      QPA[((long)(b * PQ + p)) * 2 + 1] = (float)(n % 180) + 0.5f;
    }
    __syncthreads();
  }
}

__global__ void gather_k(const float* __restrict__ LIDF, const unsigned* __restrict__ TOPC,
                         const unsigned* __restrict__ TOPI, const float* __restrict__ cew,
                         const float* __restrict__ ceb, float* __restrict__ X)
{
  int t = blockIdx.x * 256 + threadIdx.x;
  if (t >= 2 * PQ * HIDDEN) return;
  int c = t & 127; int r = t >> 7; int p = r % PQ; int b = r / PQ;
  unsigned n = TOPI[b * PQ + p]; unsigned cls = TOPC[b * PQ + p];
  if (n >= HW) n = 0;
  if (cls >= NCLS) cls = 0;
  X[t] = LIDF[((long)(b * HIDDEN + c)) * HW + n] + cew[c * NCLS + cls] + ceb[c];
}

__global__ __launch_bounds__(64) void self_attn_k(const float* __restrict__ SQKV,
                                                  float* __restrict__ SAO)
{
  int q = blockIdx.x, h = blockIdx.y, b = blockIdx.z;
  int lane = threadIdx.x;
  const float* qp = SQKV + ((long)(b * PQ + q)) * 384 + h * 16;
  float qv[16];
#pragma unroll
  for (int d = 0; d < 16; d++) qv[d] = qp[d] * 0.25f;
  float sv[4]; int kks[4]; int nk = 0;
  float lmax = -1e30f;
  for (int kk = lane; kk < PQ; kk += 64) {
    const float* kp = SQKV + ((long)(b * PQ + kk)) * 384 + 128 + h * 16;
    float s = 0.f;
#pragma unroll
    for (int d = 0; d < 16; d++) s = fmaf(qv[d], kp[d], s);
    sv[nk] = s; kks[nk] = kk; nk++;
    lmax = fmaxf(lmax, s);
  }
#pragma unroll
  for (int o = 32; o; o >>= 1) lmax = fmaxf(lmax, __shfl_xor(lmax, o, 64));
  float lsum = 0.f; float acc[16] = {};
  for (int t = 0; t < nk; t++) {
    float p = expf(sv[t] - lmax);
    lsum += p;
    const float* vp = SQKV + ((long)(b * PQ + kks[t])) * 384 + 256 + h * 16;
#pragma unroll
    for (int d = 0; d < 16; d++) acc[d] = fmaf(p, vp[d], acc[d]);
  }
#pragma unroll
  for (int o = 32; o; o >>= 1) lsum += __shfl_xor(lsum, o, 64);
#pragma unroll
  for (int d = 0; d < 16; d++) {
    float v = acc[d];
#pragma unroll
    for (int o = 32; o; o >>= 1) v += __shfl_xor(v, o, 64);
    if (lane == 0) SAO[((long)(b * PQ + q)) * HIDDEN + h * 16 + d] = v / lsum;
  }
}

// ---------------------------------------------------------------------------
// flash cross-attention, key-split. QK + online softmax merged (8-lane q-group
// shuffle stats), K/V staging ping-pong. 2 barriers/tile.
// ---------------------------------------------------------------------------
__global__ __launch_bounds__(256) void flash_k(const float* __restrict__ QH,
                                               const bf16* __restrict__ KVT,
                                               float* __restrict__ PART)
{
  int s = blockIdx.x, h = blockIdx.y;
  int b = blockIdx.z >> 1, qh = blockIdx.z & 1;
  int tid = threadIdx.x;
  __shared__ __align__(16) float sL[QT][36];
  __shared__ __align__(16) float qtL[16][104];
  __shared__ __align__(16) float kjL[2][16][36];
  __shared__ __align__(16) float vjL[2][16][36];
  __shared__ float mL[QT], lL[QT], aL[QT];
  int qbase = qh * QT;
  for (int e = tid; e < QT * 16; e += 256) {
    int q = e >> 4, d = e & 15;
    qtL[d][q] = QH[((long)(b * PQ + qbase + q)) * HIDDEN + h * 16 + d] * 0.25f;
  }
  if (tid < QT) { mL[tid] = -1e30f; lL[tid] = 0.f; }
  float ovr[4][2] = {};
  int qg = tid >> 3, jg = tid & 7;
  int q0 = qg * 4, j0 = jg * 4;
  int pd = (tid & 7) * 2;
  int nbeg = s * SPLITLEN;
  const bf16* Kb = KVT + (long)b * 256 * HW + (long)(h * 16) * HW;
  const bf16* Vb = Kb + (long)128 * HW;
  int sd = tid >> 4, sj = (tid & 15) * 2;
  {
    long o = (long)sd * HW + nbeg + sj;
    float2 kv, vv;
    kv.x = b2f(Kb[o]);     kv.y = b2f(Kb[o + 1]);
    vv.x = b2f(Vb[o]);     vv.y = b2f(Vb[o + 1]);
    *(float2*)&kjL[0][sd][sj] = kv;
    *(float2*)&vjL[0][sd][sj] = vv;
  }
  __syncthreads();
  const int ntiles = (SPLITLEN + 31) / 32;
  for (int t = 0; t < ntiles; t++) {
    int cur = t & 1;
    if (t + 1 < ntiles) {
      int n0 = nbeg + (t + 1) * 32;
      int rem = SPLITLEN - (t + 1) * 32; if (rem > 32) rem = 32;
      float2 kv = {0.f, 0.f}, vv = {0.f, 0.f};
      if (sj < rem) {
        long o = (long)sd * HW + n0 + sj;
        kv.x = b2f(Kb[o]); vv.x = b2f(Vb[o]);
        if (sj + 1 < rem) { kv.y = b2f(Kb[o + 1]); vv.y = b2f(Vb[o + 1]); }
      }
      *(float2*)&kjL[cur ^ 1][sd][sj] = kv;
      *(float2*)&vjL[cur ^ 1][sd][sj] = vv;
    }
    int remt = SPLITLEN - t * 32; if (remt > 32) remt = 32;
    if (tid < 200) {
      float acc[4][4] = {};
#pragma unroll
      for (int d = 0; d < 16; d++) {
        float4 kv = *(const float4*)&kjL[cur][d][j0];
        float4 qv = *(const float4*)&qtL[d][q0];
        float qa[4] = {qv.x, qv.y, qv.z, qv.w};
        float ka[4] = {kv.x, kv.y, kv.z, kv.w};
#pragma unroll
        for (int i = 0; i < 4; i++)
#pragma unroll
          for (int jj = 0; jj < 4; jj++)
            acc[i][jj] = fmaf(qa[i], ka[jj], acc[i][jj]);
      }
      if (remt < 32) {
#pragma unroll
        for (int i = 0; i < 4; i++)
#pragma unroll
          for (int jj = 0; jj < 4; jj++)
            if (j0 + jj >= remt) acc[i][jj] = -1e30f;
      }
#pragma unroll
      for (int i = 0; i < 4; i++) {
        float mx = fmaxf(fmaxf(acc[i][0], acc[i][1]), fmaxf(acc[i][2], acc[i][3]));
        mx = fmaxf(mx, __shfl_xor(mx, 1, 64));
        mx = fmaxf(mx, __shfl_xor(mx, 2, 64));
        mx = fmaxf(mx, __shfl_xor(mx, 4, 64));
        float mold = mL[q0 + i];
        float mnew = fmaxf(mx, mold);
        float ls = 0.f;
#pragma unroll
        for (int jj = 0; jj < 4; jj++) {
          float p = expf(acc[i][jj] - mnew);
          acc[i][jj] = p;
          ls += p;
        }
        ls += __shfl_xor(ls, 1, 64);
        ls += __shfl_xor(ls, 2, 64);
        ls += __shfl_xor(ls, 4, 64);
        if (jg == 0) {
          float al = expf(mold - mnew);
          lL[q0 + i] = lL[q0 + i] * al + ls;
          mL[q0 + i] = mnew;
          aL[q0 + i] = al;
        }
        float4 ov;
        ov.x = acc[i][0]; ov.y = acc[i][1]; ov.z = acc[i][2]; ov.w = acc[i][3];
        *(float4*)&sL[q0 + i][j0] = ov;
      }
    }
    __syncthreads();
    if (tid < 200) {
#pragma unroll
      for (int i = 0; i < 4; i++) {
        float a = aL[qg + 25 * i];
        ovr[i][0] *= a; ovr[i][1] *= a;
      }
#pragma unroll
      for (int j00 = 0; j00 < 32; j00 += 4) {
        float4 v0 = *(const float4*)&vjL[cur][pd][j00];
        float4 v1 = *(const float4*)&vjL[cur][pd + 1][j00];
#pragma unroll
        for (int i = 0; i < 4; i++) {
          float4 p = *(const float4*)&sL[qg + 25 * i][j00];
          ovr[i][0] = fmaf(p.x, v0.x, ovr[i][0]);
          ovr[i][0] = fmaf(p.y, v0.y, ovr[i][0]);
          ovr[i][0] = fmaf(p.z, v0.z, ovr[i][0]);
          ovr[i][0] = fmaf(p.w, v0.w, ovr[i][0]);
          ovr[i][1] = fmaf(p.x, v1.x, ovr[i][1]);
          ovr[i][1] = fmaf(p.y, v1.y, ovr[i][1]);
          ovr[i][1] = fmaf(p.z, v1.z, ovr[i][1]);
          ovr[i][1] = fmaf(p.w, v1.w, ovr[i][1]);
        }
      }
    }
    __syncthreads();
  }
  long base = ((((long)(b * 8 + h)) * NSPLIT + s) * PQ) * 18;
  if (tid < 200) {
#pragma unroll
    for (int i = 0; i < 4; i++) {
      long ro = base + (long)(qbase + qg + 25 * i) * 18;
      PART[ro + pd] = ovr[i][0];
      PART[ro + pd + 1] = ovr[i][1];
    }
  }
  if (tid < QT) {
    long ro = base + (long)(qbase + tid) * 18;
    PART[ro + 16] = mL[tid];
    PART[ro + 17] = lL[tid];
  }
}

__global__ void combine_k(const float* __restrict__ PART, float* __restrict__ CAO)
{
  int t = blockIdx.x * 256 + threadIdx.x;
  if (t >= 2 * 8 * PQ * 16) return;
  int d = t & 15; int r = t >> 4;
  int q = r % PQ; r /= PQ;
  int h = r & 7; int b = r >> 3;
  long base = (((long)(b * 8 + h)) * NSPLIT) * PQ * 18 + (long)q * 18;
  float M = -1e30f;
  for (int s = 0; s < NSPLIT; s++) M = fmaxf(M, PART[base + (long)s * PQ * 18 + 16]);
  float L = 0.f, O = 0.f;
  for (int s = 0; s < NSPLIT; s++) {
    long p0 = base + (long)s * PQ * 18;
    float w = expf(PART[p0 + 16] - M);
    L += PART[p0 + 17] * w;
    O += PART[p0 + d] * w;
  }
  CAO[((long)(b * PQ + q)) * HIDDEN + h * 16 + d] = (L > 0.f) ? O / L : 0.f;
}

__global__ __launch_bounds__(256) void ln_k(const float* __restrict__ PRE,
                                            const float* __restrict__ g,
                                            const float* __restrict__ bta,
                                            float* __restrict__ X)
{
  int row = blockIdx.x * 4 + (threadIdx.x >> 6);
  int lane = threadIdx.x & 63;
  const float* p = PRE + (long)row * HIDDEN;
  float v0 = p[lane], v1 = p[lane + 64];
  float s = v0 + v1;
#pragma unroll
  for (int o = 32; o; o >>= 1) s += __shfl_xor(s, o, 64);
  float mu = s * (1.f / 128.f);
  float d0 = v0 - mu, d1 = v1 - mu;
  float vs = d0 * d0 + d1 * d1;
#pragma unroll
  for (int o = 32; o; o >>= 1) vs += __shfl_xor(vs, o, 64);
  float rs = rsqrtf(vs * (1.f / 128.f) + 1e-5f);
  float* xo = X + (long)row * HIDDEN;
  xo[lane] = d0 * rs * g[lane] + bta[lane];
  xo[lane + 64] = d1 * rs * g[lane + 64] + bta[lane + 64];
}

__global__ __launch_bounds__(128) void conv1d_k(const float* __restrict__ X,
                                                const float* __restrict__ w,
                                                const float* __restrict__ bias,
                                                const float* __restrict__ g,
                                                const float* __restrict__ beta,
                                                float* __restrict__ Y)
{
  int p = blockIdx.x, b = blockIdx.y;
  int co = threadIdx.x;
  __shared__ float xs[3][HIDDEN];
  for (int e = co; e < 3 * HIDDEN; e += HIDDEN) {
    int t = e >> 7, c = e & 127;
    int pp = p + t - 1;
    xs[t][c] = (pp >= 0 && pp < PQ) ? X[((long)(b * PQ + pp)) * HIDDEN + c] : 0.f;
  }
  __syncthreads();
  const float* wr = w + (long)co * HIDDEN * 3;
  float acc = 0.f;
  for (int c = 0; c < HIDDEN; c++) {
    acc = fmaf(xs[0][c], wr[c * 3 + 0], acc);
    acc = fmaf(xs[1][c], wr[c * 3 + 1], acc);
    acc = fmaf(xs[2][c], wr[c * 3 + 2], acc);
  }
  float v = (acc + bias[co]) * g[co] + beta[co];
  Y[((long)(b * PQ + p)) * HIDDEN + co] = fmaxf(v, 0.f);
}

__global__ void head2_k(const float* __restrict__ Y, const float* __restrict__ w,
                        const float* __restrict__ bias, const float* __restrict__ qpos,
                        float* __restrict__ OUT, int N, float* __restrict__ qnext)
{
  int t = blockIdx.x * 256 + threadIdx.x;
  if (t >= 2 * N * PQ) return;
  int p = t % PQ; int r = t / PQ; int co = r % N; int b = r / N;
  const float* wr = w + (long)co * HIDDEN * 3;
  float acc = 0.f;
  for (int tap = 0; tap < 3; tap++) {
    int pp = p + tap - 1;
    if (pp < 0 || pp >= PQ) continue;
    const float* yr = Y + ((long)(b * PQ + pp)) * HIDDEN;
    for (int c = 0; c < HIDDEN; c++)
      acc = fmaf(yr[c], wr[c * 3 + tap], acc);
  }
  float v = acc + bias[co];
  if (qpos) v += qpos[((long)(b * PQ + p)) * 2 + co];
  OUT[((long)(b * N + co)) * PQ + p] = v;
  if (qnext) qnext[((long)(b * PQ + p)) * 2 + co] = v;
}

__global__ void out_k(const float* __restrict__ CENT, const float* __restrict__ HMP,
                      void* __restrict__ out, const unsigned* __restrict__ FLAGS)
{
  int t = blockIdx.x * 256 + threadIdx.x;
  if (t >= 2 * 12 * PQ) return;
  int p = t % PQ; int r = t / PQ; int ch = r % 12; int b = r / 12;
  float v = (ch < 2) ? CENT[((long)(b * 2 + ch)) * PQ + p]
                     : HMP[((long)(b * 10 + ch - 2)) * PQ + p];
  if (FLAGS[0]) ((bf16*)out)[t] = __float2bfloat16(v);
  else          ((float*)out)[t] = v;
}

// ---------------------------------------------------------------------------
extern "C" void kernel_launch(void* const* d_in, const int* in_sizes, int n_in,
                              void* d_out, int out_size, void* d_ws, size_t ws_size,
                              hipStream_t stream)
{
  (void)n_in; (void)out_size; (void)ws_size;

  // ---- workspace layout (~80 MB == R3's validated watermark) --------------
  float* F = (float*)d_ws;
  size_t off = 0;
  int aoff[42];
  {
    size_t acc = 0;
    for (int i = 2; i < 42; i++) { aoff[i] = (int)acc; acc += (size_t)in_sizes[i]; }
    off = acc;
  }
  float* ARENA = F;
  float* LIDF = F + off;                        // [2][128][HW] fp32 (dead after gather)
  bf16*  KVT16 = (bf16*)(F + off);              // alias: [2][256][HW] bf16 (decoder)
  off += 8294400;
  float* HBUF = F + off;                        // [1][128][HW] fp32 (per-batch reuse)
  bf16*  KPET16 = (bf16*)(F + off);             // alias: [128][HW] bf16 (decoder)
  float* PART  = F + off;                       // alias: [2][8][NSPLIT][200][18]
  off += 4147200;
  bf16*  CAMF16 = (bf16*)(F + off);             // [2][128][HW] bf16 (live all run)
  off += 4147200;
  float* HEAT  = F + off;                       // [2][10][HW] (dead after nms)
  float* SCORE = F + off + 648000;              // (dead after collect)
  off += 1296000;
  float* X   = F + off; off += 51200;           // decoder smalls — all dead during
  float* XQ  = F + off; off += 51200;           // convs; WB_* aliases this region
  float* QPE = F + off; off += 51200;
  float* T1Q = F + off; off += 51200;
  float* SQKV = F + off; off += 153600;
  float* SAO = F + off; off += 51200;
  float* PRE = F + off; off += 51200;
  float* QH2 = F + off; off += 51200;
  float* CAO = F + off; off += 51200;
  float* FF1 = F + off; off += 102400;
  float* YC  = F + off; off += 51200;           // X..YC span = 716800 floats
  float* CENT = F + off; off += 800;
  float* HMP = F + off; off += 4000;
  float* QPA = F + off; off += 800;
  float* QPB = F + off; off += 800;
  unsigned* U = (unsigned*)(F + off);
  unsigned* HIST  = U;                          // [0, 8192)
  unsigned* ACNT  = U + 8192;                   // 2
  unsigned* THR   = U + 8194;                   // 2
  unsigned* FLAGS = U + 8196;                   // 2 (NOT zeroed by zero_u32)
  unsigned* TOPC  = U + 8198;                   // 400
  unsigned* TOPI  = U + 8598;                   // 400
  unsigned long long* CAND = (unsigned long long*)(U + 9000); // 2*CAP u64
  // fp16 MFMA weight planes: alias the decoder-smalls region (dead during
  // wprep + convs). 1,327,104 f16 = 663,552 floats fits 716,800-float span.
  f16* WB_LID = (f16*)((((uintptr_t)X) + 15) & ~(uintptr_t)15);
  f16* WB_CAM = WB_LID + 884736;                // 2*9*12*8*512 = 884736
  f16* WB_HM1 = WB_CAM + 110592;                // 1*9*3*8*512  = 110592
  f16* WB_HM2 = WB_HM1 + 294912;                // 2*9*4*8*512  = 294912 (+36864)

  auto W = [&](int i) -> const float* { return ARENA + aoff[i]; };

  // ---- dtype detect + weight conversion -----------------------------------
  detect_k<<<1, 256, 0, stream>>>((const unsigned*)d_in[0], FLAGS);
  {
    CvtArgs a;
    for (int i = 2; i < 42; i++) { a.src[i - 2] = d_in[i]; a.n[i - 2] = in_sizes[i]; a.off[i - 2] = aoff[i]; }
    cvt_k<<<dim3(432, 40), 256, 0, stream>>>(a, ARENA, FLAGS);
  }
  wprep_k<<<3456, 256, 0, stream>>>(W(2), WB_LID, 128, 384, 12, 8, 1);
  wprep_k<<<432, 256, 0, stream>>>(W(4), WB_CAM, 128, 80, 3, 8, 0);
  wprep_k<<<1152, 256, 0, stream>>>(W(6), WB_HM1, 128, 128, 4, 8, 1);
  wprep_k<<<144, 256, 0, stream>>>(W(10), WB_HM2, 10, 128, 4, 1, 1);

  auto gemm = [&](const float* A, const float* A2, int lda, const float* Wp,
                  const float* bias, int act, const float* res, float* C, int ldc,
                  int M, int N, int K) {
    dim3 grid((M + 63) / 64, (N + 63) / 64, 1);
    gemm_k<float, float><<<grid, 256, 0, stream>>>(
        A, A2, lda, 0, 0L, Wp, bias, act, res,
        nullptr, nullptr, nullptr, nullptr, C, ldc, 0, 0L, M, N, K);
  };

  // ---- backbone convs (MFMA, fp16 split, XCD y-band swizzle, grid 544) ----
  conv_mfma<3, 1, 4, 4, 2, float><<<dim3(544, 1, 2), 256, 0, stream>>>(
      d_in[0], FLAGS, 1, (long)384 * HW, WB_LID, W(3), nullptr, nullptr, 0,
      LIDF, (long)128 * HW, 128, 384, 12, 8);
  conv_mfma<1, 1, 4, 4, 2, bf16><<<dim3(544, 1, 2), 256, 0, stream>>>(
      d_in[1], FLAGS, 1, (long)80 * HW, WB_CAM, W(5), nullptr, nullptr, 0,
      CAMF16, (long)128 * HW, 128, 80, 3, 8);
  for (int b = 0; b < 2; b++) {
    conv_mfma<3, 1, 4, 4, 2, float><<<dim3(544, 1, 1), 256, 0, stream>>>(
        LIDF + (long)b * 128 * HW, FLAGS, 0, 0L, WB_HM1, W(7), W(8), W(9), 1,
        HBUF, 0L, 128, 128, 4, 8);
    conv_mfma<3, 4, 1, 1, 1, float><<<dim3(544, 1, 1), 256, 0, stream>>>(
        HBUF, FLAGS, 0, 0L, WB_HM2, W(11), nullptr, nullptr, 2,
        HEAT + (long)b * NCLS * HW, 0L, 10, 128, 4, 1);
  }

  // ---- NMS + exact top-200 ------------------------------------------------
  nms_k<<<(2 * NCLS * HW + 255) / 256, 256, 0, stream>>>(HEAT, SCORE);
  zero_u32<<<(8196 + 255) / 256, 256, 0, stream>>>(U, 8196);
  hist_k<<<dim3(240, 2), 256, 0, stream>>>(SCORE, HIST);
  thresh_k<<<2, 256, 0, stream>>>(HIST, THR);
  collect_k<<<(2 * NCLS * HW + 255) / 256, 256, 0, stream>>>(SCORE, THR, ACNT, CAND);
  select_k<<<2, 64, 0, stream>>>(CAND, ACNT, TOPC, TOPI, QPA);
  gather_k<<<200, 256, 0, stream>>>(LIDF, TOPC, TOPI, W(12), W(13), X);

  // ---- decoder layers -----------------------------------------------------
  for (int i = 0; i < 2; i++) {
    const float* qcur = (i == 0) ? QPA : QPB;
    float* qnext = (i == 0) ? QPB : QPA;
    // query pos-embed fused into GEMM staging (amode 3, A = qpos)
    gemm_k<float, float><<<dim3(7, 2, 1), 256, 0, stream>>>(
        qcur, (const float*)nullptr, 0, 3, 0L,
        W(18) + (size_t)(i * 2 + 0) * 16384, W(19) + (i * 2 + 0) * 128, 0, nullptr,
        W(14) + (i * 2 + 0) * 256, W(15) + (i * 2 + 0) * 128,
        W(16) + (i * 2 + 0) * 128, W(17) + (i * 2 + 0) * 128,
        QPE, 128, 0, 0L, 400, 128, 128);
    // key pos-embed (BEV grid fused), stored transposed [128][HW] bf16
    gemm_k<float, bf16><<<dim3(507, 2, 1), 256, 0, stream>>>(
        ARENA, (const float*)nullptr, 0, 2, 0L,
        W(18) + (size_t)(i * 2 + 1) * 16384, W(19) + (i * 2 + 1) * 128, 0, nullptr,
        W(14) + (i * 2 + 1) * 256, W(15) + (i * 2 + 1) * 128,
        W(16) + (i * 2 + 1) * 128, W(17) + (i * 2 + 1) * 128,
        KPET16, HW, 1, 0L, 32400, 128, 128);
    // self-attention (X+QPE fused via A2)
    gemm(X, QPE, 128, W(20) + (size_t)(i * 2 + 0) * 49152, W(21) + (i * 2 + 0) * 384,
         0, nullptr, SQKV, 384, 400, 384, 128);
    self_attn_k<<<dim3(200, 8, 2), 64, 0, stream>>>(SQKV, SAO);
    gemm(SAO, nullptr, 128, W(22) + (size_t)(i * 2 + 0) * 16384, W(23) + (i * 2 + 0) * 128,
         0, X, PRE, 128, 400, 128, 128);
    ln_k<<<100, 256, 0, stream>>>(PRE, W(24) + (i * 3 + 0) * 128, W(25) + (i * 3 + 0) * 128, X);
    // cross-attention (X+QPE fused via A2)
    gemm(X, QPE, 128, W(20) + (size_t)(i * 2 + 1) * 49152, W(21) + (i * 2 + 1) * 384,
         0, nullptr, QH2, 128, 400, 128, 128);
    kvproj_k<<<dim3(507, 4, 2), 256, 0, stream>>>(
        CAMF16, KPET16,
        W(20) + (size_t)(i * 2 + 1) * 49152 + 16384,
        W(21) + (i * 2 + 1) * 384 + 128, KVT16);
    flash_k<<<dim3(NSPLIT, 8, 4), 256, 0, stream>>>(QH2, KVT16, PART);
    combine_k<<<200, 256, 0, stream>>>(PART, CAO);
    gemm(CAO, nullptr, 128, W(22) + (size_t)(i * 2 + 1) * 16384, W(23) + (i * 2 + 1) * 128,
         0, X, PRE, 128, 400, 128, 128);
    ln_k<<<100, 256, 0, stream>>>(PRE, W(24) + (i * 3 + 1) * 128, W(25) + (i * 3 + 1) * 128, X);
    // FFN
    gemm(X, nullptr, 128, W(26) + (size_t)i * 32768, W(27) + i * 256,
         1, nullptr, FF1, 256, 400, 256, 128);
    gemm(FF1, nullptr, 256, W(28) + (size_t)i * 32768, W(29) + i * 128,
         0, X, PRE, 128, 400, 128, 256);
    ln_k<<<100, 256, 0, stream>>>(PRE, W(24) + (i * 3 + 2) * 128, W(25) + (i * 3 + 2) * 128, X);
    // prediction heads
    conv1d_k<<<dim3(200, 2), 128, 0, stream>>>(X, W(30) + (size_t)i * 49152,
        W(31) + i * 128, W(32) + i * 128, W(33) + i * 128, YC);
    head2_k<<<4, 256, 0, stream>>>(YC, W(34) + (size_t)i * 768, W(35) + i * 2,
        qcur, CENT, 2, qnext);
    conv1d_k<<<dim3(200, 2), 128, 0, stream>>>(X, W(36) + (size_t)i * 49152,
        W(37) + i * 128, W(38) + i * 128, W(39) + i * 128, YC);
    head2_k<<<16, 256, 0, stream>>>(YC, W(40) + (size_t)i * 3840, W(41) + i * 10,
        nullptr, HMP, 10, nullptr);
  }
  out_k<<<19, 256, 0, stream>>>(CENT, HMP, d_out, FLAGS);
}